// Round 8
// baseline (551.648 us; speedup 1.0000x reference)
//
#include <hip/hip_runtime.h>
#include <hip/hip_bf16.h>
#include <math.h>

#define T     2048
#define HID   1536
#define NH    12
#define DK    128
#define DV    128
#define CONVK 4
#define CH    64
#define NC    32

typedef __attribute__((ext_vector_type(8))) short bf16x8;
typedef __attribute__((ext_vector_type(8))) _Float16 fp16x8;
typedef __attribute__((ext_vector_type(4))) float floatx4;

__device__ __forceinline__ float siluf(float x) {
    return x / (1.0f + __expf(-x));
}
__device__ __forceinline__ unsigned short f2bf(float f) {
    union { __hip_bfloat16 b; unsigned short u; } cv;
    cv.b = __float2bfloat16(f);
    return cv.u;
}
__device__ __forceinline__ float bf2f(unsigned short u) {
    union { unsigned int u; float f; } cv;
    cv.u = ((unsigned int)u) << 16;
    return cv.f;
}
__device__ __forceinline__ unsigned short f2h(float f) {
    union { _Float16 h; unsigned short u; } cv;
    cv.h = (_Float16)f;
    return cv.u;
}
__device__ __forceinline__ void gl_lds16(const void* g, void* l) {
    __builtin_amdgcn_global_load_lds(
        (const __attribute__((address_space(1))) void*)g,
        (__attribute__((address_space(3))) void*)l, 16, 0, 0);
}
// split 8 fp32 -> hi/lo bf16, write as 2x ushort4 each
__device__ __forceinline__ void split8_store(const float* xv,
                                             unsigned short* dh, unsigned short* dl) {
    ushort4 h0, h1, l0, l1;
    h0.x = f2bf(xv[0]); l0.x = f2bf(xv[0] - bf2f(h0.x));
    h0.y = f2bf(xv[1]); l0.y = f2bf(xv[1] - bf2f(h0.y));
    h0.z = f2bf(xv[2]); l0.z = f2bf(xv[2] - bf2f(h0.z));
    h0.w = f2bf(xv[3]); l0.w = f2bf(xv[3] - bf2f(h0.w));
    h1.x = f2bf(xv[4]); l1.x = f2bf(xv[4] - bf2f(h1.x));
    h1.y = f2bf(xv[5]); l1.y = f2bf(xv[5] - bf2f(h1.y));
    h1.z = f2bf(xv[6]); l1.z = f2bf(xv[6] - bf2f(h1.z));
    h1.w = f2bf(xv[7]); l1.w = f2bf(xv[7] - bf2f(h1.w));
    *(ushort4*)dh = h0; *(ushort4*)(dh + 4) = h1;
    *(ushort4*)dl = l0; *(ushort4*)(dl + 4) = l1;
}

// ---------------------------------------------------------------------------
// hs: fp32 -> bf16 hi, bf16 lo, fp16  (one pass)
// ---------------------------------------------------------------------------
__global__ __launch_bounds__(256) void splitcast3_kernel(const float* __restrict__ s,
                                                         unsigned short* __restrict__ hi,
                                                         unsigned short* __restrict__ lo,
                                                         unsigned short* __restrict__ h16,
                                                         int n4) {
    int i = blockIdx.x * 256 + threadIdx.x;
    if (i >= n4) return;
    float4 x = ((const float4*)s)[i];
    ushort4 h, l, f;
    h.x = f2bf(x.x); l.x = f2bf(x.x - bf2f(h.x)); f.x = f2h(x.x);
    h.y = f2bf(x.y); l.y = f2bf(x.y - bf2f(h.y)); f.y = f2h(x.y);
    h.z = f2bf(x.z); l.z = f2bf(x.z - bf2f(h.z)); f.z = f2h(x.z);
    h.w = f2bf(x.w); l.w = f2bf(x.w - bf2f(h.w)); f.w = f2h(x.w);
    ((ushort4*)hi)[i] = h;
    ((ushort4*)lo)[i] = l;
    ((ushort4*)h16)[i] = f;
}

// ---------------------------------------------------------------------------
// transpose + split: src (K x N fp32) -> hi/lo (N x K bf16). K%32==0.
// ---------------------------------------------------------------------------
__global__ __launch_bounds__(256) void transsplit_kernel(const float* __restrict__ src,
                                                         unsigned short* __restrict__ hi,
                                                         unsigned short* __restrict__ lo,
                                                         int K, int N) {
    __shared__ float tile[32][33];
    const int k0 = blockIdx.y * 32, n0 = blockIdx.x * 32;
    const int tx = threadIdx.x, ty = threadIdx.y;
#pragma unroll
    for (int r = 0; r < 4; ++r) {
        int kk = k0 + ty + 8 * r, nn = n0 + tx;
        tile[ty + 8 * r][tx] = (nn < N) ? src[(size_t)kk * N + nn] : 0.0f;
    }
    __syncthreads();
#pragma unroll
    for (int r = 0; r < 4; ++r) {
        int nn = n0 + ty + 8 * r, kk = k0 + tx;
        if (nn < N) {
            float x = tile[tx][ty + 8 * r];
            unsigned short h = f2bf(x);
            hi[(size_t)nn * K + kk] = h;
            lo[(size_t)nn * K + kk] = f2bf(x - bf2f(h));
        }
    }
}

// ---------------------------------------------------------------------------
// transpose + cast fp16: src (K x N fp32) -> dst (N x K fp16).
// ---------------------------------------------------------------------------
__global__ __launch_bounds__(256) void transcasth_kernel(const float* __restrict__ src,
                                                         unsigned short* __restrict__ dst,
                                                         int K, int N) {
    __shared__ float tile[32][33];
    const int k0 = blockIdx.y * 32, n0 = blockIdx.x * 32;
    const int tx = threadIdx.x, ty = threadIdx.y;
#pragma unroll
    for (int r = 0; r < 4; ++r) {
        int kk = k0 + ty + 8 * r, nn = n0 + tx;
        tile[ty + 8 * r][tx] = (nn < N) ? src[(size_t)kk * N + nn] : 0.0f;
    }
    __syncthreads();
#pragma unroll
    for (int r = 0; r < 4; ++r) {
        int nn = n0 + ty + 8 * r, kk = k0 + tx;
        if (nn < N) dst[(size_t)nn * K + kk] = f2h(tile[tx][ty + 8 * r]);
    }
}

// ---------------------------------------------------------------------------
// MFMA GEMM template (used only for the final output GEMM: EPI 0, MODE 1).
// MODE 1: 3-term bf16 split (eff. fp32), 128x64 tile, 2-phase prefetch.
// ---------------------------------------------------------------------------
template<int EPI, int MODE>
__global__ __launch_bounds__(256)
void mgemm(const unsigned short* __restrict__ Ah, const unsigned short* __restrict__ Al,
           const unsigned short* __restrict__ Bh, const unsigned short* __restrict__ Bl,
           int K, int N, float* __restrict__ C, unsigned short* __restrict__ Cb)
{
    constexpr int BN   = MODE ? 64 : 128;
    constexpr int BCH  = BN / 16;
    constexpr int NFR  = MODE ? 2 : 4;
    __shared__ unsigned short AsH[2][4096];
    __shared__ unsigned short BsH[2][BCH * 512];
    __shared__ unsigned short AsL[MODE ? 2 : 1][MODE ? 4096 : 4];
    __shared__ unsigned short BsL[MODE ? 2 : 1][MODE ? BCH * 512 : 4];
    const int tid = threadIdx.x;
    const int wave = tid >> 6, lane = tid & 63;
    const int wr = wave >> 1, wc = wave & 1;
    const int lm = lane & 15, lq = lane >> 4;
    const int rowBase = blockIdx.y * 128, colBase = blockIdx.x * BN;

    floatx4 acc[4][NFR];
#pragma unroll
    for (int i = 0; i < 4; ++i)
#pragma unroll
        for (int j = 0; j < NFR; ++j) acc[i][j] = (floatx4){0.f, 0.f, 0.f, 0.f};

    const int mt0 = wave * 2, mt1 = wave * 2 + 1;
    const size_t aOff0 = (size_t)(rowBase + mt0 * 16 + lm) * K + lq * 8;
    const size_t aOff1 = (size_t)(rowBase + mt1 * 16 + lm) * K + lq * 8;
    const size_t bOff0 = (size_t)(colBase + mt0 * 16 + lm) * K + lq * 8;
    const size_t bOff1 = (size_t)(colBase + mt1 * 16 + lm) * K + lq * 8;
    const size_t bOffW = (size_t)(colBase + wave * 16 + lm) * K + lq * 8;

    auto STAGE = [&](int buf, int k0) {
        gl_lds16(Ah + aOff0 + k0, &AsH[buf][mt0 * 512]);
        gl_lds16(Ah + aOff1 + k0, &AsH[buf][mt1 * 512]);
        if (MODE) {
            gl_lds16(Al + aOff0 + k0, &AsL[buf][mt0 * 512]);
            gl_lds16(Al + aOff1 + k0, &AsL[buf][mt1 * 512]);
            gl_lds16(Bh + bOffW + k0, &BsH[buf][wave * 512]);
            gl_lds16(Bl + bOffW + k0, &BsL[buf][wave * 512]);
        } else {
            gl_lds16(Bh + bOff0 + k0, &BsH[buf][mt0 * 512]);
            gl_lds16(Bh + bOff1 + k0, &BsH[buf][mt1 * 512]);
        }
    };

    const int nIter = K >> 5;
    STAGE(0, 0);
    __syncthreads();
    int cur = 0;
    for (int it = 0; it < nIter; ++it) {
        if (it + 1 < nIter) STAGE(cur ^ 1, (it + 1) << 5);
        if (MODE == 0) {
            fp16x8 a[4], b[4];
#pragma unroll
            for (int i = 0; i < 4; ++i) {
                a[i] = *(const fp16x8*)&AsH[cur][(wr * 4 + i) * 512 + lane * 8];
                b[i] = *(const fp16x8*)&BsH[cur][(wc * 4 + i) * 512 + lane * 8];
            }
#pragma unroll
            for (int mi = 0; mi < 4; ++mi)
#pragma unroll
                for (int ni = 0; ni < 4; ++ni)
                    acc[mi][ni] = __builtin_amdgcn_mfma_f32_16x16x32_f16(
                        a[mi], b[ni], acc[mi][ni], 0, 0, 0);
        } else {
            bf16x8 ah[4], al[4], bh[2], bl[2];
#pragma unroll
            for (int i = 0; i < 4; ++i) {
                ah[i] = *(const bf16x8*)&AsH[cur][(wr * 4 + i) * 512 + lane * 8];
                al[i] = *(const bf16x8*)&AsL[cur][(wr * 4 + i) * 512 + lane * 8];
            }
#pragma unroll
            for (int j = 0; j < 2; ++j) {
                bh[j] = *(const bf16x8*)&BsH[cur][(wc * 2 + j) * 512 + lane * 8];
                bl[j] = *(const bf16x8*)&BsL[cur][(wc * 2 + j) * 512 + lane * 8];
            }
#pragma unroll
            for (int mi = 0; mi < 4; ++mi)
#pragma unroll
                for (int ni = 0; ni < 2; ++ni) {
                    acc[mi][ni] = __builtin_amdgcn_mfma_f32_16x16x32_bf16(
                        ah[mi], bh[ni], acc[mi][ni], 0, 0, 0);
                    acc[mi][ni] = __builtin_amdgcn_mfma_f32_16x16x32_bf16(
                        al[mi], bh[ni], acc[mi][ni], 0, 0, 0);
                    acc[mi][ni] = __builtin_amdgcn_mfma_f32_16x16x32_bf16(
                        ah[mi], bl[ni], acc[mi][ni], 0, 0, 0);
                }
        }
        __syncthreads();
        cur ^= 1;
    }

#pragma unroll
    for (int mi = 0; mi < 4; ++mi)
#pragma unroll
        for (int ni = 0; ni < NFR; ++ni) {
            const int col = colBase + wc * (NFR * 16) + ni * 16 + lm;
#pragma unroll
            for (int r = 0; r < 4; ++r) {
                const int row = rowBase + wr * 64 + mi * 16 + lq * 4 + r;
                const float x = acc[mi][ni][r];
                if (EPI == 0) C[(size_t)row * N + col] = x;
                else          Cb[(size_t)row * N + col] = f2bf(x);
            }
        }
}

// ---------------------------------------------------------------------------
// FUSED GEMM A+B (round-7 win, +bg2 epilogue fused): GEMM-A (fp16, 128x128,
// q|v|gate|w1) and GEMM-B (3-term bf16, 128x64, k|beta/g) in one 1024-block
// launch with interleaved roles. B's bg columns now compute beta/g directly
// (bg2_kernel removed).
// ---------------------------------------------------------------------------
__global__ __launch_bounds__(256)
void mgemm_ab(const unsigned short* __restrict__ Ah0, const unsigned short* __restrict__ Bh0,
              const unsigned short* __restrict__ Ah1, const unsigned short* __restrict__ Al1,
              const unsigned short* __restrict__ Bh1, const unsigned short* __restrict__ Bl1,
              float* __restrict__ qf, float* __restrict__ vf,
              unsigned short* __restrict__ gsilb, unsigned short* __restrict__ w1h16,
              float* __restrict__ kf,
              const float* __restrict__ A_log, const float* __restrict__ dt_bias,
              float* __restrict__ beta, float* __restrict__ g)
{
    __shared__ unsigned short smem[24576];   // 48 KB union
    const int tid = threadIdx.x;
    const int wave = tid >> 6, lane = tid & 63;
    const int wr = wave >> 1, wc = wave & 1;
    const int lm = lane & 15, lq = lane >> 4;
    const int K = 1536;
    const int bx = blockIdx.x;

    // interleave roles: A,B,A,B,... for bx<832 (416 B), then all A.
    bool roleA; int aidx = 0, bidx = 0;
    if (bx < 832) { roleA = ((bx & 1) == 0); aidx = bx >> 1; bidx = bx >> 1; }
    else          { roleA = true;            aidx = 416 + (bx - 832); }

    const int mt0 = wave * 2, mt1 = wave * 2 + 1;

    if (roleA) {
        // ---- GEMM-A: fp16 128x128, EPI q|v|gate|w1.  grid map (38,16) ----
        const int rowBase = (aidx / 38) * 128, colBase = (aidx % 38) * 128;
        unsigned short* AsH = smem;          // [2][4096]
        unsigned short* BsH = smem + 8192;   // [2][4096]
        floatx4 acc[4][4];
#pragma unroll
        for (int i = 0; i < 4; ++i)
#pragma unroll
            for (int j = 0; j < 4; ++j) acc[i][j] = (floatx4){0.f, 0.f, 0.f, 0.f};

        const size_t aOff0 = (size_t)(rowBase + mt0 * 16 + lm) * K + lq * 8;
        const size_t aOff1 = (size_t)(rowBase + mt1 * 16 + lm) * K + lq * 8;
        const size_t bOff0 = (size_t)(colBase + mt0 * 16 + lm) * K + lq * 8;
        const size_t bOff1 = (size_t)(colBase + mt1 * 16 + lm) * K + lq * 8;

        auto STAGE = [&](int buf, int k0) {
            gl_lds16(Ah0 + aOff0 + k0, &AsH[buf * 4096 + mt0 * 512]);
            gl_lds16(Ah0 + aOff1 + k0, &AsH[buf * 4096 + mt1 * 512]);
            gl_lds16(Bh0 + bOff0 + k0, &BsH[buf * 4096 + mt0 * 512]);
            gl_lds16(Bh0 + bOff1 + k0, &BsH[buf * 4096 + mt1 * 512]);
        };
        STAGE(0, 0);
        __syncthreads();
        int cur = 0;
        for (int it = 0; it < 48; ++it) {
            if (it + 1 < 48) STAGE(cur ^ 1, (it + 1) << 5);
            fp16x8 a[4], b[4];
#pragma unroll
            for (int i = 0; i < 4; ++i) {
                a[i] = *(const fp16x8*)&AsH[cur * 4096 + (wr * 4 + i) * 512 + lane * 8];
                b[i] = *(const fp16x8*)&BsH[cur * 4096 + (wc * 4 + i) * 512 + lane * 8];
            }
#pragma unroll
            for (int mi = 0; mi < 4; ++mi)
#pragma unroll
                for (int ni = 0; ni < 4; ++ni)
                    acc[mi][ni] = __builtin_amdgcn_mfma_f32_16x16x32_f16(
                        a[mi], b[ni], acc[mi][ni], 0, 0, 0);
            __syncthreads();
            cur ^= 1;
        }
#pragma unroll
        for (int mi = 0; mi < 4; ++mi)
#pragma unroll
            for (int ni = 0; ni < 4; ++ni) {
                const int col = colBase + wc * 64 + ni * 16 + lm;
#pragma unroll
                for (int r = 0; r < 4; ++r) {
                    const int row = rowBase + wr * 64 + mi * 16 + lq * 4 + r;
                    const float x = acc[mi][ni][r];
                    if (col < 1536)       qf[(size_t)row * 1536 + col] = siluf(x);
                    else if (col < 3072)  vf[(size_t)row * 1536 + col - 1536] = x;
                    else if (col < 4608)  gsilb[(size_t)row * 1536 + col - 3072] = f2bf(siluf(x));
                    else if (col < 4800)  w1h16[(size_t)row * 192 + col - 4608] = f2h(siluf(x));
                }
            }
    } else {
        // ---- GEMM-B: 3-term bf16 128x64, EPI k|beta|g.  grid map (26,16) ----
        const int rowBase = (bidx / 26) * 128, colBase = (bidx % 26) * 64;
        unsigned short* AsH = smem;           // [2][4096]
        unsigned short* AsL = smem + 8192;    // [2][4096]
        unsigned short* BsH = smem + 16384;   // [2][2048]
        unsigned short* BsL = smem + 20480;   // [2][2048]
        floatx4 acc[4][2];
#pragma unroll
        for (int i = 0; i < 4; ++i)
#pragma unroll
            for (int j = 0; j < 2; ++j) acc[i][j] = (floatx4){0.f, 0.f, 0.f, 0.f};

        const size_t aOff0 = (size_t)(rowBase + mt0 * 16 + lm) * K + lq * 8;
        const size_t aOff1 = (size_t)(rowBase + mt1 * 16 + lm) * K + lq * 8;
        const size_t bOffW = (size_t)(colBase + wave * 16 + lm) * K + lq * 8;

        auto STAGE = [&](int buf, int k0) {
            gl_lds16(Ah1 + aOff0 + k0, &AsH[buf * 4096 + mt0 * 512]);
            gl_lds16(Ah1 + aOff1 + k0, &AsH[buf * 4096 + mt1 * 512]);
            gl_lds16(Al1 + aOff0 + k0, &AsL[buf * 4096 + mt0 * 512]);
            gl_lds16(Al1 + aOff1 + k0, &AsL[buf * 4096 + mt1 * 512]);
            gl_lds16(Bh1 + bOffW + k0, &BsH[buf * 2048 + wave * 512]);
            gl_lds16(Bl1 + bOffW + k0, &BsL[buf * 2048 + wave * 512]);
        };
        STAGE(0, 0);
        __syncthreads();
        int cur = 0;
        for (int it = 0; it < 48; ++it) {
            if (it + 1 < 48) STAGE(cur ^ 1, (it + 1) << 5);
            bf16x8 ah[4], al[4], bh[2], bl[2];
#pragma unroll
            for (int i = 0; i < 4; ++i) {
                ah[i] = *(const bf16x8*)&AsH[cur * 4096 + (wr * 4 + i) * 512 + lane * 8];
                al[i] = *(const bf16x8*)&AsL[cur * 4096 + (wr * 4 + i) * 512 + lane * 8];
            }
#pragma unroll
            for (int j = 0; j < 2; ++j) {
                bh[j] = *(const bf16x8*)&BsH[cur * 2048 + (wc * 2 + j) * 512 + lane * 8];
                bl[j] = *(const bf16x8*)&BsL[cur * 2048 + (wc * 2 + j) * 512 + lane * 8];
            }
#pragma unroll
            for (int mi = 0; mi < 4; ++mi)
#pragma unroll
                for (int ni = 0; ni < 2; ++ni) {
                    acc[mi][ni] = __builtin_amdgcn_mfma_f32_16x16x32_bf16(
                        ah[mi], bh[ni], acc[mi][ni], 0, 0, 0);
                    acc[mi][ni] = __builtin_amdgcn_mfma_f32_16x16x32_bf16(
                        al[mi], bh[ni], acc[mi][ni], 0, 0, 0);
                    acc[mi][ni] = __builtin_amdgcn_mfma_f32_16x16x32_bf16(
                        ah[mi], bl[ni], acc[mi][ni], 0, 0, 0);
                }
            __syncthreads();
            cur ^= 1;
        }
#pragma unroll
        for (int mi = 0; mi < 4; ++mi)
#pragma unroll
            for (int ni = 0; ni < 2; ++ni) {
                const int col = colBase + wc * 32 + ni * 16 + lm;
#pragma unroll
                for (int r = 0; r < 4; ++r) {
                    const int row = rowBase + wr * 64 + mi * 16 + lq * 4 + r;
                    const float x = acc[mi][ni][r];
                    if (col < 1536) {
                        kf[(size_t)row * 1536 + col] = siluf(x);
                    } else if (col < 1560) {
                        // fused bg2: beta / g directly (identical numerics)
                        const int c2 = col - 1536;
                        if (c2 < 12) {
                            beta[row * NH + c2] = 1.0f / (1.0f + __expf(-x));
                        } else {
                            const int hh = c2 - 12;
                            const float y = x + dt_bias[hh];
                            const float sp = (y > 20.0f) ? y : log1pf(__expf(y));
                            g[row * NH + hh] = -__expf(A_log[hh]) * sp;
                        }
                    }
                }
            }
    }
}

// ---------------------------------------------------------------------------
// FUSED conv-weights GEMM + depthwise conv: wcv = w1 @ Wg2 (fp16 MFMA,
// 128x128 tile, K=192) with the causal depthwise conv applied in the
// epilogue — the 128x128 C-tile is staged in LDS as bf16 (same rounding as
// the old wcv global store), then each thread computes 16 conv outputs
// reading vpre directly.  Kills conv_kernel and the 48MB wcv round-trip.
// grid (48, 16).
// ---------------------------------------------------------------------------
__global__ __launch_bounds__(256)
void convgemm(const unsigned short* __restrict__ Ah, const unsigned short* __restrict__ Bh,
              const float* __restrict__ vpre, float* __restrict__ v)
{
    __shared__ unsigned short smem[16384];   // K-loop: AsH|BsH; epilogue: 128x128 bf16 tile
    const int tid = threadIdx.x;
    const int wave = tid >> 6, lane = tid & 63;
    const int wr = wave >> 1, wc = wave & 1;
    const int lm = lane & 15, lq = lane >> 4;
    const int K = 192;
    const int rowBase = blockIdx.y * 128, colBase = blockIdx.x * 128;

    unsigned short* AsH = smem;          // [2][4096]
    unsigned short* BsH = smem + 8192;   // [2][4096]

    floatx4 acc[4][4];
#pragma unroll
    for (int i = 0; i < 4; ++i)
#pragma unroll
        for (int j = 0; j < 4; ++j) acc[i][j] = (floatx4){0.f, 0.f, 0.f, 0.f};

    const int mt0 = wave * 2, mt1 = wave * 2 + 1;
    const size_t aOff0 = (size_t)(rowBase + mt0 * 16 + lm) * K + lq * 8;
    const size_t aOff1 = (size_t)(rowBase + mt1 * 16 + lm) * K + lq * 8;
    const size_t bOff0 = (size_t)(colBase + mt0 * 16 + lm) * K + lq * 8;
    const size_t bOff1 = (size_t)(colBase + mt1 * 16 + lm) * K + lq * 8;

    auto STAGE = [&](int buf, int k0) {
        gl_lds16(Ah + aOff0 + k0, &AsH[buf * 4096 + mt0 * 512]);
        gl_lds16(Ah + aOff1 + k0, &AsH[buf * 4096 + mt1 * 512]);
        gl_lds16(Bh + bOff0 + k0, &BsH[buf * 4096 + mt0 * 512]);
        gl_lds16(Bh + bOff1 + k0, &BsH[buf * 4096 + mt1 * 512]);
    };

    const int nIter = 6;   // K=192 / 32
    STAGE(0, 0);
    __syncthreads();
    int cur = 0;
    for (int it = 0; it < nIter; ++it) {
        if (it + 1 < nIter) STAGE(cur ^ 1, (it + 1) << 5);
        fp16x8 a[4], b[4];
#pragma unroll
        for (int i = 0; i < 4; ++i) {
            a[i] = *(const fp16x8*)&AsH[cur * 4096 + (wr * 4 + i) * 512 + lane * 8];
            b[i] = *(const fp16x8*)&BsH[cur * 4096 + (wc * 4 + i) * 512 + lane * 8];
        }
#pragma unroll
        for (int mi = 0; mi < 4; ++mi)
#pragma unroll
            for (int ni = 0; ni < 4; ++ni)
                acc[mi][ni] = __builtin_amdgcn_mfma_f32_16x16x32_f16(
                    a[mi], b[ni], acc[mi][ni], 0, 0, 0);
        __syncthreads();
        cur ^= 1;
    }

    // epilogue: C tile -> LDS bf16 (same rounding as old wcv store)
#pragma unroll
    for (int mi = 0; mi < 4; ++mi)
#pragma unroll
        for (int ni = 0; ni < 4; ++ni) {
            const int cl = wc * 64 + ni * 16 + lm;
#pragma unroll
            for (int r = 0; r < 4; ++r) {
                const int rl = wr * 64 + mi * 16 + lq * 4 + r;
                smem[rl * 128 + cl] = f2bf(acc[mi][ni][r]);
            }
        }
    __syncthreads();

    // fused depthwise causal conv: v[t][d] = silu( sum_tap vpre[t-3+tap][d] * w[t][d][tap] )
    const int dB = blockIdx.x * 32;   // 32 d-channels per block (128 cols / 4 taps)
#pragma unroll
    for (int e = 0; e < 16; ++e) {
        const int u = e * 256 + tid;
        const int tl = u >> 5, dd = u & 31;
        const int t = rowBase + tl, d = dB + dd;
        float a0 = 0.0f;
#pragma unroll
        for (int tap = 0; tap < CONVK; ++tap) {
            const int ts = t - (CONVK - 1) + tap;
            if (ts >= 0)
                a0 += vpre[(size_t)ts * HID + d] * bf2f(smem[tl * 128 + dd * 4 + tap]);
        }
        v[(size_t)t * HID + d] = siluf(a0);
    }
}

// ---------------------------------------------------------------------------
// D1: chunk-local WY precompute + FUSED prep emission.  chunkloc already
// stages q/k as split bf16 (QhS/QlS, KhS/KlS) and K^T fp32 (KT) — the old
// prep_kernel re-read the same data from global and re-did the same splits.
// Emitting the tiled Q/K buffers here is numerically identical and kills a
// 384-block kernel + ~25MB of global re-reads.
// ---------------------------------------------------------------------------
__global__ __launch_bounds__(256, 1) void chunkloc_kernel(
    const float* __restrict__ q, const float* __restrict__ k, const float* __restrict__ v,
    const float* __restrict__ g, const float* __restrict__ beta,
    float* __restrict__ X1g,
    unsigned short* __restrict__ X2th, unsigned short* __restrict__ X2tl,
    float* __restrict__ Mg, float* __restrict__ csg,
    unsigned short* __restrict__ Qth, unsigned short* __restrict__ Qtl,
    unsigned short* __restrict__ Kth, unsigned short* __restrict__ Ktl)
{
    __shared__ unsigned short KhS[64 * 136], KlS[64 * 136];
    __shared__ unsigned short QhS[64 * 136], QlS[64 * 136];
    __shared__ float KT[128 * 68];
    __shared__ float Vs[64 * 132];
    __shared__ float As[64 * 68];
    __shared__ float cs[64], sb[64], sbb[64];

    const int c = blockIdx.x, h = blockIdx.y;
    const int tid = threadIdx.x;
    const int wave = tid >> 6, lane = tid & 63;
    const int lm = lane & 15, lq = lane >> 4;
    const int li = tid >> 2, lq4 = tid & 3;
    const size_t rowbase = (size_t)(c * CH) * HID + h * DK;

    {
        const float* ksrc = k + rowbase + (size_t)li * HID + lq4 * 32;
        const float* qsrc = q + rowbase + (size_t)li * HID + lq4 * 32;
        const float* vsrc = v + (size_t)(c * CH + li) * HID + h * DV + lq4 * 32;
#pragma unroll
        for (int f = 0; f < 8; ++f) {
            float4 kx = *(const float4*)(ksrc + f * 4);
            float4 qx = *(const float4*)(qsrc + f * 4);
            float4 vx = *(const float4*)(vsrc + f * 4);
            const int d0 = lq4 * 32 + f * 4;
            {
                ushort4 hh, ll;
                hh.x = f2bf(kx.x); ll.x = f2bf(kx.x - bf2f(hh.x));
                hh.y = f2bf(kx.y); ll.y = f2bf(kx.y - bf2f(hh.y));
                hh.z = f2bf(kx.z); ll.z = f2bf(kx.z - bf2f(hh.z));
                hh.w = f2bf(kx.w); ll.w = f2bf(kx.w - bf2f(hh.w));
                *(ushort4*)&KhS[li * 136 + d0] = hh;
                *(ushort4*)&KlS[li * 136 + d0] = ll;
            }
            {
                ushort4 hh, ll;
                hh.x = f2bf(qx.x); ll.x = f2bf(qx.x - bf2f(hh.x));
                hh.y = f2bf(qx.y); ll.y = f2bf(qx.y - bf2f(hh.y));
                hh.z = f2bf(qx.z); ll.z = f2bf(qx.z - bf2f(hh.z));
                hh.w = f2bf(qx.w); ll.w = f2bf(qx.w - bf2f(hh.w));
                *(ushort4*)&QhS[li * 136 + d0] = hh;
                *(ushort4*)&QlS[li * 136 + d0] = ll;
            }
            KT[(d0 + 0) * 68 + li] = kx.x;
            KT[(d0 + 1) * 68 + li] = kx.y;
            KT[(d0 + 2) * 68 + li] = kx.z;
            KT[(d0 + 3) * 68 + li] = kx.w;
            *(float4*)&Vs[li * 132 + d0] = vx;
        }
    }
    if (tid < 64) {
        float gv = g[(c * CH + tid) * NH + h];
        float bv = beta[(c * CH + tid) * NH + h];
        float csv = gv;
#pragma unroll
        for (int off = 1; off < 64; off <<= 1) {
            float n = __shfl_up(csv, off);
            if (tid >= off) csv += n;
        }
        cs[tid] = csv; sb[tid] = bv; sbb[tid] = bv * __expf(csv);
    }
    __syncthreads();

    {
        const int ti = wave;
#pragma unroll
        for (int tj = 0; tj < 4; ++tj) {
            floatx4 acc = (floatx4){0.f, 0.f, 0.f, 0.f};
#pragma unroll
            for (int ks = 0; ks < 4; ++ks) {
                bf16x8 a_h = *(const bf16x8*)&KhS[(ti * 16 + lm) * 136 + ks * 32 + lq * 8];
                bf16x8 a_l = *(const bf16x8*)&KlS[(ti * 16 + lm) * 136 + ks * 32 + lq * 8];
                bf16x8 b_h = *(const bf16x8*)&KhS[(tj * 16 + lm) * 136 + ks * 32 + lq * 8];
                bf16x8 b_l = *(const bf16x8*)&KlS[(tj * 16 + lm) * 136 + ks * 32 + lq * 8];
                acc = __builtin_amdgcn_mfma_f32_16x16x32_bf16(a_h, b_h, acc, 0, 0, 0);
                acc = __builtin_amdgcn_mfma_f32_16x16x32_bf16(a_h, b_l, acc, 0, 0, 0);
                acc = __builtin_amdgcn_mfma_f32_16x16x32_bf16(a_l, b_h, acc, 0, 0, 0);
            }
#pragma unroll
            for (int r = 0; r < 4; ++r) {
                const int i = ti * 16 + lq * 4 + r, j = tj * 16 + lm;
                As[i * 68 + j] = (j < i) ? sb[i] * __expf(cs[i] - cs[j]) * acc[r] : 0.0f;
            }
        }
        const size_t mbase = (size_t)(h * NC + c) * CH * CH;
#pragma unroll
        for (int tj = 0; tj < 4; ++tj) {
            floatx4 acc = (floatx4){0.f, 0.f, 0.f, 0.f};
#pragma unroll
            for (int ks = 0; ks < 4; ++ks) {
                bf16x8 a_h = *(const bf16x8*)&QhS[(ti * 16 + lm) * 136 + ks * 32 + lq * 8];
                bf16x8 a_l = *(const bf16x8*)&QlS[(ti * 16 + lm) * 136 + ks * 32 + lq * 8];
                bf16x8 b_h = *(const bf16x8*)&KhS[(tj * 16 + lm) * 136 + ks * 32 + lq * 8];
                bf16x8 b_l = *(const bf16x8*)&KlS[(tj * 16 + lm) * 136 + ks * 32 + lq * 8];
                acc = __builtin_amdgcn_mfma_f32_16x16x32_bf16(a_h, b_h, acc, 0, 0, 0);
                acc = __builtin_amdgcn_mfma_f32_16x16x32_bf16(a_h, b_l, acc, 0, 0, 0);
                acc = __builtin_amdgcn_mfma_f32_16x16x32_bf16(a_l, b_h, acc, 0, 0, 0);
            }
#pragma unroll
            for (int r = 0; r < 4; ++r) {
                const int i = ti * 16 + lq * 4 + r, j = tj * 16 + lm;
                Mg[mbase + (size_t)i * 64 + j] =
                    (j <= i) ? __expf(cs[i] - cs[j]) * acc[r] : 0.0f;
            }
        }
    }

    float xc[64];
    const int col = tid;
    if (col < 128) {
#pragma unroll
        for (int i = 0; i < 64; ++i) xc[i] = sb[i] * Vs[i * 132 + col];
    } else {
        const int dcol = col - 128;
#pragma unroll
        for (int i4 = 0; i4 < 16; ++i4) {
            float4 kq = *(const float4*)&KT[dcol * 68 + i4 * 4];
            xc[i4 * 4 + 0] = sbb[i4 * 4 + 0] * kq.x;
            xc[i4 * 4 + 1] = sbb[i4 * 4 + 1] * kq.y;
            xc[i4 * 4 + 2] = sbb[i4 * 4 + 2] * kq.z;
            xc[i4 * 4 + 3] = sbb[i4 * 4 + 3] * kq.w;
        }
    }
    __syncthreads();

#pragma unroll
    for (int i = 1; i < 64; ++i) {
        float a = xc[i];
#pragma unroll
        for (int j4 = 0; j4 < (i + 3) / 4; ++j4) {
            float4 a4 = *(const float4*)&As[i * 68 + j4 * 4];
            a -= a4.x * xc[j4 * 4 + 0] + a4.y * xc[j4 * 4 + 1]
               + a4.z * xc[j4 * 4 + 2] + a4.w * xc[j4 * 4 + 3];
        }
        xc[i] = a;
    }

    // X1 fp32; X2 columns -> Vs for transpose
    {
        const size_t xbase = (size_t)(h * NC + c) * CH * 128;
        if (col < 128) {
            for (int i = 0; i < 64; ++i) X1g[xbase + (size_t)i * 128 + col] = xc[i];
        } else {
            for (int i = 0; i < 64; ++i) Vs[i * 132 + (col - 128)] = xc[i];
        }
    }
    if (tid < 64) csg[(size_t)(h * NC + c) * CH + tid] = cs[tid];
    __syncthreads();

    const size_t tb = (size_t)(h * NC + c) * 8192;

    // tiled (negated) X2 emission
    {
#pragma unroll
        for (int e = 0; e < 4; ++e) {
            int u = e * 256 + tid;
            int ch = u >> 6, l = u & 63;
            int i = (ch >> 2) * 16 + (l & 15);
            int dbase = (ch & 3) * 32 + (l >> 4) * 8;
            float4 a = *(const float4*)&Vs[i * 132 + dbase];
            float4 b = *(const float4*)&Vs[i * 132 + dbase + 4];
            float xv[8] = {-a.x, -a.y, -a.z, -a.w, -b.x, -b.y, -b.z, -b.w};
            split8_store(xv, &X2th[tb + ch * 512 + l * 8], &X2tl[tb + ch * 512 + l * 8]);
        }
    }

    // fused prep: Q tiled emission (copy from QhS/QlS — identical splits)
    {
#pragma unroll
        for (int e = 0; e < 4; ++e) {
            int u = e * 256 + tid;
            int ch = u >> 6, l = u & 63;
            int i = (ch >> 2) * 16 + (l & 15);
            int dbase = (ch & 3) * 32 + (l >> 4) * 8;
            *(bf16x8*)&Qth[tb + ch * 512 + l * 8] = *(const bf16x8*)&QhS[i * 136 + dbase];
            *(bf16x8*)&Qtl[tb + ch * 512 + l * 8] = *(const bf16x8*)&QlS[i * 136 + dbase];
        }
    }

    // fused prep: K^T tiled emission (split from fp32 KT — identical numerics)
    {
#pragma unroll
        for (int e = 0; e < 4; ++e) {
            int u = e * 256 + tid;
            int ch = u >> 6, l = u & 63;
            int dk = (ch >> 1) * 16 + (l & 15);
            int ibase = (ch & 1) * 32 + (l >> 4) * 8;
            float4 a = *(const float4*)&KT[dk * 68 + ibase];
            float4 b = *(const float4*)&KT[dk * 68 + ibase + 4];
            float xv[8] = {a.x, a.y, a.z, a.w, b.x, b.y, b.z, b.w};
            split8_store(xv, &Kth[tb + ch * 512 + l * 8], &Ktl[tb + ch * 512 + l * 8]);
        }
    }
}

// ---------------------------------------------------------------------------
// D2 support: per-chunk register fragment set. All indices compile-time.
// ---------------------------------------------------------------------------
struct StFrags {
    bf16x8 xh[4], xl[4], qh[4], ql[4], kh[4], kl[4];
    float x1r[4], csr[4], cs63;
};

__device__ __forceinline__ void st_load(
    StFrags& f,
    const unsigned short* __restrict__ Qth, const unsigned short* __restrict__ Qtl,
    const unsigned short* __restrict__ Kth, const unsigned short* __restrict__ Ktl,
    const unsigned short* __restrict__ X2th, const unsigned short* __restrict__ X2tl,
    const float* __restrict__ X1g, const float* __restrict__ csg,
    int h, int c, int db, int mw, int lane, int lq, int lm)
{
    const size_t hc = (size_t)(h * NC + c);
    const size_t xb = hc * CH * 128;
    const size_t tb = hc * 8192 + (size_t)lane * 8;
#pragma unroll
    for (int ks = 0; ks < 4; ++ks) {
        const size_t off = tb + (size_t)(mw * 4 + ks) * 512;
        f.xh[ks] = *(const bf16x8*)(X2th + off);
        f.xl[ks] = *(const bf16x8*)(X2tl + off);
        f.qh[ks] = *(const bf16x8*)(Qth + off);
        f.ql[ks] = *(const bf16x8*)(Qtl + off);
        f.kh[ks] = *(const bf16x8*)(Kth + off);
        f.kl[ks] = *(const bf16x8*)(Ktl + off);
    }
#pragma unroll
    for (int r = 0; r < 4; ++r) {
        const int row = mw * 16 + lq * 4 + r;
        f.x1r[r] = X1g[xb + (size_t)row * 128 + db * 16 + lm];
        f.csr[r] = csg[hc * CH + row];
    }
    f.cs63 = csg[hc * CH + 63];
}

__device__ __forceinline__ void st_compute(
    const StFrags& f, floatx4& st0, floatx4& st1,
    unsigned short* SBh, unsigned short* SBl,
    unsigned short* UBh, unsigned short* UBl,
    float* __restrict__ X1g, float* __restrict__ o,
    int h, int c, int db, int mw, int lane, int lq, int lm)
{
    const size_t hc = (size_t)(h * NC + c);
    const size_t xb = hc * CH * 128;

    // ---- phase 2: U + o1 via MFMA (SB from prev chunk's phase 3) ----
    {
        floatx4 aU0 = (floatx4){0.f, 0.f, 0.f, 0.f};
        floatx4 aU1 = (floatx4){0.f, 0.f, 0.f, 0.f};
        floatx4 aO0 = (floatx4){0.f, 0.f, 0.f, 0.f};
        floatx4 aO1 = (floatx4){0.f, 0.f, 0.f, 0.f};
#pragma unroll
        for (int ks = 0; ks < 4; ++ks) {
            bf16x8 sh = *(const bf16x8*)&SBh[lm * 136 + ks * 32 + lq * 8];
            bf16x8 sl = *(const bf16x8*)&SBl[lm * 136 + ks * 32 + lq * 8];
            if (ks & 1) {
                aU1 = __builtin_amdgcn_mfma_f32_16x16x32_bf16(f.xh[ks], sh, aU1, 0, 0, 0);
                aU1 = __builtin_amdgcn_mfma_f32_16x16x32_bf16(f.xh[ks], sl, aU1, 0, 0, 0);
                aU1 = __builtin_amdgcn_mfma_f32_16x16x32_bf16(f.xl[ks], sh, aU1, 0, 0, 0);
                aO1 = __builtin_amdgcn_mfma_f32_16x16x32_bf16(f.qh[ks], sh, aO1, 0, 0, 0);
                aO1 = __builtin_amdgcn_mfma_f32_16x16x32_bf16(f.qh[ks], sl, aO1, 0, 0, 0);
                aO1 = __builtin_amdgcn_mfma_f32_16x16x32_bf16(f.ql[ks], sh, aO1, 0, 0, 0);
            } else {
                aU0 = __builtin_amdgcn_mfma_f32_16x16x32_bf16(f.xh[ks], sh, aU0, 0, 0, 0);
                aU0 = __builtin_amdgcn_mfma_f32_16x16x32_bf16(f.xh[ks], sl, aU0, 0, 0, 0);
                aU0 = __builtin_amdgcn_mfma_f32_16x16x32_bf16(f.xl[ks], sh, aU0, 0, 0, 0);
                aO0 = __builtin_amdgcn_mfma_f32_16x16x32_bf16(f.qh[ks], sh, aO0, 0, 0, 0);
                aO0 = __builtin_amdgcn_mfma_f32_16x16x32_bf16(f.qh[ks], sl, aO0, 0, 0, 0);
                aO0 = __builtin_amdgcn_mfma_f32_16x16x32_bf16(f.ql[ks], sh, aO0, 0, 0, 0);
            }
        }
#pragma unroll
        for (int r = 0; r < 4; ++r) {
            const int row = mw * 16 + lq * 4 + r;
            const float u = aU0[r] + aU1[r] + f.x1r[r];
            X1g[xb + (size_t)row * 128 + db * 16 + lm] = u;
            const float up = u * __expf(f.cs63 - f.csr[r]);
            unsigned short uh = f2bf(up);
            UBh[lm * 72 + row] = uh;
            UBl[lm * 72 + row] = f2bf(up - bf2f(uh));
            o[(size_t)(c * CH + row) * HID + h * DV + db * 16 + lm] =
                __expf(f.csr[r]) * (aO0[r] + aO1[r]);
        }
    }
    __syncthreads();   // UB ready; SB reads done before SB rewrite below

    // ---- phase 3: S = exp(cs63)*S + K^T U' via MFMA ----
    {
        const float bC = __expf(f.cs63);
#pragma unroll
        for (int mt2 = 0; mt2 < 2; ++mt2) {
            const int mt = mw * 2 + mt2;
            floatx4 acc;
            floatx4 stc = mt2 ? st1 : st0;
#pragma unroll
            for (int r = 0; r < 4; ++r) acc[r] = bC * stc[r];
#pragma unroll
            for (int ks = 0; ks < 2; ++ks) {
                bf16x8 ah = f.kh[mt2 * 2 + ks];
                bf16x8 al = f.kl[mt2 * 2 + ks];
                bf16x8 bh = *(const bf16x8*)&UBh[lm * 72 + ks * 32 + lq * 8];
                bf16x8 bl = *(const bf16x8*)&UBl[lm * 72 + ks * 32 + lq * 8];
                acc = __builtin_amdgcn_mfma_f32_16x16x32_bf16(ah, bh, acc, 0, 0, 0);
                acc = __builtin_amdgcn_mfma_f32_16x16x32_bf16(ah, bl, acc, 0, 0, 0);
                acc = __builtin_amdgcn_mfma_f32_16x16x32_bf16(al, bh, acc, 0, 0, 0);
            }
            if (mt2) st1 = acc; else st0 = acc;
            ushort4 shv, slv;
#pragma unroll
            for (int r = 0; r < 4; ++r) {
                const float sv = acc[r];
                unsigned short sh = f2bf(sv);
                ((unsigned short*)&shv)[r] = sh;
                ((unsigned short*)&slv)[r] = f2bf(sv - bf2f(sh));
            }
            const int dkb = mt * 16 + lq * 4;
            *(ushort4*)&SBh[lm * 136 + dkb] = shv;
            *(ushort4*)&SBl[lm * 136 + dkb] = slv;
        }
    }
    __syncthreads();   // SB ready for next chunk's phase 2; UB free
}

// ---------------------------------------------------------------------------
// D2: serial inter-chunk recurrence — register fragments, cross-chunk
// double-buffered prefetch (fA/fB named sets, sched_barrier-pinned).
// grid (NH, 8).
// ---------------------------------------------------------------------------
__global__ __launch_bounds__(256, 1) void state_kernel(
    const unsigned short* __restrict__ Qth, const unsigned short* __restrict__ Qtl,
    const unsigned short* __restrict__ Kth, const unsigned short* __restrict__ Ktl,
    const unsigned short* __restrict__ X2th, const unsigned short* __restrict__ X2tl,
    float* __restrict__ X1g /* in: X1, out: U */,
    const float* __restrict__ csg, float* __restrict__ o)
{
    __shared__ unsigned short SBh[16 * 136], SBl[16 * 136];
    __shared__ unsigned short UBh[16 * 72],  UBl[16 * 72];

    const int h = blockIdx.x, db = blockIdx.y;
    const int tid = threadIdx.x;
    const int mw = tid >> 6, lane = tid & 63;
    const int lm = lane & 15, lq = lane >> 4;

    for (int idx = tid; idx < 16 * 136; idx += 256) { SBh[idx] = 0; SBl[idx] = 0; }
    floatx4 st0 = (floatx4){0.f, 0.f, 0.f, 0.f};
    floatx4 st1 = (floatx4){0.f, 0.f, 0.f, 0.f};
    __syncthreads();

    StFrags fA, fB;
    st_load(fA, Qth, Qtl, Kth, Ktl, X2th, X2tl, X1g, csg, h, 0, db, mw, lane, lq, lm);
    for (int c = 0; c < NC; c += 2) {
        st_load(fB, Qth, Qtl, Kth, Ktl, X2th, X2tl, X1g, csg, h, c + 1, db, mw, lane, lq, lm);
        __builtin_amdgcn_sched_barrier(0);
        st_compute(fA, st0, st1, SBh, SBl, UBh, UBl, X1g, o, h, c, db, mw, lane, lq, lm);
        if (c + 2 < NC)
            st_load(fA, Qth, Qtl, Kth, Ktl, X2th, X2tl, X1g, csg, h, c + 2, db, mw, lane, lq, lm);
        __builtin_amdgcn_sched_barrier(0);
        st_compute(fB, st0, st1, SBh, SBl, UBh, UBl, X1g, o, h, c + 1, db, mw, lane, lq, lm);
    }
}

// ---------------------------------------------------------------------------
// D3: o = scale * (o + M U), all fp32 (verified)
// ---------------------------------------------------------------------------
__global__ __launch_bounds__(256) void outk_kernel(
    const float* __restrict__ Ug, const float* __restrict__ Mg,
    float* __restrict__ o)
{
    __shared__ float Msh[64 * 68];
    __shared__ float Ush[64 * 68];

    const int c = blockIdx.x, h = blockIdx.y;
    const int dvb = blockIdx.z * 64;
    const int tid = threadIdx.x;
    const size_t hc = (size_t)(h * NC + c);

    for (int e = 0; e < 16; ++e) {
        int idx = e * 256 + tid;
        Msh[(idx >> 6) * 68 + (idx & 63)] = Mg[hc * CH * CH + idx];
    }
    for (int e = 0; e < 16; ++e) {
        int idx = e * 256 + tid;
        int j = idx >> 6, cc = idx & 63;
        Ush[j * 68 + cc] = Ug[hc * CH * 128 + (size_t)j * 128 + dvb + cc];
    }
    __syncthreads();

    const int tx = tid & 15, ty = tid >> 4;
    const int c0 = tx * 4, i0 = ty * 4;
    float acc[4][4] = {{0}};
    for (int j4 = 0; j4 < 16; ++j4) {
        float uv[4][4];
#pragma unroll
        for (int s = 0; s < 4; ++s) {
            float4 u4 = *(const float4*)&Ush[(j4 * 4 + s) * 68 + c0];
            uv[s][0] = u4.x; uv[s][1] = u4.y; uv[s][2] = u4.z; uv[s][3] = u4.w;
        }
#pragma unroll
        for (int r = 0; r < 4; ++r) {
            float4 m4 = *(const float4*)&Msh[(i0 + r) * 68 + j4 * 4];
            const float mv[4] = {m4.x, m4.y, m4.z, m4.w};
#pragma unroll
            for (int s = 0; s < 4; ++s)
#pragma unroll
                for (int e = 0; e < 4; ++e) acc[r][e] += mv[s] * uv[s][e];
        }
    }
    const float scale = 0.08838834764831845f;
#pragma unroll
    for (int r = 0; r < 4; ++r) {
        float* op = &o[(size_t)(c * CH + i0 + r) * HID + h * DV + dvb + c0];
        float4 prev = *(const float4*)op;
        float4 ov = make_float4(scale * (prev.x + acc[r][0]),
                                scale * (prev.y + acc[r][1]),
                                scale * (prev.z + acc[r][2]),
                                scale * (prev.w + acc[r][3]));
        *(float4*)op = ov;
    }
}

// ---------------------------------------------------------------------------
// Gated RMSNorm: gsil bf16 in, onorm (hi,lo) bf16 out
// ---------------------------------------------------------------------------
__global__ __launch_bounds__(256) void normgate_kernel(const float* __restrict__ o,
                                                       const unsigned short* __restrict__ gsil,
                                                       const float* __restrict__ nw,
                                                       unsigned short* __restrict__ out_hi,
                                                       unsigned short* __restrict__ out_lo) {
    const int gw = (blockIdx.x * 256 + threadIdx.x) >> 6;
    const int lane = threadIdx.x & 63;
    if (gw >= T * NH) return;
    const int t = gw / NH, h = gw % NH;
    const size_t base = (size_t)t * HID + h * DV;
    const float a = o[base + lane];
    const float b = o[base + lane + 64];
    float ss = a * a + b * b;
    ss += __shfl_xor(ss, 1);  ss += __shfl_xor(ss, 2);  ss += __shfl_xor(ss, 4);
    ss += __shfl_xor(ss, 8);  ss += __shfl_xor(ss, 16); ss += __shfl_xor(ss, 32);
    const float r = rsqrtf(ss * (1.0f / 128.0f) + 1e-5f);
    float va = a * r * nw[lane]      * bf2f(gsil[base + lane]);
    float vb = b * r * nw[lane + 64] * bf2f(gsil[base + lane + 64]);
    unsigned short ha = f2bf(va), hb = f2bf(vb);
    out_hi[base + lane]      = ha;  out_lo[base + lane]      = f2bf(va - bf2f(ha));
    out_hi[base + lane + 64] = hb;  out_lo[base + lane + 64] = f2bf(vb - bf2f(hb));
}

// ---------------------------------------------------------------------------
extern "C" void kernel_launch(void* const* d_in, const int* in_sizes, int n_in,
                              void* d_out, int out_size, void* d_ws, size_t ws_size,
                              hipStream_t stream) {
    const float* hs      = (const float*)d_in[0];
    const float* Wq      = (const float*)d_in[1];
    const float* Wk      = (const float*)d_in[2];
    const float* Wv      = (const float*)d_in[3];
    const float* Wb      = (const float*)d_in[4];
    const float* Wa      = (const float*)d_in[5];
    const float* A_log   = (const float*)d_in[6];
    const float* dt_bias = (const float*)d_in[7];
    const float* Wg1     = (const float*)d_in[8];
    const float* Wg2     = (const float*)d_in[9];
    const float* Wgate   = (const float*)d_in[10];
    const float* norm_w  = (const float*)d_in[11];
    const float* Wo      = (const float*)d_in[12];

    float* ws = (float*)d_ws;
    // ---- layout (floats), end = 25,264,128 f = 101.1 MB (<= proven 102.4) ----
    float* q    = ws;                                        // later WoTh/WoTl
    float* kbuf = ws + 3145728;
    float* vpre = ws + 6291456;                              // later Qt, then onh/onl
    float* vbuf = ws + 9437184;                              // early hsbh/hsbl; then v / o
    unsigned short* gsil = (unsigned short*)(ws + 12582912); // [ ,14155776)
    // region B:
    float* X1g  = ws + 14155776;                             // fp32, becomes U
    unsigned short* X2th = (unsigned short*)(ws + 17301504); // tiled -X2 hi (3.15M sh)
    unsigned short* X2tl = (unsigned short*)(ws + 18874368); // tiled -X2 lo
    float* Mg   = ws + 20447232;                             // -> 22,020,096
    unsigned short* WTAfh = (unsigned short*)(ws + 14155776); // early overlay: 4864x1536 fp16
    unsigned short* WTBh  = (unsigned short*)(ws + 17891328); // early: 1664x1536 bf16
    unsigned short* WTBl  = (unsigned short*)(ws + 19169280);
    // region C:
    unsigned short* WG2h  = (unsigned short*)(ws + 22044672); // transient
    unsigned short* hsh   = (unsigned short*)(ws + 22634496); // transient
    unsigned short* w1h16 = (unsigned short*)(ws + 24207360); // transient
    unsigned short* Kth = (unsigned short*)(ws + 22044672);   // tiled K hi (after convgemm)
    unsigned short* Ktl = (unsigned short*)(ws + 23617536);   // tiled K lo
    float* beta  = ws + 25190400;
    float* g     = ws + 25214976;
    float* csg   = ws + 25239552;                             // -> 25,264,128
    // overlays
    unsigned short* hsbh = (unsigned short*)(ws + 9437184);
    unsigned short* hsbl = (unsigned short*)(ws + 11010048);
    unsigned short* Qth  = (unsigned short*)(ws + 6291456);   // tiled Q hi (after convgemm)
    unsigned short* Qtl  = (unsigned short*)(ws + 7864320);
    unsigned short* WoTh = (unsigned short*)(ws);
    unsigned short* WoTl = (unsigned short*)(ws + 1179648);
    unsigned short* onh  = (unsigned short*)(ws + 6291456);
    unsigned short* onl  = (unsigned short*)(ws + 7864320);

    const dim3 blk(256);
    const dim3 blkT(32, 8);

    // P0: hs -> bf16 hi/lo + fp16; weights: A-batch fp16, B-batch bf16 split.
    splitcast3_kernel<<<3072, blk, 0, stream>>>(hs, hsbh, hsbl, hsh, (T * HID) / 4);
    transcasth_kernel<<<dim3(48, 48), blkT, 0, stream>>>(Wq,    WTAfh,               1536, 1536);
    transcasth_kernel<<<dim3(48, 48), blkT, 0, stream>>>(Wv,    WTAfh + 1536 * 1536, 1536, 1536);
    transcasth_kernel<<<dim3(48, 48), blkT, 0, stream>>>(Wgate, WTAfh + 3072 * 1536, 1536, 1536);
    transcasth_kernel<<<dim3(6, 48),  blkT, 0, stream>>>(Wg1,   WTAfh + 4608 * 1536, 1536, 192);
    transsplit_kernel<<<dim3(48, 48), blkT, 0, stream>>>(Wk, WTBh,               WTBl,               1536, 1536);
    transsplit_kernel<<<dim3(1, 48),  blkT, 0, stream>>>(Wb, WTBh + 1536 * 1536, WTBl + 1536 * 1536, 1536, 12);
    transsplit_kernel<<<dim3(1, 48),  blkT, 0, stream>>>(Wa, WTBh + 1548 * 1536, WTBl + 1548 * 1536, 1536, 12);
    transcasth_kernel<<<dim3(192, 6), blkT, 0, stream>>>(Wg2, WG2h, 192, 6144);

    // P1: fused GEMM-A + GEMM-B (+ inline beta/g epilogue)
    mgemm_ab<<<1024, blk, 0, stream>>>(hsh, WTAfh, hsbh, hsbl, WTBh, WTBl,
                                       q, vpre, gsil, w1h16, kbuf,
                                       A_log, dt_bias, beta, g);

    // P2: conv weights GEMM with fused depthwise conv epilogue
    convgemm<<<dim3(48, 16), blk, 0, stream>>>(w1h16, WG2h, vpre, vbuf);

    // P3: chunked delta rule (chunkloc now also emits tiled Q/K — prep fused)
    chunkloc_kernel<<<dim3(NC, NH), blk, 0, stream>>>(q, kbuf, vbuf, g, beta,
                                                      X1g, X2th, X2tl, Mg, csg,
                                                      Qth, Qtl, Kth, Ktl);
    state_kernel<<<dim3(NH, 8), blk, 0, stream>>>(Qth, Qtl, Kth, Ktl, X2th, X2tl,
                                                  X1g, csg, vbuf);
    transsplit_kernel<<<dim3(48, 48), blkT, 0, stream>>>(Wo, WoTh, WoTl, 1536, 1536);
    outk_kernel<<<dim3(NC, NH, 2), blk, 0, stream>>>(X1g, Mg, vbuf);

    // P4: norm + output GEMM (3-term bf16)
    normgate_kernel<<<6144, blk, 0, stream>>>(vbuf, gsil, norm_w, onh, onl);
    mgemm<0, 1><<<dim3(24, 16), blk, 0, stream>>>(onh, onl, WoTh, WoTl, 1536, 1536,
        (float*)d_out, nullptr);
}

// Round 10
// 532.354 us; speedup vs baseline: 1.0362x; 1.0362x over previous
//
#include <hip/hip_runtime.h>
#include <hip/hip_bf16.h>
#include <math.h>

#define T     2048
#define HID   1536
#define NH    12
#define DK    128
#define DV    128
#define CONVK 4
#define CH    64
#define NC    32

typedef __attribute__((ext_vector_type(8))) short bf16x8;
typedef __attribute__((ext_vector_type(8))) _Float16 fp16x8;
typedef __attribute__((ext_vector_type(4))) float floatx4;

__device__ __forceinline__ float siluf(float x) {
    return x / (1.0f + __expf(-x));
}
__device__ __forceinline__ unsigned short f2bf(float f) {
    union { __hip_bfloat16 b; unsigned short u; } cv;
    cv.b = __float2bfloat16(f);
    return cv.u;
}
__device__ __forceinline__ float bf2f(unsigned short u) {
    union { unsigned int u; float f; } cv;
    cv.u = ((unsigned int)u) << 16;
    return cv.f;
}
__device__ __forceinline__ unsigned short f2h(float f) {
    union { _Float16 h; unsigned short u; } cv;
    cv.h = (_Float16)f;
    return cv.u;
}
__device__ __forceinline__ void gl_lds16(const void* g, void* l) {
    __builtin_amdgcn_global_load_lds(
        (const __attribute__((address_space(1))) void*)g,
        (__attribute__((address_space(3))) void*)l, 16, 0, 0);
}
// split 8 fp32 -> hi/lo bf16, write as 2x ushort4 each
__device__ __forceinline__ void split8_store(const float* xv,
                                             unsigned short* dh, unsigned short* dl) {
    ushort4 h0, h1, l0, l1;
    h0.x = f2bf(xv[0]); l0.x = f2bf(xv[0] - bf2f(h0.x));
    h0.y = f2bf(xv[1]); l0.y = f2bf(xv[1] - bf2f(h0.y));
    h0.z = f2bf(xv[2]); l0.z = f2bf(xv[2] - bf2f(h0.z));
    h0.w = f2bf(xv[3]); l0.w = f2bf(xv[3] - bf2f(h0.w));
    h1.x = f2bf(xv[4]); l1.x = f2bf(xv[4] - bf2f(h1.x));
    h1.y = f2bf(xv[5]); l1.y = f2bf(xv[5] - bf2f(h1.y));
    h1.z = f2bf(xv[6]); l1.z = f2bf(xv[6] - bf2f(h1.z));
    h1.w = f2bf(xv[7]); l1.w = f2bf(xv[7] - bf2f(h1.w));
    *(ushort4*)dh = h0; *(ushort4*)(dh + 4) = h1;
    *(ushort4*)dl = l0; *(ushort4*)(dl + 4) = l1;
}

// ---------------------------------------------------------------------------
// device bodies for the fused prep kernel. REQUIRE a flat 256-thread tid.
// ---------------------------------------------------------------------------
__device__ __forceinline__ void tch_body(const float* __restrict__ src,
                                         unsigned short* __restrict__ dst,
                                         int K, int N, int gx, int gy, int tid,
                                         float* tile /*32*33*/) {
    const int tx = tid & 31, ty = tid >> 5;
    const int k0 = gy * 32, n0 = gx * 32;
#pragma unroll
    for (int r = 0; r < 4; ++r) {
        int kk = k0 + ty + 8 * r, nn = n0 + tx;
        tile[(ty + 8 * r) * 33 + tx] = (nn < N) ? src[(size_t)kk * N + nn] : 0.0f;
    }
    __syncthreads();
#pragma unroll
    for (int r = 0; r < 4; ++r) {
        int nn = n0 + ty + 8 * r, kk = k0 + tx;
        if (nn < N) dst[(size_t)nn * K + kk] = f2h(tile[tx * 33 + ty + 8 * r]);
    }
}
__device__ __forceinline__ void tsp_body(const float* __restrict__ src,
                                         unsigned short* __restrict__ hi,
                                         unsigned short* __restrict__ lo,
                                         int K, int N, int gx, int gy, int tid,
                                         float* tile) {
    const int tx = tid & 31, ty = tid >> 5;
    const int k0 = gy * 32, n0 = gx * 32;
#pragma unroll
    for (int r = 0; r < 4; ++r) {
        int kk = k0 + ty + 8 * r, nn = n0 + tx;
        tile[(ty + 8 * r) * 33 + tx] = (nn < N) ? src[(size_t)kk * N + nn] : 0.0f;
    }
    __syncthreads();
#pragma unroll
    for (int r = 0; r < 4; ++r) {
        int nn = n0 + ty + 8 * r, kk = k0 + tx;
        if (nn < N) {
            float x = tile[tx * 33 + ty + 8 * r];
            unsigned short h = f2bf(x);
            hi[(size_t)nn * K + kk] = h;
            lo[(size_t)nn * K + kk] = f2bf(x - bf2f(h));
        }
    }
}

// ---------------------------------------------------------------------------
// prep_all: ONE launch for all P0 data-independent prep (was 9 launches).
// Flat block index partitioned by task; branch is block-uniform. 256thr 1-D.
// ---------------------------------------------------------------------------
__global__ __launch_bounds__(256) void prep_all(
    const float* __restrict__ hs,
    unsigned short* __restrict__ hsbh, unsigned short* __restrict__ hsbl,
    unsigned short* __restrict__ hsh,
    const float* __restrict__ Wq, const float* __restrict__ Wv,
    const float* __restrict__ Wgate, const float* __restrict__ Wg1,
    const float* __restrict__ Wg2,
    const float* __restrict__ Wk, const float* __restrict__ Wb,
    const float* __restrict__ Wa,
    unsigned short* __restrict__ WTAfh, unsigned short* __restrict__ WG2h,
    unsigned short* __restrict__ WTBh, unsigned short* __restrict__ WTBl)
{
    __shared__ float tile[32 * 33];
    const int bx = blockIdx.x, tid = threadIdx.x;

    if (bx < 3072) {
        const int i = bx * 256 + tid;
        float4 x = ((const float4*)hs)[i];
        ushort4 h, l, f;
        h.x = f2bf(x.x); l.x = f2bf(x.x - bf2f(h.x)); f.x = f2h(x.x);
        h.y = f2bf(x.y); l.y = f2bf(x.y - bf2f(h.y)); f.y = f2h(x.y);
        h.z = f2bf(x.z); l.z = f2bf(x.z - bf2f(h.z)); f.z = f2h(x.z);
        h.w = f2bf(x.w); l.w = f2bf(x.w - bf2f(h.w)); f.w = f2h(x.w);
        ((ushort4*)hsbh)[i] = h;
        ((ushort4*)hsbl)[i] = l;
        ((ushort4*)hsh)[i]  = f;
    } else if (bx < 5376) {
        const int t = bx - 3072;
        tch_body(Wq, WTAfh, 1536, 1536, t % 48, t / 48, tid, tile);
    } else if (bx < 7680) {
        const int t = bx - 5376;
        tch_body(Wv, WTAfh + 1536 * 1536, 1536, 1536, t % 48, t / 48, tid, tile);
    } else if (bx < 9984) {
        const int t = bx - 7680;
        tch_body(Wgate, WTAfh + 3072 * 1536, 1536, 1536, t % 48, t / 48, tid, tile);
    } else if (bx < 10272) {
        const int t = bx - 9984;
        tch_body(Wg1, WTAfh + 4608 * 1536, 1536, 192, t % 6, t / 6, tid, tile);
    } else if (bx < 11424) {
        const int t = bx - 10272;
        tch_body(Wg2, WG2h, 192, 6144, t % 192, t / 192, tid, tile);
    } else if (bx < 13728) {
        const int t = bx - 11424;
        tsp_body(Wk, WTBh, WTBl, 1536, 1536, t % 48, t / 48, tid, tile);
    } else if (bx < 13776) {
        const int t = bx - 13728;
        tsp_body(Wb, WTBh + 1536 * 1536, WTBl + 1536 * 1536, 1536, 12, 0, t, tid, tile);
    } else {
        const int t = bx - 13776;
        tsp_body(Wa, WTBh + 1548 * 1536, WTBl + 1548 * 1536, 1536, 12, 0, t, tid, tile);
    }
}

// ---------------------------------------------------------------------------
// transpose + split (standalone — used for Wo, which must wait until q is
// dead because WoTh overlays it).  ROUND-9 FIX: compute a FLAT tid so the
// body is correct regardless of block shape (the NaN failure was tsp_body
// receiving threadIdx.x from a dim3(32,8) launch: ty = tid>>5 was always 0,
// leaving 3/4 of WoTh/WoTl as stale garbage -> NaN in the output GEMM).
// Launched with 256x1 threads below.
// ---------------------------------------------------------------------------
__global__ __launch_bounds__(256) void transsplit_kernel(const float* __restrict__ src,
                                                         unsigned short* __restrict__ hi,
                                                         unsigned short* __restrict__ lo,
                                                         int K, int N) {
    __shared__ float tile[32 * 33];
    const int tid = (int)(threadIdx.y * blockDim.x + threadIdx.x);
    tsp_body(src, hi, lo, K, N, blockIdx.x, blockIdx.y, tid, tile);
}

// ---------------------------------------------------------------------------
// MFMA GEMM template (used only for the final output GEMM: EPI 0, MODE 1).
// ---------------------------------------------------------------------------
template<int EPI, int MODE>
__global__ __launch_bounds__(256)
void mgemm(const unsigned short* __restrict__ Ah, const unsigned short* __restrict__ Al,
           const unsigned short* __restrict__ Bh, const unsigned short* __restrict__ Bl,
           int K, int N, float* __restrict__ C, unsigned short* __restrict__ Cb)
{
    constexpr int BN   = MODE ? 64 : 128;
    constexpr int BCH  = BN / 16;
    constexpr int NFR  = MODE ? 2 : 4;
    __shared__ unsigned short AsH[2][4096];
    __shared__ unsigned short BsH[2][BCH * 512];
    __shared__ unsigned short AsL[MODE ? 2 : 1][MODE ? 4096 : 4];
    __shared__ unsigned short BsL[MODE ? 2 : 1][MODE ? BCH * 512 : 4];
    const int tid = threadIdx.x;
    const int wave = tid >> 6, lane = tid & 63;
    const int wr = wave >> 1, wc = wave & 1;
    const int lm = lane & 15, lq = lane >> 4;
    const int rowBase = blockIdx.y * 128, colBase = blockIdx.x * BN;

    floatx4 acc[4][NFR];
#pragma unroll
    for (int i = 0; i < 4; ++i)
#pragma unroll
        for (int j = 0; j < NFR; ++j) acc[i][j] = (floatx4){0.f, 0.f, 0.f, 0.f};

    const int mt0 = wave * 2, mt1 = wave * 2 + 1;
    const size_t aOff0 = (size_t)(rowBase + mt0 * 16 + lm) * K + lq * 8;
    const size_t aOff1 = (size_t)(rowBase + mt1 * 16 + lm) * K + lq * 8;
    const size_t bOff0 = (size_t)(colBase + mt0 * 16 + lm) * K + lq * 8;
    const size_t bOff1 = (size_t)(colBase + mt1 * 16 + lm) * K + lq * 8;
    const size_t bOffW = (size_t)(colBase + wave * 16 + lm) * K + lq * 8;

    auto STAGE = [&](int buf, int k0) {
        gl_lds16(Ah + aOff0 + k0, &AsH[buf][mt0 * 512]);
        gl_lds16(Ah + aOff1 + k0, &AsH[buf][mt1 * 512]);
        if (MODE) {
            gl_lds16(Al + aOff0 + k0, &AsL[buf][mt0 * 512]);
            gl_lds16(Al + aOff1 + k0, &AsL[buf][mt1 * 512]);
            gl_lds16(Bh + bOffW + k0, &BsH[buf][wave * 512]);
            gl_lds16(Bl + bOffW + k0, &BsL[buf][wave * 512]);
        } else {
            gl_lds16(Bh + bOff0 + k0, &BsH[buf][mt0 * 512]);
            gl_lds16(Bh + bOff1 + k0, &BsH[buf][mt1 * 512]);
        }
    };

    const int nIter = K >> 5;
    STAGE(0, 0);
    __syncthreads();
    int cur = 0;
    for (int it = 0; it < nIter; ++it) {
        if (it + 1 < nIter) STAGE(cur ^ 1, (it + 1) << 5);
        if (MODE == 0) {
            fp16x8 a[4], b[4];
#pragma unroll
            for (int i = 0; i < 4; ++i) {
                a[i] = *(const fp16x8*)&AsH[cur][(wr * 4 + i) * 512 + lane * 8];
                b[i] = *(const fp16x8*)&BsH[cur][(wc * 4 + i) * 512 + lane * 8];
            }
#pragma unroll
            for (int mi = 0; mi < 4; ++mi)
#pragma unroll
                for (int ni = 0; ni < 4; ++ni)
                    acc[mi][ni] = __builtin_amdgcn_mfma_f32_16x16x32_f16(
                        a[mi], b[ni], acc[mi][ni], 0, 0, 0);
        } else {
            bf16x8 ah[4], al[4], bh[2], bl[2];
#pragma unroll
            for (int i = 0; i < 4; ++i) {
                ah[i] = *(const bf16x8*)&AsH[cur][(wr * 4 + i) * 512 + lane * 8];
                al[i] = *(const bf16x8*)&AsL[cur][(wr * 4 + i) * 512 + lane * 8];
            }
#pragma unroll
            for (int j = 0; j < 2; ++j) {
                bh[j] = *(const bf16x8*)&BsH[cur][(wc * 2 + j) * 512 + lane * 8];
                bl[j] = *(const bf16x8*)&BsL[cur][(wc * 2 + j) * 512 + lane * 8];
            }
#pragma unroll
            for (int mi = 0; mi < 4; ++mi)
#pragma unroll
                for (int ni = 0; ni < 2; ++ni) {
                    acc[mi][ni] = __builtin_amdgcn_mfma_f32_16x16x32_bf16(
                        ah[mi], bh[ni], acc[mi][ni], 0, 0, 0);
                    acc[mi][ni] = __builtin_amdgcn_mfma_f32_16x16x32_bf16(
                        al[mi], bh[ni], acc[mi][ni], 0, 0, 0);
                    acc[mi][ni] = __builtin_amdgcn_mfma_f32_16x16x32_bf16(
                        ah[mi], bl[ni], acc[mi][ni], 0, 0, 0);
                }
        }
        __syncthreads();
        cur ^= 1;
    }

#pragma unroll
    for (int mi = 0; mi < 4; ++mi)
#pragma unroll
        for (int ni = 0; ni < NFR; ++ni) {
            const int col = colBase + wc * (NFR * 16) + ni * 16 + lm;
#pragma unroll
            for (int r = 0; r < 4; ++r) {
                const int row = rowBase + wr * 64 + mi * 16 + lq * 4 + r;
                const float x = acc[mi][ni][r];
                if (EPI == 0) C[(size_t)row * N + col] = x;
                else          Cb[(size_t)row * N + col] = f2bf(x);
            }
        }
}

// ---------------------------------------------------------------------------
// FUSED GEMM A+B with inline beta/g epilogue (rounds 7/8).
// ---------------------------------------------------------------------------
__global__ __launch_bounds__(256)
void mgemm_ab(const unsigned short* __restrict__ Ah0, const unsigned short* __restrict__ Bh0,
              const unsigned short* __restrict__ Ah1, const unsigned short* __restrict__ Al1,
              const unsigned short* __restrict__ Bh1, const unsigned short* __restrict__ Bl1,
              float* __restrict__ qf, float* __restrict__ vf,
              unsigned short* __restrict__ gsilb, unsigned short* __restrict__ w1h16,
              float* __restrict__ kf,
              const float* __restrict__ A_log, const float* __restrict__ dt_bias,
              float* __restrict__ beta, float* __restrict__ g)
{
    __shared__ unsigned short smem[24576];   // 48 KB union
    const int tid = threadIdx.x;
    const int wave = tid >> 6, lane = tid & 63;
    const int wr = wave >> 1, wc = wave & 1;
    const int lm = lane & 15, lq = lane >> 4;
    const int K = 1536;
    const int bx = blockIdx.x;

    bool roleA; int aidx = 0, bidx = 0;
    if (bx < 832) { roleA = ((bx & 1) == 0); aidx = bx >> 1; bidx = bx >> 1; }
    else          { roleA = true;            aidx = 416 + (bx - 832); }

    const int mt0 = wave * 2, mt1 = wave * 2 + 1;

    if (roleA) {
        const int rowBase = (aidx / 38) * 128, colBase = (aidx % 38) * 128;
        unsigned short* AsH = smem;
        unsigned short* BsH = smem + 8192;
        floatx4 acc[4][4];
#pragma unroll
        for (int i = 0; i < 4; ++i)
#pragma unroll
            for (int j = 0; j < 4; ++j) acc[i][j] = (floatx4){0.f, 0.f, 0.f, 0.f};

        const size_t aOff0 = (size_t)(rowBase + mt0 * 16 + lm) * K + lq * 8;
        const size_t aOff1 = (size_t)(rowBase + mt1 * 16 + lm) * K + lq * 8;
        const size_t bOff0 = (size_t)(colBase + mt0 * 16 + lm) * K + lq * 8;
        const size_t bOff1 = (size_t)(colBase + mt1 * 16 + lm) * K + lq * 8;

        auto STAGE = [&](int buf, int k0) {
            gl_lds16(Ah0 + aOff0 + k0, &AsH[buf * 4096 + mt0 * 512]);
            gl_lds16(Ah0 + aOff1 + k0, &AsH[buf * 4096 + mt1 * 512]);
            gl_lds16(Bh0 + bOff0 + k0, &BsH[buf * 4096 + mt0 * 512]);
            gl_lds16(Bh0 + bOff1 + k0, &BsH[buf * 4096 + mt1 * 512]);
        };
        STAGE(0, 0);
        __syncthreads();
        int cur = 0;
        for (int it = 0; it < 48; ++it) {
            if (it + 1 < 48) STAGE(cur ^ 1, (it + 1) << 5);
            fp16x8 a[4], b[4];
#pragma unroll
            for (int i = 0; i < 4; ++i) {
                a[i] = *(const fp16x8*)&AsH[cur * 4096 + (wr * 4 + i) * 512 + lane * 8];
                b[i] = *(const fp16x8*)&BsH[cur * 4096 + (wc * 4 + i) * 512 + lane * 8];
            }
#pragma unroll
            for (int mi = 0; mi < 4; ++mi)
#pragma unroll
                for (int ni = 0; ni < 4; ++ni)
                    acc[mi][ni] = __builtin_amdgcn_mfma_f32_16x16x32_f16(
                        a[mi], b[ni], acc[mi][ni], 0, 0, 0);
            __syncthreads();
            cur ^= 1;
        }
#pragma unroll
        for (int mi = 0; mi < 4; ++mi)
#pragma unroll
            for (int ni = 0; ni < 4; ++ni) {
                const int col = colBase + wc * 64 + ni * 16 + lm;
#pragma unroll
                for (int r = 0; r < 4; ++r) {
                    const int row = rowBase + wr * 64 + mi * 16 + lq * 4 + r;
                    const float x = acc[mi][ni][r];
                    if (col < 1536)       qf[(size_t)row * 1536 + col] = siluf(x);
                    else if (col < 3072)  vf[(size_t)row * 1536 + col - 1536] = x;
                    else if (col < 4608)  gsilb[(size_t)row * 1536 + col - 3072] = f2bf(siluf(x));
                    else if (col < 4800)  w1h16[(size_t)row * 192 + col - 4608] = f2h(siluf(x));
                }
            }
    } else {
        const int rowBase = (bidx / 26) * 128, colBase = (bidx % 26) * 64;
        unsigned short* AsH = smem;
        unsigned short* AsL = smem + 8192;
        unsigned short* BsH = smem + 16384;
        unsigned short* BsL = smem + 20480;
        floatx4 acc[4][2];
#pragma unroll
        for (int i = 0; i < 4; ++i)
#pragma unroll
            for (int j = 0; j < 2; ++j) acc[i][j] = (floatx4){0.f, 0.f, 0.f, 0.f};

        const size_t aOff0 = (size_t)(rowBase + mt0 * 16 + lm) * K + lq * 8;
        const size_t aOff1 = (size_t)(rowBase + mt1 * 16 + lm) * K + lq * 8;
        const size_t bOffW = (size_t)(colBase + wave * 16 + lm) * K + lq * 8;

        auto STAGE = [&](int buf, int k0) {
            gl_lds16(Ah1 + aOff0 + k0, &AsH[buf * 4096 + mt0 * 512]);
            gl_lds16(Ah1 + aOff1 + k0, &AsH[buf * 4096 + mt1 * 512]);
            gl_lds16(Al1 + aOff0 + k0, &AsL[buf * 4096 + mt0 * 512]);
            gl_lds16(Al1 + aOff1 + k0, &AsL[buf * 4096 + mt1 * 512]);
            gl_lds16(Bh1 + bOffW + k0, &BsH[buf * 2048 + wave * 512]);
            gl_lds16(Bl1 + bOffW + k0, &BsL[buf * 2048 + wave * 512]);
        };
        STAGE(0, 0);
        __syncthreads();
        int cur = 0;
        for (int it = 0; it < 48; ++it) {
            if (it + 1 < 48) STAGE(cur ^ 1, (it + 1) << 5);
            bf16x8 ah[4], al[4], bh[2], bl[2];
#pragma unroll
            for (int i = 0; i < 4; ++i) {
                ah[i] = *(const bf16x8*)&AsH[cur * 4096 + (wr * 4 + i) * 512 + lane * 8];
                al[i] = *(const bf16x8*)&AsL[cur * 4096 + (wr * 4 + i) * 512 + lane * 8];
            }
#pragma unroll
            for (int j = 0; j < 2; ++j) {
                bh[j] = *(const bf16x8*)&BsH[cur * 2048 + (wc * 2 + j) * 512 + lane * 8];
                bl[j] = *(const bf16x8*)&BsL[cur * 2048 + (wc * 2 + j) * 512 + lane * 8];
            }
#pragma unroll
            for (int mi = 0; mi < 4; ++mi)
#pragma unroll
                for (int ni = 0; ni < 2; ++ni) {
                    acc[mi][ni] = __builtin_amdgcn_mfma_f32_16x16x32_bf16(
                        ah[mi], bh[ni], acc[mi][ni], 0, 0, 0);
                    acc[mi][ni] = __builtin_amdgcn_mfma_f32_16x16x32_bf16(
                        al[mi], bh[ni], acc[mi][ni], 0, 0, 0);
                    acc[mi][ni] = __builtin_amdgcn_mfma_f32_16x16x32_bf16(
                        ah[mi], bl[ni], acc[mi][ni], 0, 0, 0);
                }
            __syncthreads();
            cur ^= 1;
        }
#pragma unroll
        for (int mi = 0; mi < 4; ++mi)
#pragma unroll
            for (int ni = 0; ni < 2; ++ni) {
                const int col = colBase + wc * 32 + ni * 16 + lm;
#pragma unroll
                for (int r = 0; r < 4; ++r) {
                    const int row = rowBase + wr * 64 + mi * 16 + lq * 4 + r;
                    const float x = acc[mi][ni][r];
                    if (col < 1536) {
                        kf[(size_t)row * 1536 + col] = siluf(x);
                    } else if (col < 1560) {
                        const int c2 = col - 1536;
                        if (c2 < 12) {
                            beta[row * NH + c2] = 1.0f / (1.0f + __expf(-x));
                        } else {
                            const int hh = c2 - 12;
                            const float y = x + dt_bias[hh];
                            const float sp = (y > 20.0f) ? y : log1pf(__expf(y));
                            g[row * NH + hh] = -__expf(A_log[hh]) * sp;
                        }
                    }
                }
            }
    }
}

// ---------------------------------------------------------------------------
// FUSED conv-weights GEMM + depthwise conv (round 8).  grid (48, 16).
// ---------------------------------------------------------------------------
__global__ __launch_bounds__(256)
void convgemm(const unsigned short* __restrict__ Ah, const unsigned short* __restrict__ Bh,
              const float* __restrict__ vpre, float* __restrict__ v)
{
    __shared__ unsigned short smem[16384];
    const int tid = threadIdx.x;
    const int wave = tid >> 6, lane = tid & 63;
    const int wr = wave >> 1, wc = wave & 1;
    const int lm = lane & 15, lq = lane >> 4;
    const int K = 192;
    const int rowBase = blockIdx.y * 128, colBase = blockIdx.x * 128;

    unsigned short* AsH = smem;
    unsigned short* BsH = smem + 8192;

    floatx4 acc[4][4];
#pragma unroll
    for (int i = 0; i < 4; ++i)
#pragma unroll
        for (int j = 0; j < 4; ++j) acc[i][j] = (floatx4){0.f, 0.f, 0.f, 0.f};

    const int mt0 = wave * 2, mt1 = wave * 2 + 1;
    const size_t aOff0 = (size_t)(rowBase + mt0 * 16 + lm) * K + lq * 8;
    const size_t aOff1 = (size_t)(rowBase + mt1 * 16 + lm) * K + lq * 8;
    const size_t bOff0 = (size_t)(colBase + mt0 * 16 + lm) * K + lq * 8;
    const size_t bOff1 = (size_t)(colBase + mt1 * 16 + lm) * K + lq * 8;

    auto STAGE = [&](int buf, int k0) {
        gl_lds16(Ah + aOff0 + k0, &AsH[buf * 4096 + mt0 * 512]);
        gl_lds16(Ah + aOff1 + k0, &AsH[buf * 4096 + mt1 * 512]);
        gl_lds16(Bh + bOff0 + k0, &BsH[buf * 4096 + mt0 * 512]);
        gl_lds16(Bh + bOff1 + k0, &BsH[buf * 4096 + mt1 * 512]);
    };

    const int nIter = 6;
    STAGE(0, 0);
    __syncthreads();
    int cur = 0;
    for (int it = 0; it < nIter; ++it) {
        if (it + 1 < nIter) STAGE(cur ^ 1, (it + 1) << 5);
        fp16x8 a[4], b[4];
#pragma unroll
        for (int i = 0; i < 4; ++i) {
            a[i] = *(const fp16x8*)&AsH[cur * 4096 + (wr * 4 + i) * 512 + lane * 8];
            b[i] = *(const fp16x8*)&BsH[cur * 4096 + (wc * 4 + i) * 512 + lane * 8];
        }
#pragma unroll
        for (int mi = 0; mi < 4; ++mi)
#pragma unroll
            for (int ni = 0; ni < 4; ++ni)
                acc[mi][ni] = __builtin_amdgcn_mfma_f32_16x16x32_f16(
                    a[mi], b[ni], acc[mi][ni], 0, 0, 0);
        __syncthreads();
        cur ^= 1;
    }

#pragma unroll
    for (int mi = 0; mi < 4; ++mi)
#pragma unroll
        for (int ni = 0; ni < 4; ++ni) {
            const int cl = wc * 64 + ni * 16 + lm;
#pragma unroll
            for (int r = 0; r < 4; ++r) {
                const int rl = wr * 64 + mi * 16 + lq * 4 + r;
                smem[rl * 128 + cl] = f2bf(acc[mi][ni][r]);
            }
        }
    __syncthreads();

    const int dB = blockIdx.x * 32;
#pragma unroll
    for (int e = 0; e < 16; ++e) {
        const int u = e * 256 + tid;
        const int tl = u >> 5, dd = u & 31;
        const int t = rowBase + tl, d = dB + dd;
        float a0 = 0.0f;
#pragma unroll
        for (int tap = 0; tap < CONVK; ++tap) {
            const int ts = t - (CONVK - 1) + tap;
            if (ts >= 0)
                a0 += vpre[(size_t)ts * HID + d] * bf2f(smem[tl * 128 + dd * 4 + tap]);
        }
        v[(size_t)t * HID + d] = siluf(a0);
    }
}

// ---------------------------------------------------------------------------
// D1: chunk-local WY precompute + fused tiled Q/K emission (round 8).
// ---------------------------------------------------------------------------
__global__ __launch_bounds__(256, 1) void chunkloc_kernel(
    const float* __restrict__ q, const float* __restrict__ k, const float* __restrict__ v,
    const float* __restrict__ g, const float* __restrict__ beta,
    float* __restrict__ X1g,
    unsigned short* __restrict__ X2th, unsigned short* __restrict__ X2tl,
    float* __restrict__ Mg, float* __restrict__ csg,
    unsigned short* __restrict__ Qth, unsigned short* __restrict__ Qtl,
    unsigned short* __restrict__ Kth, unsigned short* __restrict__ Ktl)
{
    __shared__ unsigned short KhS[64 * 136], KlS[64 * 136];
    __shared__ unsigned short QhS[64 * 136], QlS[64 * 136];
    __shared__ float KT[128 * 68];
    __shared__ float Vs[64 * 132];
    __shared__ float As[64 * 68];
    __shared__ float cs[64], sb[64], sbb[64];

    const int c = blockIdx.x, h = blockIdx.y;
    const int tid = threadIdx.x;
    const int wave = tid >> 6, lane = tid & 63;
    const int lm = lane & 15, lq = lane >> 4;
    const int li = tid >> 2, lq4 = tid & 3;
    const size_t rowbase = (size_t)(c * CH) * HID + h * DK;

    {
        const float* ksrc = k + rowbase + (size_t)li * HID + lq4 * 32;
        const float* qsrc = q + rowbase + (size_t)li * HID + lq4 * 32;
        const float* vsrc = v + (size_t)(c * CH + li) * HID + h * DV + lq4 * 32;
#pragma unroll
        for (int f = 0; f < 8; ++f) {
            float4 kx = *(const float4*)(ksrc + f * 4);
            float4 qx = *(const float4*)(qsrc + f * 4);
            float4 vx = *(const float4*)(vsrc + f * 4);
            const int d0 = lq4 * 32 + f * 4;
            {
                ushort4 hh, ll;
                hh.x = f2bf(kx.x); ll.x = f2bf(kx.x - bf2f(hh.x));
                hh.y = f2bf(kx.y); ll.y = f2bf(kx.y - bf2f(hh.y));
                hh.z = f2bf(kx.z); ll.z = f2bf(kx.z - bf2f(hh.z));
                hh.w = f2bf(kx.w); ll.w = f2bf(kx.w - bf2f(hh.w));
                *(ushort4*)&KhS[li * 136 + d0] = hh;
                *(ushort4*)&KlS[li * 136 + d0] = ll;
            }
            {
                ushort4 hh, ll;
                hh.x = f2bf(qx.x); ll.x = f2bf(qx.x - bf2f(hh.x));
                hh.y = f2bf(qx.y); ll.y = f2bf(qx.y - bf2f(hh.y));
                hh.z = f2bf(qx.z); ll.z = f2bf(qx.z - bf2f(hh.z));
                hh.w = f2bf(qx.w); ll.w = f2bf(qx.w - bf2f(hh.w));
                *(ushort4*)&QhS[li * 136 + d0] = hh;
                *(ushort4*)&QlS[li * 136 + d0] = ll;
            }
            KT[(d0 + 0) * 68 + li] = kx.x;
            KT[(d0 + 1) * 68 + li] = kx.y;
            KT[(d0 + 2) * 68 + li] = kx.z;
            KT[(d0 + 3) * 68 + li] = kx.w;
            *(float4*)&Vs[li * 132 + d0] = vx;
        }
    }
    if (tid < 64) {
        float gv = g[(c * CH + tid) * NH + h];
        float bv = beta[(c * CH + tid) * NH + h];
        float csv = gv;
#pragma unroll
        for (int off = 1; off < 64; off <<= 1) {
            float n = __shfl_up(csv, off);
            if (tid >= off) csv += n;
        }
        cs[tid] = csv; sb[tid] = bv; sbb[tid] = bv * __expf(csv);
    }
    __syncthreads();

    {
        const int ti = wave;
#pragma unroll
        for (int tj = 0; tj < 4; ++tj) {
            floatx4 acc = (floatx4){0.f, 0.f, 0.f, 0.f};
#pragma unroll
            for (int ks = 0; ks < 4; ++ks) {
                bf16x8 a_h = *(const bf16x8*)&KhS[(ti * 16 + lm) * 136 + ks * 32 + lq * 8];
                bf16x8 a_l = *(const bf16x8*)&KlS[(ti * 16 + lm) * 136 + ks * 32 + lq * 8];
                bf16x8 b_h = *(const bf16x8*)&KhS[(tj * 16 + lm) * 136 + ks * 32 + lq * 8];
                bf16x8 b_l = *(const bf16x8*)&KlS[(tj * 16 + lm) * 136 + ks * 32 + lq * 8];
                acc = __builtin_amdgcn_mfma_f32_16x16x32_bf16(a_h, b_h, acc, 0, 0, 0);
                acc = __builtin_amdgcn_mfma_f32_16x16x32_bf16(a_h, b_l, acc, 0, 0, 0);
                acc = __builtin_amdgcn_mfma_f32_16x16x32_bf16(a_l, b_h, acc, 0, 0, 0);
            }
#pragma unroll
            for (int r = 0; r < 4; ++r) {
                const int i = ti * 16 + lq * 4 + r, j = tj * 16 + lm;
                As[i * 68 + j] = (j < i) ? sb[i] * __expf(cs[i] - cs[j]) * acc[r] : 0.0f;
            }
        }
        const size_t mbase = (size_t)(h * NC + c) * CH * CH;
#pragma unroll
        for (int tj = 0; tj < 4; ++tj) {
            floatx4 acc = (floatx4){0.f, 0.f, 0.f, 0.f};
#pragma unroll
            for (int ks = 0; ks < 4; ++ks) {
                bf16x8 a_h = *(const bf16x8*)&QhS[(ti * 16 + lm) * 136 + ks * 32 + lq * 8];
                bf16x8 a_l = *(const bf16x8*)&QlS[(ti * 16 + lm) * 136 + ks * 32 + lq * 8];
                bf16x8 b_h = *(const bf16x8*)&KhS[(tj * 16 + lm) * 136 + ks * 32 + lq * 8];
                bf16x8 b_l = *(const bf16x8*)&KlS[(tj * 16 + lm) * 136 + ks * 32 + lq * 8];
                acc = __builtin_amdgcn_mfma_f32_16x16x32_bf16(a_h, b_h, acc, 0, 0, 0);
                acc = __builtin_amdgcn_mfma_f32_16x16x32_bf16(a_h, b_l, acc, 0, 0, 0);
                acc = __builtin_amdgcn_mfma_f32_16x16x32_bf16(a_l, b_h, acc, 0, 0, 0);
            }
#pragma unroll
            for (int r = 0; r < 4; ++r) {
                const int i = ti * 16 + lq * 4 + r, j = tj * 16 + lm;
                Mg[mbase + (size_t)i * 64 + j] =
                    (j <= i) ? __expf(cs[i] - cs[j]) * acc[r] : 0.0f;
            }
        }
    }

    float xc[64];
    const int col = tid;
    if (col < 128) {
#pragma unroll
        for (int i = 0; i < 64; ++i) xc[i] = sb[i] * Vs[i * 132 + col];
    } else {
        const int dcol = col - 128;
#pragma unroll
        for (int i4 = 0; i4 < 16; ++i4) {
            float4 kq = *(const float4*)&KT[dcol * 68 + i4 * 4];
            xc[i4 * 4 + 0] = sbb[i4 * 4 + 0] * kq.x;
            xc[i4 * 4 + 1] = sbb[i4 * 4 + 1] * kq.y;
            xc[i4 * 4 + 2] = sbb[i4 * 4 + 2] * kq.z;
            xc[i4 * 4 + 3] = sbb[i4 * 4 + 3] * kq.w;
        }
    }
    __syncthreads();

#pragma unroll
    for (int i = 1; i < 64; ++i) {
        float a = xc[i];
#pragma unroll
        for (int j4 = 0; j4 < (i + 3) / 4; ++j4) {
            float4 a4 = *(const float4*)&As[i * 68 + j4 * 4];
            a -= a4.x * xc[j4 * 4 + 0] + a4.y * xc[j4 * 4 + 1]
               + a4.z * xc[j4 * 4 + 2] + a4.w * xc[j4 * 4 + 3];
        }
        xc[i] = a;
    }

    {
        const size_t xbase = (size_t)(h * NC + c) * CH * 128;
        if (col < 128) {
            for (int i = 0; i < 64; ++i) X1g[xbase + (size_t)i * 128 + col] = xc[i];
        } else {
            for (int i = 0; i < 64; ++i) Vs[i * 132 + (col - 128)] = xc[i];
        }
    }
    if (tid < 64) csg[(size_t)(h * NC + c) * CH + tid] = cs[tid];
    __syncthreads();

    const size_t tb = (size_t)(h * NC + c) * 8192;

    {
#pragma unroll
        for (int e = 0; e < 4; ++e) {
            int u = e * 256 + tid;
            int ch = u >> 6, l = u & 63;
            int i = (ch >> 2) * 16 + (l & 15);
            int dbase = (ch & 3) * 32 + (l >> 4) * 8;
            float4 a = *(const float4*)&Vs[i * 132 + dbase];
            float4 b = *(const float4*)&Vs[i * 132 + dbase + 4];
            float xv[8] = {-a.x, -a.y, -a.z, -a.w, -b.x, -b.y, -b.z, -b.w};
            split8_store(xv, &X2th[tb + ch * 512 + l * 8], &X2tl[tb + ch * 512 + l * 8]);
        }
    }
    {
#pragma unroll
        for (int e = 0; e < 4; ++e) {
            int u = e * 256 + tid;
            int ch = u >> 6, l = u & 63;
            int i = (ch >> 2) * 16 + (l & 15);
            int dbase = (ch & 3) * 32 + (l >> 4) * 8;
            *(bf16x8*)&Qth[tb + ch * 512 + l * 8] = *(const bf16x8*)&QhS[i * 136 + dbase];
            *(bf16x8*)&Qtl[tb + ch * 512 + l * 8] = *(const bf16x8*)&QlS[i * 136 + dbase];
        }
    }
    {
#pragma unroll
        for (int e = 0; e < 4; ++e) {
            int u = e * 256 + tid;
            int ch = u >> 6, l = u & 63;
            int dk = (ch >> 1) * 16 + (l & 15);
            int ibase = (ch & 1) * 32 + (l >> 4) * 8;
            float4 a = *(const float4*)&KT[dk * 68 + ibase];
            float4 b = *(const float4*)&KT[dk * 68 + ibase + 4];
            float xv[8] = {a.x, a.y, a.z, a.w, b.x, b.y, b.z, b.w};
            split8_store(xv, &Kth[tb + ch * 512 + l * 8], &Ktl[tb + ch * 512 + l * 8]);
        }
    }
}

// ---------------------------------------------------------------------------
// D2 support + kernel (rounds 4-8, unchanged).
// ---------------------------------------------------------------------------
struct StFrags {
    bf16x8 xh[4], xl[4], qh[4], ql[4], kh[4], kl[4];
    float x1r[4], csr[4], cs63;
};

__device__ __forceinline__ void st_load(
    StFrags& f,
    const unsigned short* __restrict__ Qth, const unsigned short* __restrict__ Qtl,
    const unsigned short* __restrict__ Kth, const unsigned short* __restrict__ Ktl,
    const unsigned short* __restrict__ X2th, const unsigned short* __restrict__ X2tl,
    const float* __restrict__ X1g, const float* __restrict__ csg,
    int h, int c, int db, int mw, int lane, int lq, int lm)
{
    const size_t hc = (size_t)(h * NC + c);
    const size_t xb = hc * CH * 128;
    const size_t tb = hc * 8192 + (size_t)lane * 8;
#pragma unroll
    for (int ks = 0; ks < 4; ++ks) {
        const size_t off = tb + (size_t)(mw * 4 + ks) * 512;
        f.xh[ks] = *(const bf16x8*)(X2th + off);
        f.xl[ks] = *(const bf16x8*)(X2tl + off);
        f.qh[ks] = *(const bf16x8*)(Qth + off);
        f.ql[ks] = *(const bf16x8*)(Qtl + off);
        f.kh[ks] = *(const bf16x8*)(Kth + off);
        f.kl[ks] = *(const bf16x8*)(Ktl + off);
    }
#pragma unroll
    for (int r = 0; r < 4; ++r) {
        const int row = mw * 16 + lq * 4 + r;
        f.x1r[r] = X1g[xb + (size_t)row * 128 + db * 16 + lm];
        f.csr[r] = csg[hc * CH + row];
    }
    f.cs63 = csg[hc * CH + 63];
}

__device__ __forceinline__ void st_compute(
    const StFrags& f, floatx4& st0, floatx4& st1,
    unsigned short* SBh, unsigned short* SBl,
    unsigned short* UBh, unsigned short* UBl,
    float* __restrict__ X1g, float* __restrict__ o,
    int h, int c, int db, int mw, int lane, int lq, int lm)
{
    const size_t hc = (size_t)(h * NC + c);
    const size_t xb = hc * CH * 128;

    {
        floatx4 aU0 = (floatx4){0.f, 0.f, 0.f, 0.f};
        floatx4 aU1 = (floatx4){0.f, 0.f, 0.f, 0.f};
        floatx4 aO0 = (floatx4){0.f, 0.f, 0.f, 0.f};
        floatx4 aO1 = (floatx4){0.f, 0.f, 0.f, 0.f};
#pragma unroll
        for (int ks = 0; ks < 4; ++ks) {
            bf16x8 sh = *(const bf16x8*)&SBh[lm * 136 + ks * 32 + lq * 8];
            bf16x8 sl = *(const bf16x8*)&SBl[lm * 136 + ks * 32 + lq * 8];
            if (ks & 1) {
                aU1 = __builtin_amdgcn_mfma_f32_16x16x32_bf16(f.xh[ks], sh, aU1, 0, 0, 0);
                aU1 = __builtin_amdgcn_mfma_f32_16x16x32_bf16(f.xh[ks], sl, aU1, 0, 0, 0);
                aU1 = __builtin_amdgcn_mfma_f32_16x16x32_bf16(f.xl[ks], sh, aU1, 0, 0, 0);
                aO1 = __builtin_amdgcn_mfma_f32_16x16x32_bf16(f.qh[ks], sh, aO1, 0, 0, 0);
                aO1 = __builtin_amdgcn_mfma_f32_16x16x32_bf16(f.qh[ks], sl, aO1, 0, 0, 0);
                aO1 = __builtin_amdgcn_mfma_f32_16x16x32_bf16(f.ql[ks], sh, aO1, 0, 0, 0);
            } else {
                aU0 = __builtin_amdgcn_mfma_f32_16x16x32_bf16(f.xh[ks], sh, aU0, 0, 0, 0);
                aU0 = __builtin_amdgcn_mfma_f32_16x16x32_bf16(f.xh[ks], sl, aU0, 0, 0, 0);
                aU0 = __builtin_amdgcn_mfma_f32_16x16x32_bf16(f.xl[ks], sh, aU0, 0, 0, 0);
                aO0 = __builtin_amdgcn_mfma_f32_16x16x32_bf16(f.qh[ks], sh, aO0, 0, 0, 0);
                aO0 = __builtin_amdgcn_mfma_f32_16x16x32_bf16(f.qh[ks], sl, aO0, 0, 0, 0);
                aO0 = __builtin_amdgcn_mfma_f32_16x16x32_bf16(f.ql[ks], sh, aO0, 0, 0, 0);
            }
        }
#pragma unroll
        for (int r = 0; r < 4; ++r) {
            const int row = mw * 16 + lq * 4 + r;
            const float u = aU0[r] + aU1[r] + f.x1r[r];
            X1g[xb + (size_t)row * 128 + db * 16 + lm] = u;
            const float up = u * __expf(f.cs63 - f.csr[r]);
            unsigned short uh = f2bf(up);
            UBh[lm * 72 + row] = uh;
            UBl[lm * 72 + row] = f2bf(up - bf2f(uh));
            o[(size_t)(c * CH + row) * HID + h * DV + db * 16 + lm] =
                __expf(f.csr[r]) * (aO0[r] + aO1[r]);
        }
    }
    __syncthreads();

    {
        const float bC = __expf(f.cs63);
#pragma unroll
        for (int mt2 = 0; mt2 < 2; ++mt2) {
            const int mt = mw * 2 + mt2;
            floatx4 acc;
            floatx4 stc = mt2 ? st1 : st0;
#pragma unroll
            for (int r = 0; r < 4; ++r) acc[r] = bC * stc[r];
#pragma unroll
            for (int ks = 0; ks < 2; ++ks) {
                bf16x8 ah = f.kh[mt2 * 2 + ks];
                bf16x8 al = f.kl[mt2 * 2 + ks];
                bf16x8 bh = *(const bf16x8*)&UBh[lm * 72 + ks * 32 + lq * 8];
                bf16x8 bl = *(const bf16x8*)&UBl[lm * 72 + ks * 32 + lq * 8];
                acc = __builtin_amdgcn_mfma_f32_16x16x32_bf16(ah, bh, acc, 0, 0, 0);
                acc = __builtin_amdgcn_mfma_f32_16x16x32_bf16(ah, bl, acc, 0, 0, 0);
                acc = __builtin_amdgcn_mfma_f32_16x16x32_bf16(al, bh, acc, 0, 0, 0);
            }
            if (mt2) st1 = acc; else st0 = acc;
            ushort4 shv, slv;
#pragma unroll
            for (int r = 0; r < 4; ++r) {
                const float sv = acc[r];
                unsigned short sh = f2bf(sv);
                ((unsigned short*)&shv)[r] = sh;
                ((unsigned short*)&slv)[r] = f2bf(sv - bf2f(sh));
            }
            const int dkb = mt * 16 + lq * 4;
            *(ushort4*)&SBh[lm * 136 + dkb] = shv;
            *(ushort4*)&SBl[lm * 136 + dkb] = slv;
        }
    }
    __syncthreads();
}

__global__ __launch_bounds__(256, 1) void state_kernel(
    const unsigned short* __restrict__ Qth, const unsigned short* __restrict__ Qtl,
    const unsigned short* __restrict__ Kth, const unsigned short* __restrict__ Ktl,
    const unsigned short* __restrict__ X2th, const unsigned short* __restrict__ X2tl,
    float* __restrict__ X1g, const float* __restrict__ csg, float* __restrict__ o)
{
    __shared__ unsigned short SBh[16 * 136], SBl[16 * 136];
    __shared__ unsigned short UBh[16 * 72],  UBl[16 * 72];

    const int h = blockIdx.x, db = blockIdx.y;
    const int tid = threadIdx.x;
    const int mw = tid >> 6, lane = tid & 63;
    const int lm = lane & 15, lq = lane >> 4;

    for (int idx = tid; idx < 16 * 136; idx += 256) { SBh[idx] = 0; SBl[idx] = 0; }
    floatx4 st0 = (floatx4){0.f, 0.f, 0.f, 0.f};
    floatx4 st1 = (floatx4){0.f, 0.f, 0.f, 0.f};
    __syncthreads();

    StFrags fA, fB;
    st_load(fA, Qth, Qtl, Kth, Ktl, X2th, X2tl, X1g, csg, h, 0, db, mw, lane, lq, lm);
    for (int c = 0; c < NC; c += 2) {
        st_load(fB, Qth, Qtl, Kth, Ktl, X2th, X2tl, X1g, csg, h, c + 1, db, mw, lane, lq, lm);
        __builtin_amdgcn_sched_barrier(0);
        st_compute(fA, st0, st1, SBh, SBl, UBh, UBl, X1g, o, h, c, db, mw, lane, lq, lm);
        if (c + 2 < NC)
            st_load(fA, Qth, Qtl, Kth, Ktl, X2th, X2tl, X1g, csg, h, c + 2, db, mw, lane, lq, lm);
        __builtin_amdgcn_sched_barrier(0);
        st_compute(fB, st0, st1, SBh, SBl, UBh, UBl, X1g, o, h, c + 1, db, mw, lane, lq, lm);
    }
}

// ---------------------------------------------------------------------------
// D3 + gated RMSNorm FUSED (round 8): one block per (c,h), full 64x128 tile
// in LDS, RMS+gate applied, writes onh/onl directly.  grid (NC, NH).
// ---------------------------------------------------------------------------
__global__ __launch_bounds__(256) void outknorm_kernel(
    const float* __restrict__ Ug, const float* __restrict__ Mg,
    const float* __restrict__ o /* prev from state */,
    const unsigned short* __restrict__ gsil, const float* __restrict__ nw,
    unsigned short* __restrict__ out_hi, unsigned short* __restrict__ out_lo)
{
    __shared__ float Msh[64 * 68];
    __shared__ float Ush[64 * 132];
    __shared__ float rsq[64];

    const int c = blockIdx.x, h = blockIdx.y;
    const int tid = threadIdx.x;
    const size_t hc = (size_t)(h * NC + c);

    for (int e = 0; e < 16; ++e) {
        int idx = e * 256 + tid;
        Msh[(idx >> 6) * 68 + (idx & 63)] = Mg[hc * CH * CH + idx];
    }
    for (int e = 0; e < 32; ++e) {
        int idx = e * 256 + tid;
        int j = idx >> 7, cc = idx & 127;
        Ush[j * 132 + cc] = Ug[hc * CH * 128 + (size_t)j * 128 + cc];
    }
    __syncthreads();

    const int tx = tid & 15, ty = tid >> 4;
    const int c0 = tx * 8, i0 = ty * 4;
    float acc[4][8] = {{0}};
    for (int j4 = 0; j4 < 16; ++j4) {
        float uv[4][8];
#pragma unroll
        for (int s = 0; s < 4; ++s) {
            float4 u4a = *(const float4*)&Ush[(j4 * 4 + s) * 132 + c0];
            float4 u4b = *(const float4*)&Ush[(j4 * 4 + s) * 132 + c0 + 4];
            uv[s][0] = u4a.x; uv[s][1] = u4a.y; uv[s][2] = u4a.z; uv[s][3] = u4a.w;
            uv[s][4] = u4b.x; uv[s][5] = u4b.y; uv[s][6] = u4b.z; uv[s][7] = u4b.w;
        }
#pragma unroll
        for (int r = 0; r < 4; ++r) {
            float4 m4 = *(const float4*)&Msh[(i0 + r) * 68 + j4 * 4];
            const float mv[4] = {m4.x, m4.y, m4.z, m4.w};
#pragma unroll
            for (int s = 0; s < 4; ++s)
#pragma unroll
                for (int e = 0; e < 8; ++e) acc[r][e] += mv[s] * uv[s][e];
        }
    }
    __syncthreads();   // all Ush reads done before overwrite

    const float scale = 0.08838834764831845f;
#pragma unroll
    for (int r = 0; r < 4; ++r) {
        const float* op = &o[(size_t)(c * CH + i0 + r) * HID + h * DV + c0];
        float4 p0 = *(const float4*)op;
        float4 p1 = *(const float4*)(op + 4);
        const float pv[8] = {p0.x, p0.y, p0.z, p0.w, p1.x, p1.y, p1.z, p1.w};
#pragma unroll
        for (int e = 0; e < 8; ++e)
            Ush[(i0 + r) * 132 + c0 + e] = scale * (pv[e] + acc[r][e]);
    }
    __syncthreads();   // final o-tile resident in Ush

    // per-row RMS: 4 lanes/row, 32 cols each, 2-level shfl reduce
    {
        const int row = tid >> 2, sub = tid & 3;
        float ss = 0.0f;
#pragma unroll
        for (int k2 = 0; k2 < 32; ++k2) {
            float x = Ush[row * 132 + sub * 32 + k2];
            ss += x * x;
        }
        ss += __shfl_xor(ss, 1);
        ss += __shfl_xor(ss, 2);
        if (sub == 0) rsq[row] = rsqrtf(ss * (1.0f / 128.0f) + 1e-5f);
    }
    __syncthreads();

    // coalesced gate+norm+split write
    for (int e = 0; e < 32; ++e) {
        int idx = e * 256 + tid;
        int j = idx >> 7, cc = idx & 127;
        const size_t base = (size_t)(c * CH + j) * HID + h * DV;
        float va = Ush[j * 132 + cc] * rsq[j] * nw[cc] * bf2f(gsil[base + cc]);
        unsigned short ha = f2bf(va);
        out_hi[base + cc] = ha;
        out_lo[base + cc] = f2bf(va - bf2f(ha));
    }
}

// ---------------------------------------------------------------------------
extern "C" void kernel_launch(void* const* d_in, const int* in_sizes, int n_in,
                              void* d_out, int out_size, void* d_ws, size_t ws_size,
                              hipStream_t stream) {
    const float* hs      = (const float*)d_in[0];
    const float* Wq      = (const float*)d_in[1];
    const float* Wk      = (const float*)d_in[2];
    const float* Wv      = (const float*)d_in[3];
    const float* Wb      = (const float*)d_in[4];
    const float* Wa      = (const float*)d_in[5];
    const float* A_log   = (const float*)d_in[6];
    const float* dt_bias = (const float*)d_in[7];
    const float* Wg1     = (const float*)d_in[8];
    const float* Wg2     = (const float*)d_in[9];
    const float* Wgate   = (const float*)d_in[10];
    const float* norm_w  = (const float*)d_in[11];
    const float* Wo      = (const float*)d_in[12];

    float* ws = (float*)d_ws;
    float* q    = ws;                                        // later WoTh/WoTl
    float* kbuf = ws + 3145728;
    float* vpre = ws + 6291456;                              // later Qt, then onh/onl
    float* vbuf = ws + 9437184;                              // early hsbh/hsbl; then v / o
    unsigned short* gsil = (unsigned short*)(ws + 12582912);
    float* X1g  = ws + 14155776;                             // fp32, becomes U
    unsigned short* X2th = (unsigned short*)(ws + 17301504);
    unsigned short* X2tl = (unsigned short*)(ws + 18874368);
    float* Mg   = ws + 20447232;
    unsigned short* WTAfh = (unsigned short*)(ws + 14155776);
    unsigned short* WTBh  = (unsigned short*)(ws + 17891328);
    unsigned short* WTBl  = (unsigned short*)(ws + 19169280);
    unsigned short* WG2h  = (unsigned short*)(ws + 22044672);
    unsigned short* hsh   = (unsigned short*)(ws + 22634496);
    unsigned short* w1h16 = (unsigned short*)(ws + 24207360);
    unsigned short* Kth = (unsigned short*)(ws + 22044672);
    unsigned short* Ktl = (unsigned short*)(ws + 23617536);
    float* beta  = ws + 25190400;
    float* g     = ws + 25214976;
    float* csg   = ws + 25239552;
    unsigned short* hsbh = (unsigned short*)(ws + 9437184);
    unsigned short* hsbl = (unsigned short*)(ws + 11010048);
    unsigned short* Qth  = (unsigned short*)(ws + 6291456);
    unsigned short* Qtl  = (unsigned short*)(ws + 7864320);
    unsigned short* WoTh = (unsigned short*)(ws);
    unsigned short* WoTl = (unsigned short*)(ws + 1179648);
    unsigned short* onh  = (unsigned short*)(ws + 6291456);
    unsigned short* onl  = (unsigned short*)(ws + 7864320);

    const dim3 blk(256);

    // P0: all independent prep in ONE launch (was 9)
    prep_all<<<13824, blk, 0, stream>>>(hs, hsbh, hsbl, hsh,
                                        Wq, Wv, Wgate, Wg1, Wg2, Wk, Wb, Wa,
                                        WTAfh, WG2h, WTBh, WTBl);

    // P1: fused GEMM-A + GEMM-B (+ inline beta/g epilogue)
    mgemm_ab<<<1024, blk, 0, stream>>>(hsh, WTAfh, hsbh, hsbl, WTBh, WTBl,
                                       q, vpre, gsil, w1h16, kbuf,
                                       A_log, dt_bias, beta, g);

    // P2: conv weights GEMM with fused depthwise conv epilogue
    convgemm<<<dim3(48, 16), blk, 0, stream>>>(w1h16, WG2h, vpre, vbuf);

    // P3: chunked delta rule
    chunkloc_kernel<<<dim3(NC, NH), blk, 0, stream>>>(q, kbuf, vbuf, g, beta,
                                                      X1g, X2th, X2tl, Mg, csg,
                                                      Qth, Qtl, Kth, Ktl);
    state_kernel<<<dim3(NH, 8), blk, 0, stream>>>(Qth, Qtl, Kth, Ktl, X2th, X2tl,
                                                  X1g, csg, vbuf);
    // Wo transpose+split — FLAT 256-thread launch (round-9 NaN fix)
    transsplit_kernel<<<dim3(48, 48), blk, 0, stream>>>(Wo, WoTh, WoTl, 1536, 1536);

    // P4: fused outk + gated RMSNorm, then output GEMM
    outknorm_kernel<<<dim3(NC, NH), blk, 0, stream>>>(X1g, Mg, vbuf, gsil, norm_w,
                                                      onh, onl);
    mgemm<0, 1><<<dim3(24, 16), blk, 0, stream>>>(onh, onl, WoTh, WoTl, 1536, 1536,
        (float*)d_out, nullptr);
}

// Round 11
// 498.719 us; speedup vs baseline: 1.1061x; 1.0674x over previous
//
#include <hip/hip_runtime.h>
#include <hip/hip_bf16.h>
#include <math.h>

#define T     2048
#define HID   1536
#define NH    12
#define DK    128
#define DV    128
#define CONVK 4
#define CH    64
#define NC    32

typedef __attribute__((ext_vector_type(8))) short bf16x8;
typedef __attribute__((ext_vector_type(8))) _Float16 fp16x8;
typedef __attribute__((ext_vector_type(4))) float floatx4;

__device__ __forceinline__ float siluf(float x) {
    return x / (1.0f + __expf(-x));
}
__device__ __forceinline__ unsigned short f2bf(float f) {
    union { __hip_bfloat16 b; unsigned short u; } cv;
    cv.b = __float2bfloat16(f);
    return cv.u;
}
__device__ __forceinline__ float bf2f(unsigned short u) {
    union { unsigned int u; float f; } cv;
    cv.u = ((unsigned int)u) << 16;
    return cv.f;
}
__device__ __forceinline__ unsigned short f2h(float f) {
    union { _Float16 h; unsigned short u; } cv;
    cv.h = (_Float16)f;
    return cv.u;
}
__device__ __forceinline__ void gl_lds16(const void* g, void* l) {
    __builtin_amdgcn_global_load_lds(
        (const __attribute__((address_space(1))) void*)g,
        (__attribute__((address_space(3))) void*)l, 16, 0, 0);
}
// split 8 fp32 -> hi/lo bf16, write as 2x ushort4 each
__device__ __forceinline__ void split8_store(const float* xv,
                                             unsigned short* dh, unsigned short* dl) {
    ushort4 h0, h1, l0, l1;
    h0.x = f2bf(xv[0]); l0.x = f2bf(xv[0] - bf2f(h0.x));
    h0.y = f2bf(xv[1]); l0.y = f2bf(xv[1] - bf2f(h0.y));
    h0.z = f2bf(xv[2]); l0.z = f2bf(xv[2] - bf2f(h0.z));
    h0.w = f2bf(xv[3]); l0.w = f2bf(xv[3] - bf2f(h0.w));
    h1.x = f2bf(xv[4]); l1.x = f2bf(xv[4] - bf2f(h1.x));
    h1.y = f2bf(xv[5]); l1.y = f2bf(xv[5] - bf2f(h1.y));
    h1.z = f2bf(xv[6]); l1.z = f2bf(xv[6] - bf2f(h1.z));
    h1.w = f2bf(xv[7]); l1.w = f2bf(xv[7] - bf2f(h1.w));
    *(ushort4*)dh = h0; *(ushort4*)(dh + 4) = h1;
    *(ushort4*)dl = l0; *(ushort4*)(dl + 4) = l1;
}

// ---------------------------------------------------------------------------
// device bodies for the fused prep kernel. REQUIRE a flat 256-thread tid.
// ---------------------------------------------------------------------------
__device__ __forceinline__ void tch_body(const float* __restrict__ src,
                                         unsigned short* __restrict__ dst,
                                         int K, int N, int gx, int gy, int tid,
                                         float* tile /*32*33*/) {
    const int tx = tid & 31, ty = tid >> 5;
    const int k0 = gy * 32, n0 = gx * 32;
#pragma unroll
    for (int r = 0; r < 4; ++r) {
        int kk = k0 + ty + 8 * r, nn = n0 + tx;
        tile[(ty + 8 * r) * 33 + tx] = (nn < N) ? src[(size_t)kk * N + nn] : 0.0f;
    }
    __syncthreads();
#pragma unroll
    for (int r = 0; r < 4; ++r) {
        int nn = n0 + ty + 8 * r, kk = k0 + tx;
        if (nn < N) dst[(size_t)nn * K + kk] = f2h(tile[tx * 33 + ty + 8 * r]);
    }
}
__device__ __forceinline__ void tsp_body(const float* __restrict__ src,
                                         unsigned short* __restrict__ hi,
                                         unsigned short* __restrict__ lo,
                                         int K, int N, int gx, int gy, int tid,
                                         float* tile) {
    const int tx = tid & 31, ty = tid >> 5;
    const int k0 = gy * 32, n0 = gx * 32;
#pragma unroll
    for (int r = 0; r < 4; ++r) {
        int kk = k0 + ty + 8 * r, nn = n0 + tx;
        tile[(ty + 8 * r) * 33 + tx] = (nn < N) ? src[(size_t)kk * N + nn] : 0.0f;
    }
    __syncthreads();
#pragma unroll
    for (int r = 0; r < 4; ++r) {
        int nn = n0 + ty + 8 * r, kk = k0 + tx;
        if (nn < N) {
            float x = tile[tx * 33 + ty + 8 * r];
            unsigned short h = f2bf(x);
            hi[(size_t)nn * K + kk] = h;
            lo[(size_t)nn * K + kk] = f2bf(x - bf2f(h));
        }
    }
}

// ---------------------------------------------------------------------------
// prep_all: ONE launch for all P0 data-independent prep.
// ---------------------------------------------------------------------------
__global__ __launch_bounds__(256) void prep_all(
    const float* __restrict__ hs,
    unsigned short* __restrict__ hsbh, unsigned short* __restrict__ hsbl,
    unsigned short* __restrict__ hsh,
    const float* __restrict__ Wq, const float* __restrict__ Wv,
    const float* __restrict__ Wgate, const float* __restrict__ Wg1,
    const float* __restrict__ Wg2,
    const float* __restrict__ Wk, const float* __restrict__ Wb,
    const float* __restrict__ Wa,
    unsigned short* __restrict__ WTAfh, unsigned short* __restrict__ WG2h,
    unsigned short* __restrict__ WTBh, unsigned short* __restrict__ WTBl)
{
    __shared__ float tile[32 * 33];
    const int bx = blockIdx.x, tid = threadIdx.x;

    if (bx < 3072) {
        const int i = bx * 256 + tid;
        float4 x = ((const float4*)hs)[i];
        ushort4 h, l, f;
        h.x = f2bf(x.x); l.x = f2bf(x.x - bf2f(h.x)); f.x = f2h(x.x);
        h.y = f2bf(x.y); l.y = f2bf(x.y - bf2f(h.y)); f.y = f2h(x.y);
        h.z = f2bf(x.z); l.z = f2bf(x.z - bf2f(h.z)); f.z = f2h(x.z);
        h.w = f2bf(x.w); l.w = f2bf(x.w - bf2f(h.w)); f.w = f2h(x.w);
        ((ushort4*)hsbh)[i] = h;
        ((ushort4*)hsbl)[i] = l;
        ((ushort4*)hsh)[i]  = f;
    } else if (bx < 5376) {
        const int t = bx - 3072;
        tch_body(Wq, WTAfh, 1536, 1536, t % 48, t / 48, tid, tile);
    } else if (bx < 7680) {
        const int t = bx - 5376;
        tch_body(Wv, WTAfh + 1536 * 1536, 1536, 1536, t % 48, t / 48, tid, tile);
    } else if (bx < 9984) {
        const int t = bx - 7680;
        tch_body(Wgate, WTAfh + 3072 * 1536, 1536, 1536, t % 48, t / 48, tid, tile);
    } else if (bx < 10272) {
        const int t = bx - 9984;
        tch_body(Wg1, WTAfh + 4608 * 1536, 1536, 192, t % 6, t / 6, tid, tile);
    } else if (bx < 11424) {
        const int t = bx - 10272;
        tch_body(Wg2, WG2h, 192, 6144, t % 192, t / 192, tid, tile);
    } else if (bx < 13728) {
        const int t = bx - 11424;
        tsp_body(Wk, WTBh, WTBl, 1536, 1536, t % 48, t / 48, tid, tile);
    } else if (bx < 13776) {
        const int t = bx - 13728;
        tsp_body(Wb, WTBh + 1536 * 1536, WTBl + 1536 * 1536, 1536, 12, 0, t, tid, tile);
    } else {
        const int t = bx - 13776;
        tsp_body(Wa, WTBh + 1548 * 1536, WTBl + 1548 * 1536, 1536, 12, 0, t, tid, tile);
    }
}

// ---------------------------------------------------------------------------
// standalone transpose+cast fp16 (for Wo -> WoTh; flat 256-thr launch).
// ---------------------------------------------------------------------------
__global__ __launch_bounds__(256) void transcasth_kernel(const float* __restrict__ src,
                                                         unsigned short* __restrict__ dst,
                                                         int K, int N) {
    __shared__ float tile[32 * 33];
    tch_body(src, dst, K, N, blockIdx.x, blockIdx.y, threadIdx.x, tile);
}

// ---------------------------------------------------------------------------
// FUSED GEMM A+B.  Round-11: A-role moves to BK=64 — rounds 1-6 established
// time ~ #K-steps (fixed ~1800cyc stall/step, no cross-block overlap), so
// halving the step count (48->24) is the remaining lever. LDS union 64KB
// (A: 2buf x [2 halves x 128x32] A + same B). B-role unchanged (BK=32).
// ---------------------------------------------------------------------------
__global__ __launch_bounds__(256)
void mgemm_ab(const unsigned short* __restrict__ Ah0, const unsigned short* __restrict__ Bh0,
              const unsigned short* __restrict__ Ah1, const unsigned short* __restrict__ Al1,
              const unsigned short* __restrict__ Bh1, const unsigned short* __restrict__ Bl1,
              float* __restrict__ qf, float* __restrict__ vf,
              unsigned short* __restrict__ gsilb, unsigned short* __restrict__ w1h16,
              float* __restrict__ kf,
              const float* __restrict__ A_log, const float* __restrict__ dt_bias,
              float* __restrict__ beta, float* __restrict__ g)
{
    __shared__ unsigned short smem[32768];   // 64 KB union
    const int tid = threadIdx.x;
    const int wave = tid >> 6, lane = tid & 63;
    const int wr = wave >> 1, wc = wave & 1;
    const int lm = lane & 15, lq = lane >> 4;
    const int K = 1536;
    const int bx = blockIdx.x;

    bool roleA; int aidx = 0, bidx = 0;
    if (bx < 832) { roleA = ((bx & 1) == 0); aidx = bx >> 1; bidx = bx >> 1; }
    else          { roleA = true;            aidx = 416 + (bx - 832); }

    const int mt0 = wave * 2, mt1 = wave * 2 + 1;

    if (roleA) {
        // ---- GEMM-A: fp16 128x128, BK=64 (24 steps).  grid map (38,16) ----
        const int rowBase = (aidx / 38) * 128, colBase = (aidx % 38) * 128;
        unsigned short* AsH = smem;           // [2][8192]: buf*8192 + half*4096 + mt*512
        unsigned short* BsH = smem + 16384;   // [2][8192]
        floatx4 acc[4][4];
#pragma unroll
        for (int i = 0; i < 4; ++i)
#pragma unroll
            for (int j = 0; j < 4; ++j) acc[i][j] = (floatx4){0.f, 0.f, 0.f, 0.f};

        const size_t aOff0 = (size_t)(rowBase + mt0 * 16 + lm) * K + lq * 8;
        const size_t aOff1 = (size_t)(rowBase + mt1 * 16 + lm) * K + lq * 8;
        const size_t bOff0 = (size_t)(colBase + mt0 * 16 + lm) * K + lq * 8;
        const size_t bOff1 = (size_t)(colBase + mt1 * 16 + lm) * K + lq * 8;

        auto STAGE = [&](int buf, int k0) {
            gl_lds16(Ah0 + aOff0 + k0,      &AsH[buf * 8192 + mt0 * 512]);
            gl_lds16(Ah0 + aOff1 + k0,      &AsH[buf * 8192 + mt1 * 512]);
            gl_lds16(Ah0 + aOff0 + k0 + 32, &AsH[buf * 8192 + 4096 + mt0 * 512]);
            gl_lds16(Ah0 + aOff1 + k0 + 32, &AsH[buf * 8192 + 4096 + mt1 * 512]);
            gl_lds16(Bh0 + bOff0 + k0,      &BsH[buf * 8192 + mt0 * 512]);
            gl_lds16(Bh0 + bOff1 + k0,      &BsH[buf * 8192 + mt1 * 512]);
            gl_lds16(Bh0 + bOff0 + k0 + 32, &BsH[buf * 8192 + 4096 + mt0 * 512]);
            gl_lds16(Bh0 + bOff1 + k0 + 32, &BsH[buf * 8192 + 4096 + mt1 * 512]);
        };
        STAGE(0, 0);
        __syncthreads();
        int cur = 0;
        for (int it = 0; it < 24; ++it) {
            if (it + 1 < 24) STAGE(cur ^ 1, (it + 1) << 6);
#pragma unroll
            for (int s = 0; s < 2; ++s) {
                fp16x8 a[4], b[4];
#pragma unroll
                for (int i = 0; i < 4; ++i) {
                    a[i] = *(const fp16x8*)&AsH[cur * 8192 + s * 4096 + (wr * 4 + i) * 512 + lane * 8];
                    b[i] = *(const fp16x8*)&BsH[cur * 8192 + s * 4096 + (wc * 4 + i) * 512 + lane * 8];
                }
#pragma unroll
                for (int mi = 0; mi < 4; ++mi)
#pragma unroll
                    for (int ni = 0; ni < 4; ++ni)
                        acc[mi][ni] = __builtin_amdgcn_mfma_f32_16x16x32_f16(
                            a[mi], b[ni], acc[mi][ni], 0, 0, 0);
            }
            __syncthreads();
            cur ^= 1;
        }
#pragma unroll
        for (int mi = 0; mi < 4; ++mi)
#pragma unroll
            for (int ni = 0; ni < 4; ++ni) {
                const int col = colBase + wc * 64 + ni * 16 + lm;
#pragma unroll
                for (int r = 0; r < 4; ++r) {
                    const int row = rowBase + wr * 64 + mi * 16 + lq * 4 + r;
                    const float x = acc[mi][ni][r];
                    if (col < 1536)       qf[(size_t)row * 1536 + col] = siluf(x);
                    else if (col < 3072)  vf[(size_t)row * 1536 + col - 1536] = x;
                    else if (col < 4608)  gsilb[(size_t)row * 1536 + col - 3072] = f2bf(siluf(x));
                    else if (col < 4800)  w1h16[(size_t)row * 192 + col - 4608] = f2h(siluf(x));
                }
            }
    } else {
        // ---- GEMM-B: 3-term bf16 128x64, BK=32 (48 steps).  grid (26,16) ----
        const int rowBase = (bidx / 26) * 128, colBase = (bidx % 26) * 64;
        unsigned short* AsH = smem;
        unsigned short* AsL = smem + 8192;
        unsigned short* BsH = smem + 16384;
        unsigned short* BsL = smem + 20480;
        floatx4 acc[4][2];
#pragma unroll
        for (int i = 0; i < 4; ++i)
#pragma unroll
            for (int j = 0; j < 2; ++j) acc[i][j] = (floatx4){0.f, 0.f, 0.f, 0.f};

        const size_t aOff0 = (size_t)(rowBase + mt0 * 16 + lm) * K + lq * 8;
        const size_t aOff1 = (size_t)(rowBase + mt1 * 16 + lm) * K + lq * 8;
        const size_t bOffW = (size_t)(colBase + wave * 16 + lm) * K + lq * 8;

        auto STAGE = [&](int buf, int k0) {
            gl_lds16(Ah1 + aOff0 + k0, &AsH[buf * 4096 + mt0 * 512]);
            gl_lds16(Ah1 + aOff1 + k0, &AsH[buf * 4096 + mt1 * 512]);
            gl_lds16(Al1 + aOff0 + k0, &AsL[buf * 4096 + mt0 * 512]);
            gl_lds16(Al1 + aOff1 + k0, &AsL[buf * 4096 + mt1 * 512]);
            gl_lds16(Bh1 + bOffW + k0, &BsH[buf * 2048 + wave * 512]);
            gl_lds16(Bl1 + bOffW + k0, &BsL[buf * 2048 + wave * 512]);
        };
        STAGE(0, 0);
        __syncthreads();
        int cur = 0;
        for (int it = 0; it < 48; ++it) {
            if (it + 1 < 48) STAGE(cur ^ 1, (it + 1) << 5);
            bf16x8 ah[4], al[4], bh[2], bl[2];
#pragma unroll
            for (int i = 0; i < 4; ++i) {
                ah[i] = *(const bf16x8*)&AsH[cur * 4096 + (wr * 4 + i) * 512 + lane * 8];
                al[i] = *(const bf16x8*)&AsL[cur * 4096 + (wr * 4 + i) * 512 + lane * 8];
            }
#pragma unroll
            for (int j = 0; j < 2; ++j) {
                bh[j] = *(const bf16x8*)&BsH[cur * 2048 + (wc * 2 + j) * 512 + lane * 8];
                bl[j] = *(const bf16x8*)&BsL[cur * 2048 + (wc * 2 + j) * 512 + lane * 8];
            }
#pragma unroll
            for (int mi = 0; mi < 4; ++mi)
#pragma unroll
                for (int ni = 0; ni < 2; ++ni) {
                    acc[mi][ni] = __builtin_amdgcn_mfma_f32_16x16x32_bf16(
                        ah[mi], bh[ni], acc[mi][ni], 0, 0, 0);
                    acc[mi][ni] = __builtin_amdgcn_mfma_f32_16x16x32_bf16(
                        al[mi], bh[ni], acc[mi][ni], 0, 0, 0);
                    acc[mi][ni] = __builtin_amdgcn_mfma_f32_16x16x32_bf16(
                        ah[mi], bl[ni], acc[mi][ni], 0, 0, 0);
                }
            __syncthreads();
            cur ^= 1;
        }
#pragma unroll
        for (int mi = 0; mi < 4; ++mi)
#pragma unroll
            for (int ni = 0; ni < 2; ++ni) {
                const int col = colBase + wc * 32 + ni * 16 + lm;
#pragma unroll
                for (int r = 0; r < 4; ++r) {
                    const int row = rowBase + wr * 64 + mi * 16 + lq * 4 + r;
                    const float x = acc[mi][ni][r];
                    if (col < 1536) {
                        kf[(size_t)row * 1536 + col] = siluf(x);
                    } else if (col < 1560) {
                        const int c2 = col - 1536;
                        if (c2 < 12) {
                            beta[row * NH + c2] = 1.0f / (1.0f + __expf(-x));
                        } else {
                            const int hh = c2 - 12;
                            const float y = x + dt_bias[hh];
                            const float sp = (y > 20.0f) ? y : log1pf(__expf(y));
                            g[row * NH + hh] = -__expf(A_log[hh]) * sp;
                        }
                    }
                }
            }
    }
}

// ---------------------------------------------------------------------------
// Final output GEMM: fp16 single-term, 128x64 tile, BK=64 (24 steps).
// onorm values are O(1) post-RMS; fp16 input quantization adds <1e-3 absmax
// (budget: 0.0176 current vs 0.0728 threshold).  A=onh (M x K fp16),
// B=WoTh (N x K fp16), C=d_out fp32.  grid (24, 16).
// ---------------------------------------------------------------------------
__global__ __launch_bounds__(256)
void fgemm(const unsigned short* __restrict__ Ah, const unsigned short* __restrict__ Bh,
           float* __restrict__ C)
{
    __shared__ unsigned short AsH[2][8192];   // buf, half*4096 + mt*512
    __shared__ unsigned short BsH[2][4096];   // buf, half*2048 + wv*512
    const int tid = threadIdx.x;
    const int wave = tid >> 6, lane = tid & 63;
    const int wr = wave >> 1, wc = wave & 1;
    const int lm = lane & 15, lq = lane >> 4;
    const int K = 1536;
    const int rowBase = blockIdx.y * 128, colBase = blockIdx.x * 64;

    floatx4 acc[4][2];
#pragma unroll
    for (int i = 0; i < 4; ++i)
#pragma unroll
        for (int j = 0; j < 2; ++j) acc[i][j] = (floatx4){0.f, 0.f, 0.f, 0.f};

    const int mt0 = wave * 2, mt1 = wave * 2 + 1;
    const size_t aOff0 = (size_t)(rowBase + mt0 * 16 + lm) * K + lq * 8;
    const size_t aOff1 = (size_t)(rowBase + mt1 * 16 + lm) * K + lq * 8;
    const size_t bOffW = (size_t)(colBase + wave * 16 + lm) * K + lq * 8;

    auto STAGE = [&](int buf, int k0) {
        gl_lds16(Ah + aOff0 + k0,      &AsH[buf][mt0 * 512]);
        gl_lds16(Ah + aOff1 + k0,      &AsH[buf][mt1 * 512]);
        gl_lds16(Ah + aOff0 + k0 + 32, &AsH[buf][4096 + mt0 * 512]);
        gl_lds16(Ah + aOff1 + k0 + 32, &AsH[buf][4096 + mt1 * 512]);
        gl_lds16(Bh + bOffW + k0,      &BsH[buf][wave * 512]);
        gl_lds16(Bh + bOffW + k0 + 32, &BsH[buf][2048 + wave * 512]);
    };

    STAGE(0, 0);
    __syncthreads();
    int cur = 0;
    for (int it = 0; it < 24; ++it) {
        if (it + 1 < 24) STAGE(cur ^ 1, (it + 1) << 6);
#pragma unroll
        for (int s = 0; s < 2; ++s) {
            fp16x8 a[4], b[2];
#pragma unroll
            for (int i = 0; i < 4; ++i)
                a[i] = *(const fp16x8*)&AsH[cur][s * 4096 + (wr * 4 + i) * 512 + lane * 8];
#pragma unroll
            for (int j = 0; j < 2; ++j)
                b[j] = *(const fp16x8*)&BsH[cur][s * 2048 + (wc * 2 + j) * 512 + lane * 8];
#pragma unroll
            for (int mi = 0; mi < 4; ++mi)
#pragma unroll
                for (int ni = 0; ni < 2; ++ni)
                    acc[mi][ni] = __builtin_amdgcn_mfma_f32_16x16x32_f16(
                        a[mi], b[ni], acc[mi][ni], 0, 0, 0);
        }
        __syncthreads();
        cur ^= 1;
    }

#pragma unroll
    for (int mi = 0; mi < 4; ++mi)
#pragma unroll
        for (int ni = 0; ni < 2; ++ni) {
            const int col = colBase + wc * 32 + ni * 16 + lm;
#pragma unroll
            for (int r = 0; r < 4; ++r) {
                const int row = rowBase + wr * 64 + mi * 16 + lq * 4 + r;
                C[(size_t)row * 1536 + col] = acc[mi][ni][r];
            }
        }
}

// ---------------------------------------------------------------------------
// FUSED conv-weights GEMM + depthwise conv (round 8).  grid (48, 16).
// ---------------------------------------------------------------------------
__global__ __launch_bounds__(256)
void convgemm(const unsigned short* __restrict__ Ah, const unsigned short* __restrict__ Bh,
              const float* __restrict__ vpre, float* __restrict__ v)
{
    __shared__ unsigned short smem[16384];
    const int tid = threadIdx.x;
    const int wave = tid >> 6, lane = tid & 63;
    const int wr = wave >> 1, wc = wave & 1;
    const int lm = lane & 15, lq = lane >> 4;
    const int K = 192;
    const int rowBase = blockIdx.y * 128, colBase = blockIdx.x * 128;

    unsigned short* AsH = smem;
    unsigned short* BsH = smem + 8192;

    floatx4 acc[4][4];
#pragma unroll
    for (int i = 0; i < 4; ++i)
#pragma unroll
        for (int j = 0; j < 4; ++j) acc[i][j] = (floatx4){0.f, 0.f, 0.f, 0.f};

    const int mt0 = wave * 2, mt1 = wave * 2 + 1;
    const size_t aOff0 = (size_t)(rowBase + mt0 * 16 + lm) * K + lq * 8;
    const size_t aOff1 = (size_t)(rowBase + mt1 * 16 + lm) * K + lq * 8;
    const size_t bOff0 = (size_t)(colBase + mt0 * 16 + lm) * K + lq * 8;
    const size_t bOff1 = (size_t)(colBase + mt1 * 16 + lm) * K + lq * 8;

    auto STAGE = [&](int buf, int k0) {
        gl_lds16(Ah + aOff0 + k0, &AsH[buf * 4096 + mt0 * 512]);
        gl_lds16(Ah + aOff1 + k0, &AsH[buf * 4096 + mt1 * 512]);
        gl_lds16(Bh + bOff0 + k0, &BsH[buf * 4096 + mt0 * 512]);
        gl_lds16(Bh + bOff1 + k0, &BsH[buf * 4096 + mt1 * 512]);
    };

    const int nIter = 6;
    STAGE(0, 0);
    __syncthreads();
    int cur = 0;
    for (int it = 0; it < nIter; ++it) {
        if (it + 1 < nIter) STAGE(cur ^ 1, (it + 1) << 5);
        fp16x8 a[4], b[4];
#pragma unroll
        for (int i = 0; i < 4; ++i) {
            a[i] = *(const fp16x8*)&AsH[cur * 4096 + (wr * 4 + i) * 512 + lane * 8];
            b[i] = *(const fp16x8*)&BsH[cur * 4096 + (wc * 4 + i) * 512 + lane * 8];
        }
#pragma unroll
        for (int mi = 0; mi < 4; ++mi)
#pragma unroll
            for (int ni = 0; ni < 4; ++ni)
                acc[mi][ni] = __builtin_amdgcn_mfma_f32_16x16x32_f16(
                    a[mi], b[ni], acc[mi][ni], 0, 0, 0);
        __syncthreads();
        cur ^= 1;
    }

#pragma unroll
    for (int mi = 0; mi < 4; ++mi)
#pragma unroll
        for (int ni = 0; ni < 4; ++ni) {
            const int cl = wc * 64 + ni * 16 + lm;
#pragma unroll
            for (int r = 0; r < 4; ++r) {
                const int rl = wr * 64 + mi * 16 + lq * 4 + r;
                smem[rl * 128 + cl] = f2bf(acc[mi][ni][r]);
            }
        }
    __syncthreads();

    const int dB = blockIdx.x * 32;
#pragma unroll
    for (int e = 0; e < 16; ++e) {
        const int u = e * 256 + tid;
        const int tl = u >> 5, dd = u & 31;
        const int t = rowBase + tl, d = dB + dd;
        float a0 = 0.0f;
#pragma unroll
        for (int tap = 0; tap < CONVK; ++tap) {
            const int ts = t - (CONVK - 1) + tap;
            if (ts >= 0)
                a0 += vpre[(size_t)ts * HID + d] * bf2f(smem[tl * 128 + dd * 4 + tap]);
        }
        v[(size_t)t * HID + d] = siluf(a0);
    }
}

// ---------------------------------------------------------------------------
// D1: chunk-local WY precompute + fused tiled Q/K emission (round 8).
// ---------------------------------------------------------------------------
__global__ __launch_bounds__(256, 1) void chunkloc_kernel(
    const float* __restrict__ q, const float* __restrict__ k, const float* __restrict__ v,
    const float* __restrict__ g, const float* __restrict__ beta,
    float* __restrict__ X1g,
    unsigned short* __restrict__ X2th, unsigned short* __restrict__ X2tl,
    float* __restrict__ Mg, float* __restrict__ csg,
    unsigned short* __restrict__ Qth, unsigned short* __restrict__ Qtl,
    unsigned short* __restrict__ Kth, unsigned short* __restrict__ Ktl)
{
    __shared__ unsigned short KhS[64 * 136], KlS[64 * 136];
    __shared__ unsigned short QhS[64 * 136], QlS[64 * 136];
    __shared__ float KT[128 * 68];
    __shared__ float Vs[64 * 132];
    __shared__ float As[64 * 68];
    __shared__ float cs[64], sb[64], sbb[64];

    const int c = blockIdx.x, h = blockIdx.y;
    const int tid = threadIdx.x;
    const int wave = tid >> 6, lane = tid & 63;
    const int lm = lane & 15, lq = lane >> 4;
    const int li = tid >> 2, lq4 = tid & 3;
    const size_t rowbase = (size_t)(c * CH) * HID + h * DK;

    {
        const float* ksrc = k + rowbase + (size_t)li * HID + lq4 * 32;
        const float* qsrc = q + rowbase + (size_t)li * HID + lq4 * 32;
        const float* vsrc = v + (size_t)(c * CH + li) * HID + h * DV + lq4 * 32;
#pragma unroll
        for (int f = 0; f < 8; ++f) {
            float4 kx = *(const float4*)(ksrc + f * 4);
            float4 qx = *(const float4*)(qsrc + f * 4);
            float4 vx = *(const float4*)(vsrc + f * 4);
            const int d0 = lq4 * 32 + f * 4;
            {
                ushort4 hh, ll;
                hh.x = f2bf(kx.x); ll.x = f2bf(kx.x - bf2f(hh.x));
                hh.y = f2bf(kx.y); ll.y = f2bf(kx.y - bf2f(hh.y));
                hh.z = f2bf(kx.z); ll.z = f2bf(kx.z - bf2f(hh.z));
                hh.w = f2bf(kx.w); ll.w = f2bf(kx.w - bf2f(hh.w));
                *(ushort4*)&KhS[li * 136 + d0] = hh;
                *(ushort4*)&KlS[li * 136 + d0] = ll;
            }
            {
                ushort4 hh, ll;
                hh.x = f2bf(qx.x); ll.x = f2bf(qx.x - bf2f(hh.x));
                hh.y = f2bf(qx.y); ll.y = f2bf(qx.y - bf2f(hh.y));
                hh.z = f2bf(qx.z); ll.z = f2bf(qx.z - bf2f(hh.z));
                hh.w = f2bf(qx.w); ll.w = f2bf(qx.w - bf2f(hh.w));
                *(ushort4*)&QhS[li * 136 + d0] = hh;
                *(ushort4*)&QlS[li * 136 + d0] = ll;
            }
            KT[(d0 + 0) * 68 + li] = kx.x;
            KT[(d0 + 1) * 68 + li] = kx.y;
            KT[(d0 + 2) * 68 + li] = kx.z;
            KT[(d0 + 3) * 68 + li] = kx.w;
            *(float4*)&Vs[li * 132 + d0] = vx;
        }
    }
    if (tid < 64) {
        float gv = g[(c * CH + tid) * NH + h];
        float bv = beta[(c * CH + tid) * NH + h];
        float csv = gv;
#pragma unroll
        for (int off = 1; off < 64; off <<= 1) {
            float n = __shfl_up(csv, off);
            if (tid >= off) csv += n;
        }
        cs[tid] = csv; sb[tid] = bv; sbb[tid] = bv * __expf(csv);
    }
    __syncthreads();

    {
        const int ti = wave;
#pragma unroll
        for (int tj = 0; tj < 4; ++tj) {
            floatx4 acc = (floatx4){0.f, 0.f, 0.f, 0.f};
#pragma unroll
            for (int ks = 0; ks < 4; ++ks) {
                bf16x8 a_h = *(const bf16x8*)&KhS[(ti * 16 + lm) * 136 + ks * 32 + lq * 8];
                bf16x8 a_l = *(const bf16x8*)&KlS[(ti * 16 + lm) * 136 + ks * 32 + lq * 8];
                bf16x8 b_h = *(const bf16x8*)&KhS[(tj * 16 + lm) * 136 + ks * 32 + lq * 8];
                bf16x8 b_l = *(const bf16x8*)&KlS[(tj * 16 + lm) * 136 + ks * 32 + lq * 8];
                acc = __builtin_amdgcn_mfma_f32_16x16x32_bf16(a_h, b_h, acc, 0, 0, 0);
                acc = __builtin_amdgcn_mfma_f32_16x16x32_bf16(a_h, b_l, acc, 0, 0, 0);
                acc = __builtin_amdgcn_mfma_f32_16x16x32_bf16(a_l, b_h, acc, 0, 0, 0);
            }
#pragma unroll
            for (int r = 0; r < 4; ++r) {
                const int i = ti * 16 + lq * 4 + r, j = tj * 16 + lm;
                As[i * 68 + j] = (j < i) ? sb[i] * __expf(cs[i] - cs[j]) * acc[r] : 0.0f;
            }
        }
        const size_t mbase = (size_t)(h * NC + c) * CH * CH;
#pragma unroll
        for (int tj = 0; tj < 4; ++tj) {
            floatx4 acc = (floatx4){0.f, 0.f, 0.f, 0.f};
#pragma unroll
            for (int ks = 0; ks < 4; ++ks) {
                bf16x8 a_h = *(const bf16x8*)&QhS[(ti * 16 + lm) * 136 + ks * 32 + lq * 8];
                bf16x8 a_l = *(const bf16x8*)&QlS[(ti * 16 + lm) * 136 + ks * 32 + lq * 8];
                bf16x8 b_h = *(const bf16x8*)&KhS[(tj * 16 + lm) * 136 + ks * 32 + lq * 8];
                bf16x8 b_l = *(const bf16x8*)&KlS[(tj * 16 + lm) * 136 + ks * 32 + lq * 8];
                acc = __builtin_amdgcn_mfma_f32_16x16x32_bf16(a_h, b_h, acc, 0, 0, 0);
                acc = __builtin_amdgcn_mfma_f32_16x16x32_bf16(a_h, b_l, acc, 0, 0, 0);
                acc = __builtin_amdgcn_mfma_f32_16x16x32_bf16(a_l, b_h, acc, 0, 0, 0);
            }
#pragma unroll
            for (int r = 0; r < 4; ++r) {
                const int i = ti * 16 + lq * 4 + r, j = tj * 16 + lm;
                Mg[mbase + (size_t)i * 64 + j] =
                    (j <= i) ? __expf(cs[i] - cs[j]) * acc[r] : 0.0f;
            }
        }
    }

    float xc[64];
    const int col = tid;
    if (col < 128) {
#pragma unroll
        for (int i = 0; i < 64; ++i) xc[i] = sb[i] * Vs[i * 132 + col];
    } else {
        const int dcol = col - 128;
#pragma unroll
        for (int i4 = 0; i4 < 16; ++i4) {
            float4 kq = *(const float4*)&KT[dcol * 68 + i4 * 4];
            xc[i4 * 4 + 0] = sbb[i4 * 4 + 0] * kq.x;
            xc[i4 * 4 + 1] = sbb[i4 * 4 + 1] * kq.y;
            xc[i4 * 4 + 2] = sbb[i4 * 4 + 2] * kq.z;
            xc[i4 * 4 + 3] = sbb[i4 * 4 + 3] * kq.w;
        }
    }
    __syncthreads();

#pragma unroll
    for (int i = 1; i < 64; ++i) {
        float a = xc[i];
#pragma unroll
        for (int j4 = 0; j4 < (i + 3) / 4; ++j4) {
            float4 a4 = *(const float4*)&As[i * 68 + j4 * 4];
            a -= a4.x * xc[j4 * 4 + 0] + a4.y * xc[j4 * 4 + 1]
               + a4.z * xc[j4 * 4 + 2] + a4.w * xc[j4 * 4 + 3];
        }
        xc[i] = a;
    }

    {
        const size_t xbase = (size_t)(h * NC + c) * CH * 128;
        if (col < 128) {
            for (int i = 0; i < 64; ++i) X1g[xbase + (size_t)i * 128 + col] = xc[i];
        } else {
            for (int i = 0; i < 64; ++i) Vs[i * 132 + (col - 128)] = xc[i];
        }
    }
    if (tid < 64) csg[(size_t)(h * NC + c) * CH + tid] = cs[tid];
    __syncthreads();

    const size_t tb = (size_t)(h * NC + c) * 8192;

    {
#pragma unroll
        for (int e = 0; e < 4; ++e) {
            int u = e * 256 + tid;
            int ch = u >> 6, l = u & 63;
            int i = (ch >> 2) * 16 + (l & 15);
            int dbase = (ch & 3) * 32 + (l >> 4) * 8;
            float4 a = *(const float4*)&Vs[i * 132 + dbase];
            float4 b = *(const float4*)&Vs[i * 132 + dbase + 4];
            float xv[8] = {-a.x, -a.y, -a.z, -a.w, -b.x, -b.y, -b.z, -b.w};
            split8_store(xv, &X2th[tb + ch * 512 + l * 8], &X2tl[tb + ch * 512 + l * 8]);
        }
    }
    {
#pragma unroll
        for (int e = 0; e < 4; ++e) {
            int u = e * 256 + tid;
            int ch = u >> 6, l = u & 63;
            int i = (ch >> 2) * 16 + (l & 15);
            int dbase = (ch & 3) * 32 + (l >> 4) * 8;
            *(bf16x8*)&Qth[tb + ch * 512 + l * 8] = *(const bf16x8*)&QhS[i * 136 + dbase];
            *(bf16x8*)&Qtl[tb + ch * 512 + l * 8] = *(const bf16x8*)&QlS[i * 136 + dbase];
        }
    }
    {
#pragma unroll
        for (int e = 0; e < 4; ++e) {
            int u = e * 256 + tid;
            int ch = u >> 6, l = u & 63;
            int dk = (ch >> 1) * 16 + (l & 15);
            int ibase = (ch & 1) * 32 + (l >> 4) * 8;
            float4 a = *(const float4*)&KT[dk * 68 + ibase];
            float4 b = *(const float4*)&KT[dk * 68 + ibase + 4];
            float xv[8] = {a.x, a.y, a.z, a.w, b.x, b.y, b.z, b.w};
            split8_store(xv, &Kth[tb + ch * 512 + l * 8], &Ktl[tb + ch * 512 + l * 8]);
        }
    }
}

// ---------------------------------------------------------------------------
// D2 support + kernel (rounds 4-8, unchanged).
// ---------------------------------------------------------------------------
struct StFrags {
    bf16x8 xh[4], xl[4], qh[4], ql[4], kh[4], kl[4];
    float x1r[4], csr[4], cs63;
};

__device__ __forceinline__ void st_load(
    StFrags& f,
    const unsigned short* __restrict__ Qth, const unsigned short* __restrict__ Qtl,
    const unsigned short* __restrict__ Kth, const unsigned short* __restrict__ Ktl,
    const unsigned short* __restrict__ X2th, const unsigned short* __restrict__ X2tl,
    const float* __restrict__ X1g, const float* __restrict__ csg,
    int h, int c, int db, int mw, int lane, int lq, int lm)
{
    const size_t hc = (size_t)(h * NC + c);
    const size_t xb = hc * CH * 128;
    const size_t tb = hc * 8192 + (size_t)lane * 8;
#pragma unroll
    for (int ks = 0; ks < 4; ++ks) {
        const size_t off = tb + (size_t)(mw * 4 + ks) * 512;
        f.xh[ks] = *(const bf16x8*)(X2th + off);
        f.xl[ks] = *(const bf16x8*)(X2tl + off);
        f.qh[ks] = *(const bf16x8*)(Qth + off);
        f.ql[ks] = *(const bf16x8*)(Qtl + off);
        f.kh[ks] = *(const bf16x8*)(Kth + off);
        f.kl[ks] = *(const bf16x8*)(Ktl + off);
    }
#pragma unroll
    for (int r = 0; r < 4; ++r) {
        const int row = mw * 16 + lq * 4 + r;
        f.x1r[r] = X1g[xb + (size_t)row * 128 + db * 16 + lm];
        f.csr[r] = csg[hc * CH + row];
    }
    f.cs63 = csg[hc * CH + 63];
}

__device__ __forceinline__ void st_compute(
    const StFrags& f, floatx4& st0, floatx4& st1,
    unsigned short* SBh, unsigned short* SBl,
    unsigned short* UBh, unsigned short* UBl,
    float* __restrict__ X1g, float* __restrict__ o,
    int h, int c, int db, int mw, int lane, int lq, int lm)
{
    const size_t hc = (size_t)(h * NC + c);
    const size_t xb = hc * CH * 128;

    {
        floatx4 aU0 = (floatx4){0.f, 0.f, 0.f, 0.f};
        floatx4 aU1 = (floatx4){0.f, 0.f, 0.f, 0.f};
        floatx4 aO0 = (floatx4){0.f, 0.f, 0.f, 0.f};
        floatx4 aO1 = (floatx4){0.f, 0.f, 0.f, 0.f};
#pragma unroll
        for (int ks = 0; ks < 4; ++ks) {
            bf16x8 sh = *(const bf16x8*)&SBh[lm * 136 + ks * 32 + lq * 8];
            bf16x8 sl = *(const bf16x8*)&SBl[lm * 136 + ks * 32 + lq * 8];
            if (ks & 1) {
                aU1 = __builtin_amdgcn_mfma_f32_16x16x32_bf16(f.xh[ks], sh, aU1, 0, 0, 0);
                aU1 = __builtin_amdgcn_mfma_f32_16x16x32_bf16(f.xh[ks], sl, aU1, 0, 0, 0);
                aU1 = __builtin_amdgcn_mfma_f32_16x16x32_bf16(f.xl[ks], sh, aU1, 0, 0, 0);
                aO1 = __builtin_amdgcn_mfma_f32_16x16x32_bf16(f.qh[ks], sh, aO1, 0, 0, 0);
                aO1 = __builtin_amdgcn_mfma_f32_16x16x32_bf16(f.qh[ks], sl, aO1, 0, 0, 0);
                aO1 = __builtin_amdgcn_mfma_f32_16x16x32_bf16(f.ql[ks], sh, aO1, 0, 0, 0);
            } else {
                aU0 = __builtin_amdgcn_mfma_f32_16x16x32_bf16(f.xh[ks], sh, aU0, 0, 0, 0);
                aU0 = __builtin_amdgcn_mfma_f32_16x16x32_bf16(f.xh[ks], sl, aU0, 0, 0, 0);
                aU0 = __builtin_amdgcn_mfma_f32_16x16x32_bf16(f.xl[ks], sh, aU0, 0, 0, 0);
                aO0 = __builtin_amdgcn_mfma_f32_16x16x32_bf16(f.qh[ks], sh, aO0, 0, 0, 0);
                aO0 = __builtin_amdgcn_mfma_f32_16x16x32_bf16(f.qh[ks], sl, aO0, 0, 0, 0);
                aO0 = __builtin_amdgcn_mfma_f32_16x16x32_bf16(f.ql[ks], sh, aO0, 0, 0, 0);
            }
        }
#pragma unroll
        for (int r = 0; r < 4; ++r) {
            const int row = mw * 16 + lq * 4 + r;
            const float u = aU0[r] + aU1[r] + f.x1r[r];
            X1g[xb + (size_t)row * 128 + db * 16 + lm] = u;
            const float up = u * __expf(f.cs63 - f.csr[r]);
            unsigned short uh = f2bf(up);
            UBh[lm * 72 + row] = uh;
            UBl[lm * 72 + row] = f2bf(up - bf2f(uh));
            o[(size_t)(c * CH + row) * HID + h * DV + db * 16 + lm] =
                __expf(f.csr[r]) * (aO0[r] + aO1[r]);
        }
    }
    __syncthreads();

    {
        const float bC = __expf(f.cs63);
#pragma unroll
        for (int mt2 = 0; mt2 < 2; ++mt2) {
            const int mt = mw * 2 + mt2;
            floatx4 acc;
            floatx4 stc = mt2 ? st1 : st0;
#pragma unroll
            for (int r = 0; r < 4; ++r) acc[r] = bC * stc[r];
#pragma unroll
            for (int ks = 0; ks < 2; ++ks) {
                bf16x8 ah = f.kh[mt2 * 2 + ks];
                bf16x8 al = f.kl[mt2 * 2 + ks];
                bf16x8 bh = *(const bf16x8*)&UBh[lm * 72 + ks * 32 + lq * 8];
                bf16x8 bl = *(const bf16x8*)&UBl[lm * 72 + ks * 32 + lq * 8];
                acc = __builtin_amdgcn_mfma_f32_16x16x32_bf16(ah, bh, acc, 0, 0, 0);
                acc = __builtin_amdgcn_mfma_f32_16x16x32_bf16(ah, bl, acc, 0, 0, 0);
                acc = __builtin_amdgcn_mfma_f32_16x16x32_bf16(al, bh, acc, 0, 0, 0);
            }
            if (mt2) st1 = acc; else st0 = acc;
            ushort4 shv, slv;
#pragma unroll
            for (int r = 0; r < 4; ++r) {
                const float sv = acc[r];
                unsigned short sh = f2bf(sv);
                ((unsigned short*)&shv)[r] = sh;
                ((unsigned short*)&slv)[r] = f2bf(sv - bf2f(sh));
            }
            const int dkb = mt * 16 + lq * 4;
            *(ushort4*)&SBh[lm * 136 + dkb] = shv;
            *(ushort4*)&SBl[lm * 136 + dkb] = slv;
        }
    }
    __syncthreads();
}

__global__ __launch_bounds__(256, 1) void state_kernel(
    const unsigned short* __restrict__ Qth, const unsigned short* __restrict__ Qtl,
    const unsigned short* __restrict__ Kth, const unsigned short* __restrict__ Ktl,
    const unsigned short* __restrict__ X2th, const unsigned short* __restrict__ X2tl,
    float* __restrict__ X1g, const float* __restrict__ csg, float* __restrict__ o)
{
    __shared__ unsigned short SBh[16 * 136], SBl[16 * 136];
    __shared__ unsigned short UBh[16 * 72],  UBl[16 * 72];

    const int h = blockIdx.x, db = blockIdx.y;
    const int tid = threadIdx.x;
    const int mw = tid >> 6, lane = tid & 63;
    const int lm = lane & 15, lq = lane >> 4;

    for (int idx = tid; idx < 16 * 136; idx += 256) { SBh[idx] = 0; SBl[idx] = 0; }
    floatx4 st0 = (floatx4){0.f, 0.f, 0.f, 0.f};
    floatx4 st1 = (floatx4){0.f, 0.f, 0.f, 0.f};
    __syncthreads();

    StFrags fA, fB;
    st_load(fA, Qth, Qtl, Kth, Ktl, X2th, X2tl, X1g, csg, h, 0, db, mw, lane, lq, lm);
    for (int c = 0; c < NC; c += 2) {
        st_load(fB, Qth, Qtl, Kth, Ktl, X2th, X2tl, X1g, csg, h, c + 1, db, mw, lane, lq, lm);
        __builtin_amdgcn_sched_barrier(0);
        st_compute(fA, st0, st1, SBh, SBl, UBh, UBl, X1g, o, h, c, db, mw, lane, lq, lm);
        if (c + 2 < NC)
            st_load(fA, Qth, Qtl, Kth, Ktl, X2th, X2tl, X1g, csg, h, c + 2, db, mw, lane, lq, lm);
        __builtin_amdgcn_sched_barrier(0);
        st_compute(fB, st0, st1, SBh, SBl, UBh, UBl, X1g, o, h, c + 1, db, mw, lane, lq, lm);
    }
}

// ---------------------------------------------------------------------------
// D3 + gated RMSNorm FUSED.  Round-11: writes fp16 onh ONLY (final GEMM is
// now fp16 single-term).  grid (NC, NH).
// ---------------------------------------------------------------------------
__global__ __launch_bounds__(256) void outknorm_kernel(
    const float* __restrict__ Ug, const float* __restrict__ Mg,
    const float* __restrict__ o /* prev from state */,
    const unsigned short* __restrict__ gsil, const float* __restrict__ nw,
    unsigned short* __restrict__ out_h)
{
    __shared__ float Msh[64 * 68];
    __shared__ float Ush[64 * 132];
    __shared__ float rsq[64];

    const int c = blockIdx.x, h = blockIdx.y;
    const int tid = threadIdx.x;
    const size_t hc = (size_t)(h * NC + c);

    for (int e = 0; e < 16; ++e) {
        int idx = e * 256 + tid;
        Msh[(idx >> 6) * 68 + (idx & 63)] = Mg[hc * CH * CH + idx];
    }
    for (int e = 0; e < 32; ++e) {
        int idx = e * 256 + tid;
        int j = idx >> 7, cc = idx & 127;
        Ush[j * 132 + cc] = Ug[hc * CH * 128 + (size_t)j * 128 + cc];
    }
    __syncthreads();

    const int tx = tid & 15, ty = tid >> 4;
    const int c0 = tx * 8, i0 = ty * 4;
    float acc[4][8] = {{0}};
    for (int j4 = 0; j4 < 16; ++j4) {
        float uv[4][8];
#pragma unroll
        for (int s = 0; s < 4; ++s) {
            float4 u4a = *(const float4*)&Ush[(j4 * 4 + s) * 132 + c0];
            float4 u4b = *(const float4*)&Ush[(j4 * 4 + s) * 132 + c0 + 4];
            uv[s][0] = u4a.x; uv[s][1] = u4a.y; uv[s][2] = u4a.z; uv[s][3] = u4a.w;
            uv[s][4] = u4b.x; uv[s][5] = u4b.y; uv[s][6] = u4b.z; uv[s][7] = u4b.w;
        }
#pragma unroll
        for (int r = 0; r < 4; ++r) {
            float4 m4 = *(const float4*)&Msh[(i0 + r) * 68 + j4 * 4];
            const float mv[4] = {m4.x, m4.y, m4.z, m4.w};
#pragma unroll
            for (int s = 0; s < 4; ++s)
#pragma unroll
                for (int e = 0; e < 8; ++e) acc[r][e] += mv[s] * uv[s][e];
        }
    }
    __syncthreads();   // all Ush reads done before overwrite

    const float scale = 0.08838834764831845f;
#pragma unroll
    for (int r = 0; r < 4; ++r) {
        const float* op = &o[(size_t)(c * CH + i0 + r) * HID + h * DV + c0];
        float4 p0 = *(const float4*)op;
        float4 p1 = *(const float4*)(op + 4);
        const float pv[8] = {p0.x, p0.y, p0.z, p0.w, p1.x, p1.y, p1.z, p1.w};
#pragma unroll
        for (int e = 0; e < 8; ++e)
            Ush[(i0 + r) * 132 + c0 + e] = scale * (pv[e] + acc[r][e]);
    }
    __syncthreads();   // final o-tile resident in Ush

    // per-row RMS: 4 lanes/row, 32 cols each, 2-level shfl reduce
    {
        const int row = tid >> 2, sub = tid & 3;
        float ss = 0.0f;
#pragma unroll
        for (int k2 = 0; k2 < 32; ++k2) {
            float x = Ush[row * 132 + sub * 32 + k2];
            ss += x * x;
        }
        ss += __shfl_xor(ss, 1);
        ss += __shfl_xor(ss, 2);
        if (sub == 0) rsq[row] = rsqrtf(ss * (1.0f / 128.0f) + 1e-5f);
    }
    __syncthreads();

    // coalesced gate+norm write (fp16)
    for (int e = 0; e < 32; ++e) {
        int idx = e * 256 + tid;
        int j = idx >> 7, cc = idx & 127;
        const size_t base = (size_t)(c * CH + j) * HID + h * DV;
        float va = Ush[j * 132 + cc] * rsq[j] * nw[cc] * bf2f(gsil[base + cc]);
        out_h[base + cc] = f2h(va);
    }
}

// ---------------------------------------------------------------------------
extern "C" void kernel_launch(void* const* d_in, const int* in_sizes, int n_in,
                              void* d_out, int out_size, void* d_ws, size_t ws_size,
                              hipStream_t stream) {
    const float* hs      = (const float*)d_in[0];
    const float* Wq      = (const float*)d_in[1];
    const float* Wk      = (const float*)d_in[2];
    const float* Wv      = (const float*)d_in[3];
    const float* Wb      = (const float*)d_in[4];
    const float* Wa      = (const float*)d_in[5];
    const float* A_log   = (const float*)d_in[6];
    const float* dt_bias = (const float*)d_in[7];
    const float* Wg1     = (const float*)d_in[8];
    const float* Wg2     = (const float*)d_in[9];
    const float* Wgate   = (const float*)d_in[10];
    const float* norm_w  = (const float*)d_in[11];
    const float* Wo      = (const float*)d_in[12];

    float* ws = (float*)d_ws;
    float* q    = ws;                                        // later WoTh
    float* kbuf = ws + 3145728;
    float* vpre = ws + 6291456;                              // later Qt, then onh
    float* vbuf = ws + 9437184;                              // early hsbh/hsbl; then v / o
    unsigned short* gsil = (unsigned short*)(ws + 12582912);
    float* X1g  = ws + 14155776;                             // fp32, becomes U
    unsigned short* X2th = (unsigned short*)(ws + 17301504);
    unsigned short* X2tl = (unsigned short*)(ws + 18874368);
    float* Mg   = ws + 20447232;
    unsigned short* WTAfh = (unsigned short*)(ws + 14155776);
    unsigned short* WTBh  = (unsigned short*)(ws + 17891328);
    unsigned short* WTBl  = (unsigned short*)(ws + 19169280);
    unsigned short* WG2h  = (unsigned short*)(ws + 22044672);
    unsigned short* hsh   = (unsigned short*)(ws + 22634496);
    unsigned short* w1h16 = (unsigned short*)(ws + 24207360);
    unsigned short* Kth = (unsigned short*)(ws + 22044672);
    unsigned short* Ktl = (unsigned short*)(ws + 23617536);
    float* beta  = ws + 25190400;
    float* g     = ws + 25214976;
    float* csg   = ws + 25239552;
    unsigned short* hsbh = (unsigned short*)(ws + 9437184);
    unsigned short* hsbl = (unsigned short*)(ws + 11010048);
    unsigned short* Qth  = (unsigned short*)(ws + 6291456);
    unsigned short* Qtl  = (unsigned short*)(ws + 7864320);
    unsigned short* WoTh = (unsigned short*)(ws);            // fp16 N x K
    unsigned short* onh  = (unsigned short*)(ws + 6291456);  // fp16 M x K

    const dim3 blk(256);

    // P0: all independent prep in ONE launch
    prep_all<<<13824, blk, 0, stream>>>(hs, hsbh, hsbl, hsh,
                                        Wq, Wv, Wgate, Wg1, Wg2, Wk, Wb, Wa,
                                        WTAfh, WG2h, WTBh, WTBl);

    // P1: fused GEMM-A (BK=64) + GEMM-B (+ inline beta/g epilogue)
    mgemm_ab<<<1024, blk, 0, stream>>>(hsh, WTAfh, hsbh, hsbl, WTBh, WTBl,
                                       q, vpre, gsil, w1h16, kbuf,
                                       A_log, dt_bias, beta, g);

    // P2: conv weights GEMM with fused depthwise conv epilogue
    convgemm<<<dim3(48, 16), blk, 0, stream>>>(w1h16, WG2h, vpre, vbuf);

    // P3: chunked delta rule
    chunkloc_kernel<<<dim3(NC, NH), blk, 0, stream>>>(q, kbuf, vbuf, g, beta,
                                                      X1g, X2th, X2tl, Mg, csg,
                                                      Qth, Qtl, Kth, Ktl);
    state_kernel<<<dim3(NH, 8), blk, 0, stream>>>(Qth, Qtl, Kth, Ktl, X2th, X2tl,
                                                  X1g, csg, vbuf);
    // Wo transpose+cast fp16 (flat 256-thread launch; q dead after chunkloc)
    transcasth_kernel<<<dim3(48, 48), blk, 0, stream>>>(Wo, WoTh, 1536, 1536);

    // P4: fused outk + gated RMSNorm (fp16 out), then fp16 output GEMM BK=64
    outknorm_kernel<<<dim3(NC, NH), blk, 0, stream>>>(X1g, Mg, vbuf, gsil, norm_w, onh);
    fgemm<<<dim3(24, 16), blk, 0, stream>>>(onh, WoTh, (float*)d_out);
}

// Round 12
// 493.488 us; speedup vs baseline: 1.1179x; 1.0106x over previous
//
#include <hip/hip_runtime.h>
#include <hip/hip_bf16.h>
#include <math.h>

#define T     2048
#define HID   1536
#define NH    12
#define DK    128
#define DV    128
#define CONVK 4
#define CH    64
#define NC    32

typedef __attribute__((ext_vector_type(8))) short bf16x8;
typedef __attribute__((ext_vector_type(8))) _Float16 fp16x8;
typedef __attribute__((ext_vector_type(4))) float floatx4;

__device__ __forceinline__ float siluf(float x) {
    return x / (1.0f + __expf(-x));
}
__device__ __forceinline__ unsigned short f2bf(float f) {
    union { __hip_bfloat16 b; unsigned short u; } cv;
    cv.b = __float2bfloat16(f);
    return cv.u;
}
__device__ __forceinline__ float bf2f(unsigned short u) {
    union { unsigned int u; float f; } cv;
    cv.u = ((unsigned int)u) << 16;
    return cv.f;
}
__device__ __forceinline__ unsigned short f2h(float f) {
    union { _Float16 h; unsigned short u; } cv;
    cv.h = (_Float16)f;
    return cv.u;
}
__device__ __forceinline__ void gl_lds16(const void* g, void* l) {
    __builtin_amdgcn_global_load_lds(
        (const __attribute__((address_space(1))) void*)g,
        (__attribute__((address_space(3))) void*)l, 16, 0, 0);
}
// split 8 fp32 -> hi/lo bf16, write as 2x ushort4 each
__device__ __forceinline__ void split8_store(const float* xv,
                                             unsigned short* dh, unsigned short* dl) {
    ushort4 h0, h1, l0, l1;
    h0.x = f2bf(xv[0]); l0.x = f2bf(xv[0] - bf2f(h0.x));
    h0.y = f2bf(xv[1]); l0.y = f2bf(xv[1] - bf2f(h0.y));
    h0.z = f2bf(xv[2]); l0.z = f2bf(xv[2] - bf2f(h0.z));
    h0.w = f2bf(xv[3]); l0.w = f2bf(xv[3] - bf2f(h0.w));
    h1.x = f2bf(xv[4]); l1.x = f2bf(xv[4] - bf2f(h1.x));
    h1.y = f2bf(xv[5]); l1.y = f2bf(xv[5] - bf2f(h1.y));
    h1.z = f2bf(xv[6]); l1.z = f2bf(xv[6] - bf2f(h1.z));
    h1.w = f2bf(xv[7]); l1.w = f2bf(xv[7] - bf2f(h1.w));
    *(ushort4*)dh = h0; *(ushort4*)(dh + 4) = h1;
    *(ushort4*)dl = l0; *(ushort4*)(dl + 4) = l1;
}

// ---------------------------------------------------------------------------
// device bodies for the fused prep kernel. REQUIRE a flat 256-thread tid.
// ---------------------------------------------------------------------------
__device__ __forceinline__ void tch_body(const float* __restrict__ src,
                                         unsigned short* __restrict__ dst,
                                         int K, int N, int gx, int gy, int tid,
                                         float* tile /*32*33*/) {
    const int tx = tid & 31, ty = tid >> 5;
    const int k0 = gy * 32, n0 = gx * 32;
#pragma unroll
    for (int r = 0; r < 4; ++r) {
        int kk = k0 + ty + 8 * r, nn = n0 + tx;
        tile[(ty + 8 * r) * 33 + tx] = (nn < N) ? src[(size_t)kk * N + nn] : 0.0f;
    }
    __syncthreads();
#pragma unroll
    for (int r = 0; r < 4; ++r) {
        int nn = n0 + ty + 8 * r, kk = k0 + tx;
        if (nn < N) dst[(size_t)nn * K + kk] = f2h(tile[tx * 33 + ty + 8 * r]);
    }
}
__device__ __forceinline__ void tsp_body(const float* __restrict__ src,
                                         unsigned short* __restrict__ hi,
                                         unsigned short* __restrict__ lo,
                                         int K, int N, int gx, int gy, int tid,
                                         float* tile) {
    const int tx = tid & 31, ty = tid >> 5;
    const int k0 = gy * 32, n0 = gx * 32;
#pragma unroll
    for (int r = 0; r < 4; ++r) {
        int kk = k0 + ty + 8 * r, nn = n0 + tx;
        tile[(ty + 8 * r) * 33 + tx] = (nn < N) ? src[(size_t)kk * N + nn] : 0.0f;
    }
    __syncthreads();
#pragma unroll
    for (int r = 0; r < 4; ++r) {
        int nn = n0 + ty + 8 * r, kk = k0 + tx;
        if (nn < N) {
            float x = tile[tx * 33 + ty + 8 * r];
            unsigned short h = f2bf(x);
            hi[(size_t)nn * K + kk] = h;
            lo[(size_t)nn * K + kk] = f2bf(x - bf2f(h));
        }
    }
}

// ---------------------------------------------------------------------------
// prep_all: ONE launch for all P0 data-independent prep.
// ---------------------------------------------------------------------------
__global__ __launch_bounds__(256) void prep_all(
    const float* __restrict__ hs,
    unsigned short* __restrict__ hsbh, unsigned short* __restrict__ hsbl,
    unsigned short* __restrict__ hsh,
    const float* __restrict__ Wq, const float* __restrict__ Wv,
    const float* __restrict__ Wgate, const float* __restrict__ Wg1,
    const float* __restrict__ Wg2,
    const float* __restrict__ Wk, const float* __restrict__ Wb,
    const float* __restrict__ Wa,
    unsigned short* __restrict__ WTAfh, unsigned short* __restrict__ WG2h,
    unsigned short* __restrict__ WTBh, unsigned short* __restrict__ WTBl)
{
    __shared__ float tile[32 * 33];
    const int bx = blockIdx.x, tid = threadIdx.x;

    if (bx < 3072) {
        const int i = bx * 256 + tid;
        float4 x = ((const float4*)hs)[i];
        ushort4 h, l, f;
        h.x = f2bf(x.x); l.x = f2bf(x.x - bf2f(h.x)); f.x = f2h(x.x);
        h.y = f2bf(x.y); l.y = f2bf(x.y - bf2f(h.y)); f.y = f2h(x.y);
        h.z = f2bf(x.z); l.z = f2bf(x.z - bf2f(h.z)); f.z = f2h(x.z);
        h.w = f2bf(x.w); l.w = f2bf(x.w - bf2f(h.w)); f.w = f2h(x.w);
        ((ushort4*)hsbh)[i] = h;
        ((ushort4*)hsbl)[i] = l;
        ((ushort4*)hsh)[i]  = f;
    } else if (bx < 5376) {
        const int t = bx - 3072;
        tch_body(Wq, WTAfh, 1536, 1536, t % 48, t / 48, tid, tile);
    } else if (bx < 7680) {
        const int t = bx - 5376;
        tch_body(Wv, WTAfh + 1536 * 1536, 1536, 1536, t % 48, t / 48, tid, tile);
    } else if (bx < 9984) {
        const int t = bx - 7680;
        tch_body(Wgate, WTAfh + 3072 * 1536, 1536, 1536, t % 48, t / 48, tid, tile);
    } else if (bx < 10272) {
        const int t = bx - 9984;
        tch_body(Wg1, WTAfh + 4608 * 1536, 1536, 192, t % 6, t / 6, tid, tile);
    } else if (bx < 11424) {
        const int t = bx - 10272;
        tch_body(Wg2, WG2h, 192, 6144, t % 192, t / 192, tid, tile);
    } else if (bx < 13728) {
        const int t = bx - 11424;
        tsp_body(Wk, WTBh, WTBl, 1536, 1536, t % 48, t / 48, tid, tile);
    } else if (bx < 13776) {
        const int t = bx - 13728;
        tsp_body(Wb, WTBh + 1536 * 1536, WTBl + 1536 * 1536, 1536, 12, 0, t, tid, tile);
    } else {
        const int t = bx - 13776;
        tsp_body(Wa, WTBh + 1548 * 1536, WTBl + 1548 * 1536, 1536, 12, 0, t, tid, tile);
    }
}

// ---------------------------------------------------------------------------
// standalone transpose+cast fp16 (for Wo -> WoTh; flat 256-thr launch).
// ---------------------------------------------------------------------------
__global__ __launch_bounds__(256) void transcasth_kernel(const float* __restrict__ src,
                                                         unsigned short* __restrict__ dst,
                                                         int K, int N) {
    __shared__ float tile[32 * 33];
    tch_body(src, dst, K, N, blockIdx.x, blockIdx.y, threadIdx.x, tile);
}

// ---------------------------------------------------------------------------
// FUSED GEMM A+B.  Round-12: B-role tile 128x64 -> 128x128 (208 blocks,
// round-0 verified MODE-1 geometry) — round-11 showed A's BK=64 gain was
// diluted because B's 48-steps x 416-blocks dominates; halving the per-CU
// B-step count amortizes the fixed per-step stall over 2x the MFMA work.
// LDS union unchanged at 64KB (2 blocks/CU).  Grid 816 = 608 A + 208 B.
// ---------------------------------------------------------------------------
__global__ __launch_bounds__(256)
void mgemm_ab(const unsigned short* __restrict__ Ah0, const unsigned short* __restrict__ Bh0,
              const unsigned short* __restrict__ Ah1, const unsigned short* __restrict__ Al1,
              const unsigned short* __restrict__ Bh1, const unsigned short* __restrict__ Bl1,
              float* __restrict__ qf, float* __restrict__ vf,
              unsigned short* __restrict__ gsilb, unsigned short* __restrict__ w1h16,
              float* __restrict__ kf,
              const float* __restrict__ A_log, const float* __restrict__ dt_bias,
              float* __restrict__ beta, float* __restrict__ g)
{
    __shared__ unsigned short smem[32768];   // 64 KB union
    const int tid = threadIdx.x;
    const int wave = tid >> 6, lane = tid & 63;
    const int wr = wave >> 1, wc = wave & 1;
    const int lm = lane & 15, lq = lane >> 4;
    const int K = 1536;
    const int bx = blockIdx.x;

    // 208 B blocks interleaved with first 208 A blocks; remaining 400 A.
    bool roleA; int aidx = 0, bidx = 0;
    if (bx < 416) { roleA = ((bx & 1) == 0); aidx = bx >> 1; bidx = bx >> 1; }
    else          { roleA = true;            aidx = 208 + (bx - 416); }

    const int mt0 = wave * 2, mt1 = wave * 2 + 1;

    if (roleA) {
        // ---- GEMM-A: fp16 128x128, BK=64 (24 steps).  grid map (38,16) ----
        const int rowBase = (aidx / 38) * 128, colBase = (aidx % 38) * 128;
        unsigned short* AsH = smem;           // [2][8192]: buf*8192 + half*4096 + mt*512
        unsigned short* BsH = smem + 16384;   // [2][8192]
        floatx4 acc[4][4];
#pragma unroll
        for (int i = 0; i < 4; ++i)
#pragma unroll
            for (int j = 0; j < 4; ++j) acc[i][j] = (floatx4){0.f, 0.f, 0.f, 0.f};

        const size_t aOff0 = (size_t)(rowBase + mt0 * 16 + lm) * K + lq * 8;
        const size_t aOff1 = (size_t)(rowBase + mt1 * 16 + lm) * K + lq * 8;
        const size_t bOff0 = (size_t)(colBase + mt0 * 16 + lm) * K + lq * 8;
        const size_t bOff1 = (size_t)(colBase + mt1 * 16 + lm) * K + lq * 8;

        auto STAGE = [&](int buf, int k0) {
            gl_lds16(Ah0 + aOff0 + k0,      &AsH[buf * 8192 + mt0 * 512]);
            gl_lds16(Ah0 + aOff1 + k0,      &AsH[buf * 8192 + mt1 * 512]);
            gl_lds16(Ah0 + aOff0 + k0 + 32, &AsH[buf * 8192 + 4096 + mt0 * 512]);
            gl_lds16(Ah0 + aOff1 + k0 + 32, &AsH[buf * 8192 + 4096 + mt1 * 512]);
            gl_lds16(Bh0 + bOff0 + k0,      &BsH[buf * 8192 + mt0 * 512]);
            gl_lds16(Bh0 + bOff1 + k0,      &BsH[buf * 8192 + mt1 * 512]);
            gl_lds16(Bh0 + bOff0 + k0 + 32, &BsH[buf * 8192 + 4096 + mt0 * 512]);
            gl_lds16(Bh0 + bOff1 + k0 + 32, &BsH[buf * 8192 + 4096 + mt1 * 512]);
        };
        STAGE(0, 0);
        __syncthreads();
        int cur = 0;
        for (int it = 0; it < 24; ++it) {
            if (it + 1 < 24) STAGE(cur ^ 1, (it + 1) << 6);
#pragma unroll
            for (int s = 0; s < 2; ++s) {
                fp16x8 a[4], b[4];
#pragma unroll
                for (int i = 0; i < 4; ++i) {
                    a[i] = *(const fp16x8*)&AsH[cur * 8192 + s * 4096 + (wr * 4 + i) * 512 + lane * 8];
                    b[i] = *(const fp16x8*)&BsH[cur * 8192 + s * 4096 + (wc * 4 + i) * 512 + lane * 8];
                }
#pragma unroll
                for (int mi = 0; mi < 4; ++mi)
#pragma unroll
                    for (int ni = 0; ni < 4; ++ni)
                        acc[mi][ni] = __builtin_amdgcn_mfma_f32_16x16x32_f16(
                            a[mi], b[ni], acc[mi][ni], 0, 0, 0);
            }
            __syncthreads();
            cur ^= 1;
        }
#pragma unroll
        for (int mi = 0; mi < 4; ++mi)
#pragma unroll
            for (int ni = 0; ni < 4; ++ni) {
                const int col = colBase + wc * 64 + ni * 16 + lm;
#pragma unroll
                for (int r = 0; r < 4; ++r) {
                    const int row = rowBase + wr * 64 + mi * 16 + lq * 4 + r;
                    const float x = acc[mi][ni][r];
                    if (col < 1536)       qf[(size_t)row * 1536 + col] = siluf(x);
                    else if (col < 3072)  vf[(size_t)row * 1536 + col - 1536] = x;
                    else if (col < 4608)  gsilb[(size_t)row * 1536 + col - 3072] = f2bf(siluf(x));
                    else if (col < 4800)  w1h16[(size_t)row * 192 + col - 4608] = f2h(siluf(x));
                }
            }
    } else {
        // ---- GEMM-B: 3-term bf16 128x128, BK=32 (48 steps).  grid (13,16) ----
        const int rowBase = (bidx / 13) * 128, colBase = (bidx % 13) * 128;
        unsigned short* AsH = smem;            // [2][4096]
        unsigned short* AsL = smem + 8192;     // [2][4096]
        unsigned short* BsH = smem + 16384;    // [2][4096]
        unsigned short* BsL = smem + 24576;    // [2][4096]
        floatx4 acc[4][4];
#pragma unroll
        for (int i = 0; i < 4; ++i)
#pragma unroll
            for (int j = 0; j < 4; ++j) acc[i][j] = (floatx4){0.f, 0.f, 0.f, 0.f};

        const size_t aOff0 = (size_t)(rowBase + mt0 * 16 + lm) * K + lq * 8;
        const size_t aOff1 = (size_t)(rowBase + mt1 * 16 + lm) * K + lq * 8;
        const size_t bOff0 = (size_t)(colBase + mt0 * 16 + lm) * K + lq * 8;
        const size_t bOff1 = (size_t)(colBase + mt1 * 16 + lm) * K + lq * 8;

        auto STAGE = [&](int buf, int k0) {
            gl_lds16(Ah1 + aOff0 + k0, &AsH[buf * 4096 + mt0 * 512]);
            gl_lds16(Ah1 + aOff1 + k0, &AsH[buf * 4096 + mt1 * 512]);
            gl_lds16(Al1 + aOff0 + k0, &AsL[buf * 4096 + mt0 * 512]);
            gl_lds16(Al1 + aOff1 + k0, &AsL[buf * 4096 + mt1 * 512]);
            gl_lds16(Bh1 + bOff0 + k0, &BsH[buf * 4096 + mt0 * 512]);
            gl_lds16(Bh1 + bOff1 + k0, &BsH[buf * 4096 + mt1 * 512]);
            gl_lds16(Bl1 + bOff0 + k0, &BsL[buf * 4096 + mt0 * 512]);
            gl_lds16(Bl1 + bOff1 + k0, &BsL[buf * 4096 + mt1 * 512]);
        };
        STAGE(0, 0);
        __syncthreads();
        int cur = 0;
        for (int it = 0; it < 48; ++it) {
            if (it + 1 < 48) STAGE(cur ^ 1, (it + 1) << 5);
            bf16x8 ah[4], al[4], bh[4], bl[4];
#pragma unroll
            for (int i = 0; i < 4; ++i) {
                ah[i] = *(const bf16x8*)&AsH[cur * 4096 + (wr * 4 + i) * 512 + lane * 8];
                al[i] = *(const bf16x8*)&AsL[cur * 4096 + (wr * 4 + i) * 512 + lane * 8];
                bh[i] = *(const bf16x8*)&BsH[cur * 4096 + (wc * 4 + i) * 512 + lane * 8];
                bl[i] = *(const bf16x8*)&BsL[cur * 4096 + (wc * 4 + i) * 512 + lane * 8];
            }
#pragma unroll
            for (int mi = 0; mi < 4; ++mi)
#pragma unroll
                for (int ni = 0; ni < 4; ++ni) {
                    acc[mi][ni] = __builtin_amdgcn_mfma_f32_16x16x32_bf16(
                        ah[mi], bh[ni], acc[mi][ni], 0, 0, 0);
                    acc[mi][ni] = __builtin_amdgcn_mfma_f32_16x16x32_bf16(
                        al[mi], bh[ni], acc[mi][ni], 0, 0, 0);
                    acc[mi][ni] = __builtin_amdgcn_mfma_f32_16x16x32_bf16(
                        ah[mi], bl[ni], acc[mi][ni], 0, 0, 0);
                }
            __syncthreads();
            cur ^= 1;
        }
#pragma unroll
        for (int mi = 0; mi < 4; ++mi)
#pragma unroll
            for (int ni = 0; ni < 4; ++ni) {
                const int col = colBase + wc * 64 + ni * 16 + lm;
#pragma unroll
                for (int r = 0; r < 4; ++r) {
                    const int row = rowBase + wr * 64 + mi * 16 + lq * 4 + r;
                    const float x = acc[mi][ni][r];
                    if (col < 1536) {
                        kf[(size_t)row * 1536 + col] = siluf(x);
                    } else if (col < 1560) {
                        const int c2 = col - 1536;
                        if (c2 < 12) {
                            beta[row * NH + c2] = 1.0f / (1.0f + __expf(-x));
                        } else {
                            const int hh = c2 - 12;
                            const float y = x + dt_bias[hh];
                            const float sp = (y > 20.0f) ? y : log1pf(__expf(y));
                            g[row * NH + hh] = -__expf(A_log[hh]) * sp;
                        }
                    }
                }
            }
    }
}

// ---------------------------------------------------------------------------
// Final output GEMM: fp16 single-term, 128x64 tile, BK=64 (24 steps).
// grid (24, 16).
// ---------------------------------------------------------------------------
__global__ __launch_bounds__(256)
void fgemm(const unsigned short* __restrict__ Ah, const unsigned short* __restrict__ Bh,
           float* __restrict__ C)
{
    __shared__ unsigned short AsH[2][8192];   // buf, half*4096 + mt*512
    __shared__ unsigned short BsH[2][4096];   // buf, half*2048 + wv*512
    const int tid = threadIdx.x;
    const int wave = tid >> 6, lane = tid & 63;
    const int wr = wave >> 1, wc = wave & 1;
    const int lm = lane & 15, lq = lane >> 4;
    const int K = 1536;
    const int rowBase = blockIdx.y * 128, colBase = blockIdx.x * 64;

    floatx4 acc[4][2];
#pragma unroll
    for (int i = 0; i < 4; ++i)
#pragma unroll
        for (int j = 0; j < 2; ++j) acc[i][j] = (floatx4){0.f, 0.f, 0.f, 0.f};

    const int mt0 = wave * 2, mt1 = wave * 2 + 1;
    const size_t aOff0 = (size_t)(rowBase + mt0 * 16 + lm) * K + lq * 8;
    const size_t aOff1 = (size_t)(rowBase + mt1 * 16 + lm) * K + lq * 8;
    const size_t bOffW = (size_t)(colBase + wave * 16 + lm) * K + lq * 8;

    auto STAGE = [&](int buf, int k0) {
        gl_lds16(Ah + aOff0 + k0,      &AsH[buf][mt0 * 512]);
        gl_lds16(Ah + aOff1 + k0,      &AsH[buf][mt1 * 512]);
        gl_lds16(Ah + aOff0 + k0 + 32, &AsH[buf][4096 + mt0 * 512]);
        gl_lds16(Ah + aOff1 + k0 + 32, &AsH[buf][4096 + mt1 * 512]);
        gl_lds16(Bh + bOffW + k0,      &BsH[buf][wave * 512]);
        gl_lds16(Bh + bOffW + k0 + 32, &BsH[buf][2048 + wave * 512]);
    };

    STAGE(0, 0);
    __syncthreads();
    int cur = 0;
    for (int it = 0; it < 24; ++it) {
        if (it + 1 < 24) STAGE(cur ^ 1, (it + 1) << 6);
#pragma unroll
        for (int s = 0; s < 2; ++s) {
            fp16x8 a[4], b[2];
#pragma unroll
            for (int i = 0; i < 4; ++i)
                a[i] = *(const fp16x8*)&AsH[cur][s * 4096 + (wr * 4 + i) * 512 + lane * 8];
#pragma unroll
            for (int j = 0; j < 2; ++j)
                b[j] = *(const fp16x8*)&BsH[cur][s * 2048 + (wc * 2 + j) * 512 + lane * 8];
#pragma unroll
            for (int mi = 0; mi < 4; ++mi)
#pragma unroll
                for (int ni = 0; ni < 2; ++ni)
                    acc[mi][ni] = __builtin_amdgcn_mfma_f32_16x16x32_f16(
                        a[mi], b[ni], acc[mi][ni], 0, 0, 0);
        }
        __syncthreads();
        cur ^= 1;
    }

#pragma unroll
    for (int mi = 0; mi < 4; ++mi)
#pragma unroll
        for (int ni = 0; ni < 2; ++ni) {
            const int col = colBase + wc * 32 + ni * 16 + lm;
#pragma unroll
            for (int r = 0; r < 4; ++r) {
                const int row = rowBase + wr * 64 + mi * 16 + lq * 4 + r;
                C[(size_t)row * 1536 + col] = acc[mi][ni][r];
            }
        }
}

// ---------------------------------------------------------------------------
// FUSED conv-weights GEMM + depthwise conv (round 8).  grid (48, 16).
// ---------------------------------------------------------------------------
__global__ __launch_bounds__(256)
void convgemm(const unsigned short* __restrict__ Ah, const unsigned short* __restrict__ Bh,
              const float* __restrict__ vpre, float* __restrict__ v)
{
    __shared__ unsigned short smem[16384];
    const int tid = threadIdx.x;
    const int wave = tid >> 6, lane = tid & 63;
    const int wr = wave >> 1, wc = wave & 1;
    const int lm = lane & 15, lq = lane >> 4;
    const int K = 192;
    const int rowBase = blockIdx.y * 128, colBase = blockIdx.x * 128;

    unsigned short* AsH = smem;
    unsigned short* BsH = smem + 8192;

    floatx4 acc[4][4];
#pragma unroll
    for (int i = 0; i < 4; ++i)
#pragma unroll
        for (int j = 0; j < 4; ++j) acc[i][j] = (floatx4){0.f, 0.f, 0.f, 0.f};

    const int mt0 = wave * 2, mt1 = wave * 2 + 1;
    const size_t aOff0 = (size_t)(rowBase + mt0 * 16 + lm) * K + lq * 8;
    const size_t aOff1 = (size_t)(rowBase + mt1 * 16 + lm) * K + lq * 8;
    const size_t bOff0 = (size_t)(colBase + mt0 * 16 + lm) * K + lq * 8;
    const size_t bOff1 = (size_t)(colBase + mt1 * 16 + lm) * K + lq * 8;

    auto STAGE = [&](int buf, int k0) {
        gl_lds16(Ah + aOff0 + k0, &AsH[buf * 4096 + mt0 * 512]);
        gl_lds16(Ah + aOff1 + k0, &AsH[buf * 4096 + mt1 * 512]);
        gl_lds16(Bh + bOff0 + k0, &BsH[buf * 4096 + mt0 * 512]);
        gl_lds16(Bh + bOff1 + k0, &BsH[buf * 4096 + mt1 * 512]);
    };

    const int nIter = 6;
    STAGE(0, 0);
    __syncthreads();
    int cur = 0;
    for (int it = 0; it < nIter; ++it) {
        if (it + 1 < nIter) STAGE(cur ^ 1, (it + 1) << 5);
        fp16x8 a[4], b[4];
#pragma unroll
        for (int i = 0; i < 4; ++i) {
            a[i] = *(const fp16x8*)&AsH[cur * 4096 + (wr * 4 + i) * 512 + lane * 8];
            b[i] = *(const fp16x8*)&BsH[cur * 4096 + (wc * 4 + i) * 512 + lane * 8];
        }
#pragma unroll
        for (int mi = 0; mi < 4; ++mi)
#pragma unroll
            for (int ni = 0; ni < 4; ++ni)
                acc[mi][ni] = __builtin_amdgcn_mfma_f32_16x16x32_f16(
                    a[mi], b[ni], acc[mi][ni], 0, 0, 0);
        __syncthreads();
        cur ^= 1;
    }

#pragma unroll
    for (int mi = 0; mi < 4; ++mi)
#pragma unroll
        for (int ni = 0; ni < 4; ++ni) {
            const int cl = wc * 64 + ni * 16 + lm;
#pragma unroll
            for (int r = 0; r < 4; ++r) {
                const int rl = wr * 64 + mi * 16 + lq * 4 + r;
                smem[rl * 128 + cl] = f2bf(acc[mi][ni][r]);
            }
        }
    __syncthreads();

    const int dB = blockIdx.x * 32;
#pragma unroll
    for (int e = 0; e < 16; ++e) {
        const int u = e * 256 + tid;
        const int tl = u >> 5, dd = u & 31;
        const int t = rowBase + tl, d = dB + dd;
        float a0 = 0.0f;
#pragma unroll
        for (int tap = 0; tap < CONVK; ++tap) {
            const int ts = t - (CONVK - 1) + tap;
            if (ts >= 0)
                a0 += vpre[(size_t)ts * HID + d] * bf2f(smem[tl * 128 + dd * 4 + tap]);
        }
        v[(size_t)t * HID + d] = siluf(a0);
    }
}

// ---------------------------------------------------------------------------
// D1: chunk-local WY precompute + fused tiled Q/K emission (round 8).
// ---------------------------------------------------------------------------
__global__ __launch_bounds__(256, 1) void chunkloc_kernel(
    const float* __restrict__ q, const float* __restrict__ k, const float* __restrict__ v,
    const float* __restrict__ g, const float* __restrict__ beta,
    float* __restrict__ X1g,
    unsigned short* __restrict__ X2th, unsigned short* __restrict__ X2tl,
    float* __restrict__ Mg, float* __restrict__ csg,
    unsigned short* __restrict__ Qth, unsigned short* __restrict__ Qtl,
    unsigned short* __restrict__ Kth, unsigned short* __restrict__ Ktl)
{
    __shared__ unsigned short KhS[64 * 136], KlS[64 * 136];
    __shared__ unsigned short QhS[64 * 136], QlS[64 * 136];
    __shared__ float KT[128 * 68];
    __shared__ float Vs[64 * 132];
    __shared__ float As[64 * 68];
    __shared__ float cs[64], sb[64], sbb[64];

    const int c = blockIdx.x, h = blockIdx.y;
    const int tid = threadIdx.x;
    const int wave = tid >> 6, lane = tid & 63;
    const int lm = lane & 15, lq = lane >> 4;
    const int li = tid >> 2, lq4 = tid & 3;
    const size_t rowbase = (size_t)(c * CH) * HID + h * DK;

    {
        const float* ksrc = k + rowbase + (size_t)li * HID + lq4 * 32;
        const float* qsrc = q + rowbase + (size_t)li * HID + lq4 * 32;
        const float* vsrc = v + (size_t)(c * CH + li) * HID + h * DV + lq4 * 32;
#pragma unroll
        for (int f = 0; f < 8; ++f) {
            float4 kx = *(const float4*)(ksrc + f * 4);
            float4 qx = *(const float4*)(qsrc + f * 4);
            float4 vx = *(const float4*)(vsrc + f * 4);
            const int d0 = lq4 * 32 + f * 4;
            {
                ushort4 hh, ll;
                hh.x = f2bf(kx.x); ll.x = f2bf(kx.x - bf2f(hh.x));
                hh.y = f2bf(kx.y); ll.y = f2bf(kx.y - bf2f(hh.y));
                hh.z = f2bf(kx.z); ll.z = f2bf(kx.z - bf2f(hh.z));
                hh.w = f2bf(kx.w); ll.w = f2bf(kx.w - bf2f(hh.w));
                *(ushort4*)&KhS[li * 136 + d0] = hh;
                *(ushort4*)&KlS[li * 136 + d0] = ll;
            }
            {
                ushort4 hh, ll;
                hh.x = f2bf(qx.x); ll.x = f2bf(qx.x - bf2f(hh.x));
                hh.y = f2bf(qx.y); ll.y = f2bf(qx.y - bf2f(hh.y));
                hh.z = f2bf(qx.z); ll.z = f2bf(qx.z - bf2f(hh.z));
                hh.w = f2bf(qx.w); ll.w = f2bf(qx.w - bf2f(hh.w));
                *(ushort4*)&QhS[li * 136 + d0] = hh;
                *(ushort4*)&QlS[li * 136 + d0] = ll;
            }
            KT[(d0 + 0) * 68 + li] = kx.x;
            KT[(d0 + 1) * 68 + li] = kx.y;
            KT[(d0 + 2) * 68 + li] = kx.z;
            KT[(d0 + 3) * 68 + li] = kx.w;
            *(float4*)&Vs[li * 132 + d0] = vx;
        }
    }
    if (tid < 64) {
        float gv = g[(c * CH + tid) * NH + h];
        float bv = beta[(c * CH + tid) * NH + h];
        float csv = gv;
#pragma unroll
        for (int off = 1; off < 64; off <<= 1) {
            float n = __shfl_up(csv, off);
            if (tid >= off) csv += n;
        }
        cs[tid] = csv; sb[tid] = bv; sbb[tid] = bv * __expf(csv);
    }
    __syncthreads();

    {
        const int ti = wave;
#pragma unroll
        for (int tj = 0; tj < 4; ++tj) {
            floatx4 acc = (floatx4){0.f, 0.f, 0.f, 0.f};
#pragma unroll
            for (int ks = 0; ks < 4; ++ks) {
                bf16x8 a_h = *(const bf16x8*)&KhS[(ti * 16 + lm) * 136 + ks * 32 + lq * 8];
                bf16x8 a_l = *(const bf16x8*)&KlS[(ti * 16 + lm) * 136 + ks * 32 + lq * 8];
                bf16x8 b_h = *(const bf16x8*)&KhS[(tj * 16 + lm) * 136 + ks * 32 + lq * 8];
                bf16x8 b_l = *(const bf16x8*)&KlS[(tj * 16 + lm) * 136 + ks * 32 + lq * 8];
                acc = __builtin_amdgcn_mfma_f32_16x16x32_bf16(a_h, b_h, acc, 0, 0, 0);
                acc = __builtin_amdgcn_mfma_f32_16x16x32_bf16(a_h, b_l, acc, 0, 0, 0);
                acc = __builtin_amdgcn_mfma_f32_16x16x32_bf16(a_l, b_h, acc, 0, 0, 0);
            }
#pragma unroll
            for (int r = 0; r < 4; ++r) {
                const int i = ti * 16 + lq * 4 + r, j = tj * 16 + lm;
                As[i * 68 + j] = (j < i) ? sb[i] * __expf(cs[i] - cs[j]) * acc[r] : 0.0f;
            }
        }
        const size_t mbase = (size_t)(h * NC + c) * CH * CH;
#pragma unroll
        for (int tj = 0; tj < 4; ++tj) {
            floatx4 acc = (floatx4){0.f, 0.f, 0.f, 0.f};
#pragma unroll
            for (int ks = 0; ks < 4; ++ks) {
                bf16x8 a_h = *(const bf16x8*)&QhS[(ti * 16 + lm) * 136 + ks * 32 + lq * 8];
                bf16x8 a_l = *(const bf16x8*)&QlS[(ti * 16 + lm) * 136 + ks * 32 + lq * 8];
                bf16x8 b_h = *(const bf16x8*)&KhS[(tj * 16 + lm) * 136 + ks * 32 + lq * 8];
                bf16x8 b_l = *(const bf16x8*)&KlS[(tj * 16 + lm) * 136 + ks * 32 + lq * 8];
                acc = __builtin_amdgcn_mfma_f32_16x16x32_bf16(a_h, b_h, acc, 0, 0, 0);
                acc = __builtin_amdgcn_mfma_f32_16x16x32_bf16(a_h, b_l, acc, 0, 0, 0);
                acc = __builtin_amdgcn_mfma_f32_16x16x32_bf16(a_l, b_h, acc, 0, 0, 0);
            }
#pragma unroll
            for (int r = 0; r < 4; ++r) {
                const int i = ti * 16 + lq * 4 + r, j = tj * 16 + lm;
                Mg[mbase + (size_t)i * 64 + j] =
                    (j <= i) ? __expf(cs[i] - cs[j]) * acc[r] : 0.0f;
            }
        }
    }

    float xc[64];
    const int col = tid;
    if (col < 128) {
#pragma unroll
        for (int i = 0; i < 64; ++i) xc[i] = sb[i] * Vs[i * 132 + col];
    } else {
        const int dcol = col - 128;
#pragma unroll
        for (int i4 = 0; i4 < 16; ++i4) {
            float4 kq = *(const float4*)&KT[dcol * 68 + i4 * 4];
            xc[i4 * 4 + 0] = sbb[i4 * 4 + 0] * kq.x;
            xc[i4 * 4 + 1] = sbb[i4 * 4 + 1] * kq.y;
            xc[i4 * 4 + 2] = sbb[i4 * 4 + 2] * kq.z;
            xc[i4 * 4 + 3] = sbb[i4 * 4 + 3] * kq.w;
        }
    }
    __syncthreads();

#pragma unroll
    for (int i = 1; i < 64; ++i) {
        float a = xc[i];
#pragma unroll
        for (int j4 = 0; j4 < (i + 3) / 4; ++j4) {
            float4 a4 = *(const float4*)&As[i * 68 + j4 * 4];
            a -= a4.x * xc[j4 * 4 + 0] + a4.y * xc[j4 * 4 + 1]
               + a4.z * xc[j4 * 4 + 2] + a4.w * xc[j4 * 4 + 3];
        }
        xc[i] = a;
    }

    {
        const size_t xbase = (size_t)(h * NC + c) * CH * 128;
        if (col < 128) {
            for (int i = 0; i < 64; ++i) X1g[xbase + (size_t)i * 128 + col] = xc[i];
        } else {
            for (int i = 0; i < 64; ++i) Vs[i * 132 + (col - 128)] = xc[i];
        }
    }
    if (tid < 64) csg[(size_t)(h * NC + c) * CH + tid] = cs[tid];
    __syncthreads();

    const size_t tb = (size_t)(h * NC + c) * 8192;

    {
#pragma unroll
        for (int e = 0; e < 4; ++e) {
            int u = e * 256 + tid;
            int ch = u >> 6, l = u & 63;
            int i = (ch >> 2) * 16 + (l & 15);
            int dbase = (ch & 3) * 32 + (l >> 4) * 8;
            float4 a = *(const float4*)&Vs[i * 132 + dbase];
            float4 b = *(const float4*)&Vs[i * 132 + dbase + 4];
            float xv[8] = {-a.x, -a.y, -a.z, -a.w, -b.x, -b.y, -b.z, -b.w};
            split8_store(xv, &X2th[tb + ch * 512 + l * 8], &X2tl[tb + ch * 512 + l * 8]);
        }
    }
    {
#pragma unroll
        for (int e = 0; e < 4; ++e) {
            int u = e * 256 + tid;
            int ch = u >> 6, l = u & 63;
            int i = (ch >> 2) * 16 + (l & 15);
            int dbase = (ch & 3) * 32 + (l >> 4) * 8;
            *(bf16x8*)&Qth[tb + ch * 512 + l * 8] = *(const bf16x8*)&QhS[i * 136 + dbase];
            *(bf16x8*)&Qtl[tb + ch * 512 + l * 8] = *(const bf16x8*)&QlS[i * 136 + dbase];
        }
    }
    {
#pragma unroll
        for (int e = 0; e < 4; ++e) {
            int u = e * 256 + tid;
            int ch = u >> 6, l = u & 63;
            int dk = (ch >> 1) * 16 + (l & 15);
            int ibase = (ch & 1) * 32 + (l >> 4) * 8;
            float4 a = *(const float4*)&KT[dk * 68 + ibase];
            float4 b = *(const float4*)&KT[dk * 68 + ibase + 4];
            float xv[8] = {a.x, a.y, a.z, a.w, b.x, b.y, b.z, b.w};
            split8_store(xv, &Kth[tb + ch * 512 + l * 8], &Ktl[tb + ch * 512 + l * 8]);
        }
    }
}

// ---------------------------------------------------------------------------
// D2 support + kernel (rounds 4-8, unchanged).
// ---------------------------------------------------------------------------
struct StFrags {
    bf16x8 xh[4], xl[4], qh[4], ql[4], kh[4], kl[4];
    float x1r[4], csr[4], cs63;
};

__device__ __forceinline__ void st_load(
    StFrags& f,
    const unsigned short* __restrict__ Qth, const unsigned short* __restrict__ Qtl,
    const unsigned short* __restrict__ Kth, const unsigned short* __restrict__ Ktl,
    const unsigned short* __restrict__ X2th, const unsigned short* __restrict__ X2tl,
    const float* __restrict__ X1g, const float* __restrict__ csg,
    int h, int c, int db, int mw, int lane, int lq, int lm)
{
    const size_t hc = (size_t)(h * NC + c);
    const size_t xb = hc * CH * 128;
    const size_t tb = hc * 8192 + (size_t)lane * 8;
#pragma unroll
    for (int ks = 0; ks < 4; ++ks) {
        const size_t off = tb + (size_t)(mw * 4 + ks) * 512;
        f.xh[ks] = *(const bf16x8*)(X2th + off);
        f.xl[ks] = *(const bf16x8*)(X2tl + off);
        f.qh[ks] = *(const bf16x8*)(Qth + off);
        f.ql[ks] = *(const bf16x8*)(Qtl + off);
        f.kh[ks] = *(const bf16x8*)(Kth + off);
        f.kl[ks] = *(const bf16x8*)(Ktl + off);
    }
#pragma unroll
    for (int r = 0; r < 4; ++r) {
        const int row = mw * 16 + lq * 4 + r;
        f.x1r[r] = X1g[xb + (size_t)row * 128 + db * 16 + lm];
        f.csr[r] = csg[hc * CH + row];
    }
    f.cs63 = csg[hc * CH + 63];
}

__device__ __forceinline__ void st_compute(
    const StFrags& f, floatx4& st0, floatx4& st1,
    unsigned short* SBh, unsigned short* SBl,
    unsigned short* UBh, unsigned short* UBl,
    float* __restrict__ X1g, float* __restrict__ o,
    int h, int c, int db, int mw, int lane, int lq, int lm)
{
    const size_t hc = (size_t)(h * NC + c);
    const size_t xb = hc * CH * 128;

    {
        floatx4 aU0 = (floatx4){0.f, 0.f, 0.f, 0.f};
        floatx4 aU1 = (floatx4){0.f, 0.f, 0.f, 0.f};
        floatx4 aO0 = (floatx4){0.f, 0.f, 0.f, 0.f};
        floatx4 aO1 = (floatx4){0.f, 0.f, 0.f, 0.f};
#pragma unroll
        for (int ks = 0; ks < 4; ++ks) {
            bf16x8 sh = *(const bf16x8*)&SBh[lm * 136 + ks * 32 + lq * 8];
            bf16x8 sl = *(const bf16x8*)&SBl[lm * 136 + ks * 32 + lq * 8];
            if (ks & 1) {
                aU1 = __builtin_amdgcn_mfma_f32_16x16x32_bf16(f.xh[ks], sh, aU1, 0, 0, 0);
                aU1 = __builtin_amdgcn_mfma_f32_16x16x32_bf16(f.xh[ks], sl, aU1, 0, 0, 0);
                aU1 = __builtin_amdgcn_mfma_f32_16x16x32_bf16(f.xl[ks], sh, aU1, 0, 0, 0);
                aO1 = __builtin_amdgcn_mfma_f32_16x16x32_bf16(f.qh[ks], sh, aO1, 0, 0, 0);
                aO1 = __builtin_amdgcn_mfma_f32_16x16x32_bf16(f.qh[ks], sl, aO1, 0, 0, 0);
                aO1 = __builtin_amdgcn_mfma_f32_16x16x32_bf16(f.ql[ks], sh, aO1, 0, 0, 0);
            } else {
                aU0 = __builtin_amdgcn_mfma_f32_16x16x32_bf16(f.xh[ks], sh, aU0, 0, 0, 0);
                aU0 = __builtin_amdgcn_mfma_f32_16x16x32_bf16(f.xh[ks], sl, aU0, 0, 0, 0);
                aU0 = __builtin_amdgcn_mfma_f32_16x16x32_bf16(f.xl[ks], sh, aU0, 0, 0, 0);
                aO0 = __builtin_amdgcn_mfma_f32_16x16x32_bf16(f.qh[ks], sh, aO0, 0, 0, 0);
                aO0 = __builtin_amdgcn_mfma_f32_16x16x32_bf16(f.qh[ks], sl, aO0, 0, 0, 0);
                aO0 = __builtin_amdgcn_mfma_f32_16x16x32_bf16(f.ql[ks], sh, aO0, 0, 0, 0);
            }
        }
#pragma unroll
        for (int r = 0; r < 4; ++r) {
            const int row = mw * 16 + lq * 4 + r;
            const float u = aU0[r] + aU1[r] + f.x1r[r];
            X1g[xb + (size_t)row * 128 + db * 16 + lm] = u;
            const float up = u * __expf(f.cs63 - f.csr[r]);
            unsigned short uh = f2bf(up);
            UBh[lm * 72 + row] = uh;
            UBl[lm * 72 + row] = f2bf(up - bf2f(uh));
            o[(size_t)(c * CH + row) * HID + h * DV + db * 16 + lm] =
                __expf(f.csr[r]) * (aO0[r] + aO1[r]);
        }
    }
    __syncthreads();

    {
        const float bC = __expf(f.cs63);
#pragma unroll
        for (int mt2 = 0; mt2 < 2; ++mt2) {
            const int mt = mw * 2 + mt2;
            floatx4 acc;
            floatx4 stc = mt2 ? st1 : st0;
#pragma unroll
            for (int r = 0; r < 4; ++r) acc[r] = bC * stc[r];
#pragma unroll
            for (int ks = 0; ks < 2; ++ks) {
                bf16x8 ah = f.kh[mt2 * 2 + ks];
                bf16x8 al = f.kl[mt2 * 2 + ks];
                bf16x8 bh = *(const bf16x8*)&UBh[lm * 72 + ks * 32 + lq * 8];
                bf16x8 bl = *(const bf16x8*)&UBl[lm * 72 + ks * 32 + lq * 8];
                acc = __builtin_amdgcn_mfma_f32_16x16x32_bf16(ah, bh, acc, 0, 0, 0);
                acc = __builtin_amdgcn_mfma_f32_16x16x32_bf16(ah, bl, acc, 0, 0, 0);
                acc = __builtin_amdgcn_mfma_f32_16x16x32_bf16(al, bh, acc, 0, 0, 0);
            }
            if (mt2) st1 = acc; else st0 = acc;
            ushort4 shv, slv;
#pragma unroll
            for (int r = 0; r < 4; ++r) {
                const float sv = acc[r];
                unsigned short sh = f2bf(sv);
                ((unsigned short*)&shv)[r] = sh;
                ((unsigned short*)&slv)[r] = f2bf(sv - bf2f(sh));
            }
            const int dkb = mt * 16 + lq * 4;
            *(ushort4*)&SBh[lm * 136 + dkb] = shv;
            *(ushort4*)&SBl[lm * 136 + dkb] = slv;
        }
    }
    __syncthreads();
}

__global__ __launch_bounds__(256, 1) void state_kernel(
    const unsigned short* __restrict__ Qth, const unsigned short* __restrict__ Qtl,
    const unsigned short* __restrict__ Kth, const unsigned short* __restrict__ Ktl,
    const unsigned short* __restrict__ X2th, const unsigned short* __restrict__ X2tl,
    float* __restrict__ X1g, const float* __restrict__ csg, float* __restrict__ o)
{
    __shared__ unsigned short SBh[16 * 136], SBl[16 * 136];
    __shared__ unsigned short UBh[16 * 72],  UBl[16 * 72];

    const int h = blockIdx.x, db = blockIdx.y;
    const int tid = threadIdx.x;
    const int mw = tid >> 6, lane = tid & 63;
    const int lm = lane & 15, lq = lane >> 4;

    for (int idx = tid; idx < 16 * 136; idx += 256) { SBh[idx] = 0; SBl[idx] = 0; }
    floatx4 st0 = (floatx4){0.f, 0.f, 0.f, 0.f};
    floatx4 st1 = (floatx4){0.f, 0.f, 0.f, 0.f};
    __syncthreads();

    StFrags fA, fB;
    st_load(fA, Qth, Qtl, Kth, Ktl, X2th, X2tl, X1g, csg, h, 0, db, mw, lane, lq, lm);
    for (int c = 0; c < NC; c += 2) {
        st_load(fB, Qth, Qtl, Kth, Ktl, X2th, X2tl, X1g, csg, h, c + 1, db, mw, lane, lq, lm);
        __builtin_amdgcn_sched_barrier(0);
        st_compute(fA, st0, st1, SBh, SBl, UBh, UBl, X1g, o, h, c, db, mw, lane, lq, lm);
        if (c + 2 < NC)
            st_load(fA, Qth, Qtl, Kth, Ktl, X2th, X2tl, X1g, csg, h, c + 2, db, mw, lane, lq, lm);
        __builtin_amdgcn_sched_barrier(0);
        st_compute(fB, st0, st1, SBh, SBl, UBh, UBl, X1g, o, h, c + 1, db, mw, lane, lq, lm);
    }
}

// ---------------------------------------------------------------------------
// D3 + gated RMSNorm FUSED; writes fp16 onh (final GEMM is fp16).
// grid (NC, NH).
// ---------------------------------------------------------------------------
__global__ __launch_bounds__(256) void outknorm_kernel(
    const float* __restrict__ Ug, const float* __restrict__ Mg,
    const float* __restrict__ o /* prev from state */,
    const unsigned short* __restrict__ gsil, const float* __restrict__ nw,
    unsigned short* __restrict__ out_h)
{
    __shared__ float Msh[64 * 68];
    __shared__ float Ush[64 * 132];
    __shared__ float rsq[64];

    const int c = blockIdx.x, h = blockIdx.y;
    const int tid = threadIdx.x;
    const size_t hc = (size_t)(h * NC + c);

    for (int e = 0; e < 16; ++e) {
        int idx = e * 256 + tid;
        Msh[(idx >> 6) * 68 + (idx & 63)] = Mg[hc * CH * CH + idx];
    }
    for (int e = 0; e < 32; ++e) {
        int idx = e * 256 + tid;
        int j = idx >> 7, cc = idx & 127;
        Ush[j * 132 + cc] = Ug[hc * CH * 128 + (size_t)j * 128 + cc];
    }
    __syncthreads();

    const int tx = tid & 15, ty = tid >> 4;
    const int c0 = tx * 8, i0 = ty * 4;
    float acc[4][8] = {{0}};
    for (int j4 = 0; j4 < 16; ++j4) {
        float uv[4][8];
#pragma unroll
        for (int s = 0; s < 4; ++s) {
            float4 u4a = *(const float4*)&Ush[(j4 * 4 + s) * 132 + c0];
            float4 u4b = *(const float4*)&Ush[(j4 * 4 + s) * 132 + c0 + 4];
            uv[s][0] = u4a.x; uv[s][1] = u4a.y; uv[s][2] = u4a.z; uv[s][3] = u4a.w;
            uv[s][4] = u4b.x; uv[s][5] = u4b.y; uv[s][6] = u4b.z; uv[s][7] = u4b.w;
        }
#pragma unroll
        for (int r = 0; r < 4; ++r) {
            float4 m4 = *(const float4*)&Msh[(i0 + r) * 68 + j4 * 4];
            const float mv[4] = {m4.x, m4.y, m4.z, m4.w};
#pragma unroll
            for (int s = 0; s < 4; ++s)
#pragma unroll
                for (int e = 0; e < 8; ++e) acc[r][e] += mv[s] * uv[s][e];
        }
    }
    __syncthreads();   // all Ush reads done before overwrite

    const float scale = 0.08838834764831845f;
#pragma unroll
    for (int r = 0; r < 4; ++r) {
        const float* op = &o[(size_t)(c * CH + i0 + r) * HID + h * DV + c0];
        float4 p0 = *(const float4*)op;
        float4 p1 = *(const float4*)(op + 4);
        const float pv[8] = {p0.x, p0.y, p0.z, p0.w, p1.x, p1.y, p1.z, p1.w};
#pragma unroll
        for (int e = 0; e < 8; ++e)
            Ush[(i0 + r) * 132 + c0 + e] = scale * (pv[e] + acc[r][e]);
    }
    __syncthreads();   // final o-tile resident in Ush

    // per-row RMS: 4 lanes/row, 32 cols each, 2-level shfl reduce
    {
        const int row = tid >> 2, sub = tid & 3;
        float ss = 0.0f;
#pragma unroll
        for (int k2 = 0; k2 < 32; ++k2) {
            float x = Ush[row * 132 + sub * 32 + k2];
            ss += x * x;
        }
        ss += __shfl_xor(ss, 1);
        ss += __shfl_xor(ss, 2);
        if (sub == 0) rsq[row] = rsqrtf(ss * (1.0f / 128.0f) + 1e-5f);
    }
    __syncthreads();

    // coalesced gate+norm write (fp16)
    for (int e = 0; e < 32; ++e) {
        int idx = e * 256 + tid;
        int j = idx >> 7, cc = idx & 127;
        const size_t base = (size_t)(c * CH + j) * HID + h * DV;
        float va = Ush[j * 132 + cc] * rsq[j] * nw[cc] * bf2f(gsil[base + cc]);
        out_h[base + cc] = f2h(va);
    }
}

// ---------------------------------------------------------------------------
extern "C" void kernel_launch(void* const* d_in, const int* in_sizes, int n_in,
                              void* d_out, int out_size, void* d_ws, size_t ws_size,
                              hipStream_t stream) {
    const float* hs      = (const float*)d_in[0];
    const float* Wq      = (const float*)d_in[1];
    const float* Wk      = (const float*)d_in[2];
    const float* Wv      = (const float*)d_in[3];
    const float* Wb      = (const float*)d_in[4];
    const float* Wa      = (const float*)d_in[5];
    const float* A_log   = (const float*)d_in[6];
    const float* dt_bias = (const float*)d_in[7];
    const float* Wg1     = (const float*)d_in[8];
    const float* Wg2     = (const float*)d_in[9];
    const float* Wgate   = (const float*)d_in[10];
    const float* norm_w  = (const float*)d_in[11];
    const float* Wo      = (const float*)d_in[12];

    float* ws = (float*)d_ws;
    float* q    = ws;                                        // later WoTh
    float* kbuf = ws + 3145728;
    float* vpre = ws + 6291456;                              // later Qt, then onh
    float* vbuf = ws + 9437184;                              // early hsbh/hsbl; then v / o
    unsigned short* gsil = (unsigned short*)(ws + 12582912);
    float* X1g  = ws + 14155776;                             // fp32, becomes U
    unsigned short* X2th = (unsigned short*)(ws + 17301504);
    unsigned short* X2tl = (unsigned short*)(ws + 18874368);
    float* Mg   = ws + 20447232;
    unsigned short* WTAfh = (unsigned short*)(ws + 14155776);
    unsigned short* WTBh  = (unsigned short*)(ws + 17891328);
    unsigned short* WTBl  = (unsigned short*)(ws + 19169280);
    unsigned short* WG2h  = (unsigned short*)(ws + 22044672);
    unsigned short* hsh   = (unsigned short*)(ws + 22634496);
    unsigned short* w1h16 = (unsigned short*)(ws + 24207360);
    unsigned short* Kth = (unsigned short*)(ws + 22044672);
    unsigned short* Ktl = (unsigned short*)(ws + 23617536);
    float* beta  = ws + 25190400;
    float* g     = ws + 25214976;
    float* csg   = ws + 25239552;
    unsigned short* hsbh = (unsigned short*)(ws + 9437184);
    unsigned short* hsbl = (unsigned short*)(ws + 11010048);
    unsigned short* Qth  = (unsigned short*)(ws + 6291456);
    unsigned short* Qtl  = (unsigned short*)(ws + 7864320);
    unsigned short* WoTh = (unsigned short*)(ws);            // fp16 N x K
    unsigned short* onh  = (unsigned short*)(ws + 6291456);  // fp16 M x K

    const dim3 blk(256);

    // P0: all independent prep in ONE launch
    prep_all<<<13824, blk, 0, stream>>>(hs, hsbh, hsbl, hsh,
                                        Wq, Wv, Wgate, Wg1, Wg2, Wk, Wb, Wa,
                                        WTAfh, WG2h, WTBh, WTBl);

    // P1: fused GEMM-A (BK=64) + GEMM-B (128x128) (+ inline beta/g epilogue)
    mgemm_ab<<<816, blk, 0, stream>>>(hsh, WTAfh, hsbh, hsbl, WTBh, WTBl,
                                      q, vpre, gsil, w1h16, kbuf,
                                      A_log, dt_bias, beta, g);

    // P2: conv weights GEMM with fused depthwise conv epilogue
    convgemm<<<dim3(48, 16), blk, 0, stream>>>(w1h16, WG2h, vpre, vbuf);

    // P3: chunked delta rule
    chunkloc_kernel<<<dim3(NC, NH), blk, 0, stream>>>(q, kbuf, vbuf, g, beta,
                                                      X1g, X2th, X2tl, Mg, csg,
                                                      Qth, Qtl, Kth, Ktl);
    state_kernel<<<dim3(NH, 8), blk, 0, stream>>>(Qth, Qtl, Kth, Ktl, X2th, X2tl,
                                                  X1g, csg, vbuf);
    // Wo transpose+cast fp16 (flat 256-thread launch; q dead after chunkloc)
    transcasth_kernel<<<dim3(48, 48), blk, 0, stream>>>(Wo, WoTh, 1536, 1536);

    // P4: fused outk + gated RMSNorm (fp16 out), then fp16 output GEMM BK=64
    outknorm_kernel<<<dim3(NC, NH), blk, 0, stream>>>(X1g, Mg, vbuf, gsil, norm_w, onh);
    fgemm<<<dim3(24, 16), blk, 0, stream>>>(onh, WoTh, (float*)d_out);
}